// Round 16
// baseline (4017.245 us; speedup 1.0000x reference)
//
#include <hip/hip_runtime.h>
#include <math.h>

#define H0 384
#define W0 640
#define H1 192
#define W1 320
#define H2 96
#define W2 160
#define NP1 (H1*W1)   /* 61440 */
#define NP2 (H2*W2)   /* 15360 */
#define ND  48        /* MAX_DISP/4 */
#define NBLK2 (NP2/256)  /* 60 */
#define CHW ((size_t)32*NP2)
/* padded (halo=1) layout, global coords */
#define PW 162
#define PH 98
#define PSL (PH*PW)            /* 15876 */
#define PCHW ((size_t)32*PSL)  /* 508032 */

typedef float v2f __attribute__((ext_vector_type(2)));

// wave-level channel-stats contribution: each thread holds acc[n] for ch0..ch0+n-1
__device__ __forceinline__ void wave_stats(float* __restrict__ st, int ch0,
                                           const float* acc, int n) {
    int lane = threadIdx.x & 63;
    for (int j = 0; j < n; ++j) {
        float s  = acc[j];
        float s2 = s*s;
        #pragma unroll
        for (int off = 32; off > 0; off >>= 1) {
            s  += __shfl_down(s,  off, 64);
            s2 += __shfl_down(s2, off, 64);
        }
        if (lane == 0) {
            atomicAdd(&st[2*(ch0+j)],   s);
            atomicAdd(&st[2*(ch0+j)+1], s2);
        }
    }
}

// ---------------- generic prep ----------------

__global__ void zero_buf_kernel(float* __restrict__ p, size_t n) {
    size_t i = (size_t)blockIdx.x*256 + threadIdx.x;
    size_t stride = (size_t)gridDim.x*256;
    for (; i < n; i += stride) p[i] = 0.f;
}

__device__ __forceinline__ void twr_dev(const float* __restrict__ in, float* __restrict__ out,
                                        int idx, int CI, int K, int CO) {
    int co = idx % CO;
    int t  = idx / CO;
    int k  = t % K;
    int ci = t / K;
    out[idx] = in[(co*CI + ci)*K + k];
}

// single launch: all weight transposes + packs + stats zero (74816 items)
__global__ void prep_all(const float* __restrict__ fnet_w1, const float* __restrict__ cnet_w1,
                         const float* __restrict__ fnet_w2, const float* __restrict__ cnet_w2,
                         const float* __restrict__ fnet_w3, const float* __restrict__ cnet_w3,
                         const float* __restrict__ bform_a, const float* __restrict__ bform_b,
                         const float* __restrict__ bform_cd_w, const float* __restrict__ disp_w1,
                         const float* __restrict__ gru_wz, const float* __restrict__ gru_wr,
                         const float* __restrict__ gru_wq,
                         float* __restrict__ we1f, float* __restrict__ we1c,
                         float* __restrict__ we2f, float* __restrict__ we2c,
                         float* __restrict__ w3f, float* __restrict__ w3c,
                         float* __restrict__ wat, float* __restrict__ wbt,
                         float* __restrict__ wct, float* __restrict__ wd1t,
                         float4* __restrict__ wzrpk, float2* __restrict__ wqpk,
                         float* __restrict__ stats) {
    int i = blockIdx.x*256 + threadIdx.x;
    if (i < 4704) { twr_dev(fnet_w1, we1f, i, 3, 49, 32); return; }
    i -= 4704;
    if (i < 4704) { twr_dev(cnet_w1, we1c, i, 3, 49, 32); return; }
    i -= 4704;
    if (i < 9216) { twr_dev(fnet_w2, we2f, i, 32, 9, 32); return; }
    i -= 9216;
    if (i < 9216) { twr_dev(cnet_w2, we2c, i, 32, 9, 32); return; }
    i -= 9216;
    if (i < 1024) { twr_dev(fnet_w3, w3f, i, 32, 1, 32); return; }
    i -= 1024;
    if (i < 1024) { twr_dev(cnet_w3, w3c, i, 32, 1, 32); return; }
    i -= 1024;
    if (i < 1024) { twr_dev(bform_a, wat, i, 32, 1, 32); return; }
    i -= 1024;
    if (i < 1024) { twr_dev(bform_b, wbt, i, 32, 1, 32); return; }
    i -= 1024;
    if (i < 1024) { twr_dev(bform_cd_w, wct, i, 32, 1, 32); return; }
    i -= 1024;
    if (i < 18432) { twr_dev(disp_w1, wd1t, i, 32, 9, 64); return; }
    i -= 18432;
    if (i < 9216) {   // packed z/r: [cg][ci<64][k] = {z0,z1,r0,r1}
        int k  = i % 9;
        int ci = (i/9) % 64;
        int cg = i / (9*64);
        int co0 = cg*2, co1 = co0 + 1;
        float z0, z1, r0, r1;
        if (ci < 32) {
            z0 = gru_wz[(co0*96 + ci)*9 + k] + gru_wz[(co0*96 + ci + 32)*9 + k];
            z1 = gru_wz[(co1*96 + ci)*9 + k] + gru_wz[(co1*96 + ci + 32)*9 + k];
            r0 = gru_wr[(co0*96 + ci)*9 + k] + gru_wr[(co0*96 + ci + 32)*9 + k];
            r1 = gru_wr[(co1*96 + ci)*9 + k] + gru_wr[(co1*96 + ci + 32)*9 + k];
        } else {
            z0 = gru_wz[(co0*96 + ci + 32)*9 + k];
            z1 = gru_wz[(co1*96 + ci + 32)*9 + k];
            r0 = gru_wr[(co0*96 + ci + 32)*9 + k];
            r1 = gru_wr[(co1*96 + ci + 32)*9 + k];
        }
        wzrpk[i] = make_float4(z0, z1, r0, r1);
        return;
    }
    i -= 9216;
    if (i < 13824) {  // packed q: [cg][ci<96][k] = {co0, co1}
        int k  = i % 9;
        int ci = (i/9) % 96;
        int cg = i / (9*96);
        wqpk[i] = make_float2(gru_wq[((cg*2)*96 + ci)*9 + k], gru_wq[((cg*2+1)*96 + ci)*9 + k]);
        return;
    }
    i -= 13824;
    if (i < 384) stats[i] = 0.f;
}

// hwork[c][py][px] = hidden[c][py-1][px-1] interior, 0 halo
__global__ void pad_init_kernel(const float* __restrict__ hidden, float* __restrict__ hwork) {
    int idx = blockIdx.x*256 + threadIdx.x;
    if (idx >= 32*PSL) return;
    int c = idx / PSL;
    int r = idx % PSL;
    int py = r / PW, px = r % PW;
    int y = py - 1, x = px - 1;
    float v = 0.f;
    if ((unsigned)y < (unsigned)H2 && (unsigned)x < (unsigned)W2)
        v = hidden[c*NP2 + y*W2 + x];
    hwork[idx] = v;
}

// ---------------- encoder kernels (stats fused into epilogues) ----------------

// 7x7 s2, image1: fnet AND cnet in one pass; grid dim3(240, 4); 8 co each net
__global__ __launch_bounds__(256, 4)
void conv7s2_dual(const float* __restrict__ img,
                  const float* __restrict__ wtf, const float* __restrict__ wtc,
                  const float* __restrict__ bf, const float* __restrict__ bc,
                  float* __restrict__ outf, float* __restrict__ outc,
                  float* __restrict__ stf, float* __restrict__ stc) {
    int co8 = blockIdx.y*8;
    int sp = blockIdx.x*256 + threadIdx.x;
    int oy = sp / W1, ox = sp % W1;
    float af[8], ac[8];
    #pragma unroll
    for (int j = 0; j < 8; ++j) { af[j] = bf[co8+j]; ac[j] = bc[co8+j]; }
    for (int ci = 0; ci < 3; ++ci) {
        for (int ky = 0; ky < 7; ++ky) {
            int iy = 2*oy - 3 + ky;
            if ((unsigned)iy >= (unsigned)H0) continue;
            const float* row  = img + ci*(H0*W0) + iy*W0;
            int wbase = (ci*49 + ky*7)*32 + co8;
            #pragma unroll
            for (int kx = 0; kx < 7; ++kx) {
                int ix = 2*ox - 3 + kx;
                if ((unsigned)ix >= (unsigned)W0) continue;
                float v = row[ix]*(2.0f/255.0f) - 1.0f;
                const float4* wpf = (const float4*)(wtf + wbase + kx*32);
                const float4* wpc = (const float4*)(wtc + wbase + kx*32);
                float4 f0 = wpf[0], f1 = wpf[1];
                float4 c0 = wpc[0], c1 = wpc[1];
                af[0] += v*f0.x; af[1] += v*f0.y; af[2] += v*f0.z; af[3] += v*f0.w;
                af[4] += v*f1.x; af[5] += v*f1.y; af[6] += v*f1.z; af[7] += v*f1.w;
                ac[0] += v*c0.x; ac[1] += v*c0.y; ac[2] += v*c0.z; ac[3] += v*c0.w;
                ac[4] += v*c1.x; ac[5] += v*c1.y; ac[6] += v*c1.z; ac[7] += v*c1.w;
            }
        }
    }
    #pragma unroll
    for (int j = 0; j < 8; ++j) {
        outf[(co8+j)*NP1 + sp] = af[j];
        outc[(co8+j)*NP1 + sp] = ac[j];
    }
    wave_stats(stf, co8, af, 8);
    wave_stats(stc, co8, ac, 8);
}

// 7x7 s2, single net (image2): grid dim3(240, 2); thread: 1 px, 16 co
__global__ void conv7s2_v3(const float* __restrict__ img, const float* __restrict__ wt,
                           const float* __restrict__ b, float* __restrict__ out,
                           float* __restrict__ st) {
    int cg = blockIdx.y;
    int co16 = cg*16;
    int sp = blockIdx.x*256 + threadIdx.x;
    int oy = sp / W1, ox = sp % W1;
    float acc[16];
    #pragma unroll
    for (int j = 0; j < 16; ++j) acc[j] = b[co16+j];
    for (int ci = 0; ci < 3; ++ci) {
        for (int ky = 0; ky < 7; ++ky) {
            int iy = 2*oy - 3 + ky;
            if ((unsigned)iy >= (unsigned)H0) continue;
            const float* row  = img + ci*(H0*W0) + iy*W0;
            const float* wrow = wt + (ci*49 + ky*7)*32 + co16;
            #pragma unroll
            for (int kx = 0; kx < 7; ++kx) {
                int ix = 2*ox - 3 + kx;
                if ((unsigned)ix >= (unsigned)W0) continue;
                float v = row[ix]*(2.0f/255.0f) - 1.0f;
                const float4* wp = (const float4*)(wrow + kx*32);
                #pragma unroll
                for (int j4 = 0; j4 < 4; ++j4) {
                    float4 w4 = wp[j4];
                    acc[4*j4+0] += v*w4.x; acc[4*j4+1] += v*w4.y;
                    acc[4*j4+2] += v*w4.z; acc[4*j4+3] += v*w4.w;
                }
            }
        }
    }
    #pragma unroll
    for (int j = 0; j < 16; ++j) out[(co16+j)*NP1 + sp] = acc[j];
    wave_stats(st, co16, acc, 16);
}

// 3x3 s2 with fused input instance-norm+relu and fused output stats; grid 4*NBLK2
__global__ void conv3s2_fused(const float* __restrict__ in, const float* __restrict__ st,
                              const float* __restrict__ wt, const float* __restrict__ b,
                              float* __restrict__ out, float* __restrict__ stout) {
    int cg = blockIdx.x / NBLK2;
    int sp = (blockIdx.x % NBLK2)*256 + threadIdx.x;
    int co8 = cg*8;
    int oy = sp / W2, ox = sp % W2;
    float acc[8];
    #pragma unroll
    for (int j = 0; j < 8; ++j) acc[j] = b[co8+j];
    for (int ci = 0; ci < 32; ++ci) {
        float m    = st[2*ci] * (1.0f/NP1);
        float var  = st[2*ci+1] * (1.0f/NP1) - m*m;
        float rstd = rsqrtf(var + 1e-5f);
        const float* ip  = in + ci*NP1;
        const float* wci = wt + ci*9*32 + co8;
        #pragma unroll
        for (int ky = 0; ky < 3; ++ky) {
            int iy = 2*oy - 1 + ky;
            if ((unsigned)iy >= (unsigned)H1) continue;
            const float* row = ip + iy*W1;
            #pragma unroll
            for (int kx = 0; kx < 3; ++kx) {
                int ix = 2*ox - 1 + kx;
                if ((unsigned)ix >= (unsigned)W1) continue;
                float t = fmaxf((row[ix] - m)*rstd, 0.f);
                const float4* wp = (const float4*)(wci + (ky*3+kx)*32);
                float4 w0 = wp[0], w1 = wp[1];
                acc[0] += t*w0.x; acc[1] += t*w0.y; acc[2] += t*w0.z; acc[3] += t*w0.w;
                acc[4] += t*w1.x; acc[5] += t*w1.y; acc[6] += t*w1.z; acc[7] += t*w1.w;
            }
        }
    }
    #pragma unroll
    for (int j = 0; j < 8; ++j) out[(co8+j)*NP2 + sp] = acc[j];
    wave_stats(stout, co8, acc, 8);
}

// 1x1 with fused input instance-norm+relu; grid 4*NBLK2; thread: 1 px, 8 co; optional tanh
__global__ void conv1x1_fused(const float* __restrict__ in, const float* __restrict__ st,
                              const float* __restrict__ wt, const float* __restrict__ b,
                              float* __restrict__ out, int mode) {
    int cg = blockIdx.x / NBLK2;
    int sp = (blockIdx.x % NBLK2)*256 + threadIdx.x;
    int co8 = cg*8;
    float acc[8];
    #pragma unroll
    for (int j = 0; j < 8; ++j) acc[j] = b[co8+j];
    for (int ci = 0; ci < 32; ++ci) {
        float m    = st[2*ci] * (1.0f/NP2);
        float var  = st[2*ci+1] * (1.0f/NP2) - m*m;
        float rstd = rsqrtf(var + 1e-5f);
        float t = fmaxf((in[ci*NP2 + sp] - m)*rstd, 0.f);
        const float4* wp = (const float4*)(wt + ci*32 + co8);
        float4 w0 = wp[0], w1 = wp[1];
        acc[0] += t*w0.x; acc[1] += t*w0.y; acc[2] += t*w0.z; acc[3] += t*w0.w;
        acc[4] += t*w1.x; acc[5] += t*w1.y; acc[6] += t*w1.z; acc[7] += t*w1.w;
    }
    #pragma unroll
    for (int j = 0; j < 8; ++j) {
        float a = acc[j];
        if (mode) a = tanhf(a);
        out[(co8+j)*NP2 + sp] = a;
    }
}

// ---------------- feat(0) prologue (padded) ----------------

__global__ void feat0_pad_kernel(const float* __restrict__ fmap1, const float* __restrict__ fmap2,
                                 const float* __restrict__ wat, const float* __restrict__ wbt,
                                 const float* __restrict__ wct, const float* __restrict__ bc,
                                 float* __restrict__ featA) {
    int cg  = blockIdx.x / NBLK2;
    int sp  = (blockIdx.x % NBLK2)*256 + threadIdx.x;
    int y = sp / W2;
    int gx = sp % W2;
    int co8 = cg*8;
    float acc[8];
    #pragma unroll
    for (int j = 0; j < 8; ++j) acc[j] = bc[co8+j];
    for (int ci = 0; ci < 32; ++ci) {
        float f1 = fmap1[ci*NP2 + sp];
        float f2 = fmap2[ci*NP2 + sp];
        float f12 = f1*f2;
        const float4* ap = (const float4*)(wat + ci*32 + co8);
        const float4* bp = (const float4*)(wbt + ci*32 + co8);
        const float4* cp = (const float4*)(wct + ci*32 + co8);
        float4 a0 = ap[0], a1 = ap[1];
        float4 b0 = bp[0], b1 = bp[1];
        float4 c0 = cp[0], c1 = cp[1];
        acc[0] += f1*a0.x + f2*b0.x + f12*c0.x;
        acc[1] += f1*a0.y + f2*b0.y + f12*c0.y;
        acc[2] += f1*a0.z + f2*b0.z + f12*c0.z;
        acc[3] += f1*a0.w + f2*b0.w + f12*c0.w;
        acc[4] += f1*a1.x + f2*b1.x + f12*c1.x;
        acc[5] += f1*a1.y + f2*b1.y + f12*c1.y;
        acc[6] += f1*a1.z + f2*b1.z + f12*c1.z;
        acc[7] += f1*a1.w + f2*b1.w + f12*c1.w;
    }
    float* dst = featA + (size_t)(y+1)*PW + (gx+1);
    #pragma unroll
    for (int j = 0; j < 8; ++j) dst[(size_t)(co8+j)*PSL] = acc[j];
}

// ---------------- GRU loop kernels (compact-column domain, 3-job split) ----------------
// grid dim3(nblk, 48): blockIdx.y = cg*3 + job.
//   job0: full z/r conv (zbuf, rhpad, rhpad zero col)
//   job1: feat(d+1) -> featB; q-partial over hworkA (wq ci 32..63) -> qpartA
//   job2: q-partial over featA (wq ci 64..95) -> qpartB

__global__ __launch_bounds__(256, 4)
void zrq_a(const float* __restrict__ hworkA, const float* __restrict__ featA,
           const float* __restrict__ fmap1, const float* __restrict__ fmap2,
           const float4* __restrict__ wzrpk, const float2* __restrict__ wqpk,
           const float* __restrict__ wat, const float* __restrict__ wbt,
           const float* __restrict__ wct, const float* __restrict__ bfc,
           const float* __restrict__ bz, const float* __restrict__ br,
           float* __restrict__ zbuf, float* __restrict__ rhpad,
           float* __restrict__ featB, float* __restrict__ qpartA,
           float* __restrict__ qpartB, int d, int Wd) {
    __shared__ v2f lws[1152];
    __shared__ v2f lfa[32], lfb[32], lfc[32];
    int cg  = blockIdx.y / 3;
    int job = blockIdx.y - cg*3;
    int co0 = cg*2;
    if (job == 0) {
        const float4* wsrc = wzrpk + (size_t)cg*576;
        for (int i = threadIdx.x; i < 576; i += 256) {
            float4 w = wsrc[i];
            lws[i]       = (v2f){w.x, w.y};   // z
            lws[576 + i] = (v2f){w.z, w.w};   // r
        }
    } else if (job == 1) {
        const float2* wsrc = wqpk + (size_t)cg*864 + 288;   // wq ci 32..63
        for (int i = threadIdx.x; i < 288; i += 256) {
            float2 w = wsrc[i];
            lws[i] = (v2f){w.x, w.y};
        }
        if (threadIdx.x < 32) {
            int ci = threadIdx.x;
            lfa[ci] = (v2f){wat[ci*32+co0], wat[ci*32+co0+1]};
            lfb[ci] = (v2f){wbt[ci*32+co0], wbt[ci*32+co0+1]};
            lfc[ci] = (v2f){wct[ci*32+co0], wct[ci*32+co0+1]};
        }
    } else {
        const float2* wsrc = wqpk + (size_t)cg*864 + 576;   // wq ci 64..95
        for (int i = threadIdx.x; i < 288; i += 256) {
            float2 w = wsrc[i];
            lws[i] = (v2f){w.x, w.y};
        }
    }
    __syncthreads();
    int sp2 = blockIdx.x*256 + threadIdx.x;
    if (sp2 >= 48*Wd) return;
    int rp = sp2 / Wd;
    int lx = sp2 - rp*Wd;
    int y0 = rp*2;
    int gx = d + lx;
    size_t poff = (size_t)(y0+1)*PW + (gx+1);
    int ub = y0*W2 + gx;

    if (job == 0) {
        // marching zero col for rhpad (left pad of this iteration's q conv)
        if (lx == 0) {
            #pragma unroll
            for (int j = 0; j < 2; ++j) {
                rhpad[(size_t)(co0+j)*PSL + poff - 1]      = 0.f;
                rhpad[(size_t)(co0+j)*PSL + poff + PW - 1] = 0.f;
            }
        }
        // z/r conv: pass 0 = hworkA (ci 0..31), pass 1 = featA (ci 32..63)
        v2f az0 = (v2f){bz[co0], bz[co0+1]}, az1 = az0;
        v2f ar0 = (v2f){br[co0], br[co0+1]}, ar1 = ar0;
        #pragma unroll
        for (int pass = 0; pass < 2; ++pass) {
            const float* p = (pass == 0 ? hworkA : featA) + poff;
            const v2f* wz = lws + pass*288;
            const v2f* wr = lws + 576 + pass*288;
            #pragma unroll 2
            for (int ci = 0; ci < 32; ++ci) {
                float v[12];
                #pragma unroll
                for (int r = 0; r < 4; ++r) {
                    v[r*3+0] = p[(r-1)*PW - 1];
                    v[r*3+1] = p[(r-1)*PW    ];
                    v[r*3+2] = p[(r-1)*PW + 1];
                }
                #pragma unroll
                for (int k = 0; k < 9; ++k) {
                    int ky = k/3, kx = k - 3*ky;
                    float t0 = v[ky*3+kx];
                    float t1 = v[(ky+1)*3+kx];
                    v2f wzk = wz[k], wrk = wr[k];
                    az0 += wzk*(v2f){t0,t0}; az1 += wzk*(v2f){t1,t1};
                    ar0 += wrk*(v2f){t0,t0}; ar1 += wrk*(v2f){t1,t1};
                }
                p += PSL;
                wz += 9; wr += 9;
            }
        }
        v2f z0, z1, r0, r1;
        z0.x = 1.f/(1.f + __expf(-az0.x)); z0.y = 1.f/(1.f + __expf(-az0.y));
        z1.x = 1.f/(1.f + __expf(-az1.x)); z1.y = 1.f/(1.f + __expf(-az1.y));
        r0.x = 1.f/(1.f + __expf(-ar0.x)); r0.y = 1.f/(1.f + __expf(-ar0.y));
        r1.x = 1.f/(1.f + __expf(-ar1.x)); r1.y = 1.f/(1.f + __expf(-ar1.y));
        float h00 = hworkA[(size_t)co0*PSL + poff];
        float h01 = hworkA[(size_t)(co0+1)*PSL + poff];
        float h10 = hworkA[(size_t)co0*PSL + poff + PW];
        float h11 = hworkA[(size_t)(co0+1)*PSL + poff + PW];
        zbuf[(size_t)co0*NP2 + ub]          = z0.x;
        zbuf[(size_t)(co0+1)*NP2 + ub]      = z0.y;
        zbuf[(size_t)co0*NP2 + ub + W2]     = z1.x;
        zbuf[(size_t)(co0+1)*NP2 + ub + W2] = z1.y;
        rhpad[(size_t)co0*PSL + poff]          = r0.x*h00;
        rhpad[(size_t)(co0+1)*PSL + poff]      = r0.y*h01;
        rhpad[(size_t)co0*PSL + poff + PW]     = r1.x*h10;
        rhpad[(size_t)(co0+1)*PSL + poff + PW] = r1.y*h11;
    } else if (job == 1) {
        // feat(d+1) -> featB; col d (lx==0) is its left-halo zero col
        int dn = d + 1;
        if (dn < ND) {
            if (lx == 0) {
                #pragma unroll
                for (int j = 0; j < 2; ++j) {
                    featB[(size_t)(co0+j)*PSL + poff]      = 0.f;
                    featB[(size_t)(co0+j)*PSL + poff + PW] = 0.f;
                }
            } else {
                v2f f0 = (v2f){bfc[co0], bfc[co0+1]};
                v2f f1 = f0;
                int base1 = y0*W2 + gx;
                #pragma unroll 2
                for (int ci = 0; ci < 32; ++ci) {
                    float a1 = fmap1[ci*NP2 + base1];
                    float a2 = fmap1[ci*NP2 + base1 + W2];
                    float b1 = fmap2[ci*NP2 + base1 - dn];
                    float b2 = fmap2[ci*NP2 + base1 + W2 - dn];
                    v2f wa = lfa[ci], wb = lfb[ci], wc = lfc[ci];
                    f0 += wa*(v2f){a1,a1} + wb*(v2f){b1,b1} + wc*(v2f){a1*b1,a1*b1};
                    f1 += wa*(v2f){a2,a2} + wb*(v2f){b2,b2} + wc*(v2f){a2*b2,a2*b2};
                }
                featB[(size_t)co0*PSL + poff]          = f0.x;
                featB[(size_t)(co0+1)*PSL + poff]      = f0.y;
                featB[(size_t)co0*PSL + poff + PW]     = f1.x;
                featB[(size_t)(co0+1)*PSL + poff + PW] = f1.y;
            }
        }
        // q partial A: hworkA with wq ci 32..63
        v2f a0 = (v2f){0.f, 0.f};
        v2f a1 = a0;
        {
            const float* p = hworkA + poff;
            const v2f* wp = lws;
            #pragma unroll 2
            for (int ci = 0; ci < 32; ++ci) {
                float v[12];
                #pragma unroll
                for (int r = 0; r < 4; ++r) {
                    v[r*3+0] = p[(r-1)*PW - 1];
                    v[r*3+1] = p[(r-1)*PW    ];
                    v[r*3+2] = p[(r-1)*PW + 1];
                }
                #pragma unroll
                for (int k = 0; k < 9; ++k) {
                    int ky = k/3, kx = k - 3*ky;
                    float t0 = v[ky*3+kx];
                    float t1 = v[(ky+1)*3+kx];
                    v2f wk = wp[k];
                    a0 += wk*(v2f){t0,t0};
                    a1 += wk*(v2f){t1,t1};
                }
                p += PSL;
                wp += 9;
            }
        }
        qpartA[(size_t)co0*NP2 + ub]          = a0.x;
        qpartA[(size_t)(co0+1)*NP2 + ub]      = a0.y;
        qpartA[(size_t)co0*NP2 + ub + W2]     = a1.x;
        qpartA[(size_t)(co0+1)*NP2 + ub + W2] = a1.y;
    } else {
        // q partial B: featA with wq ci 64..95
        v2f a0 = (v2f){0.f, 0.f};
        v2f a1 = a0;
        {
            const float* p = featA + poff;
            const v2f* wp = lws;
            #pragma unroll 2
            for (int ci = 0; ci < 32; ++ci) {
                float v[12];
                #pragma unroll
                for (int r = 0; r < 4; ++r) {
                    v[r*3+0] = p[(r-1)*PW - 1];
                    v[r*3+1] = p[(r-1)*PW    ];
                    v[r*3+2] = p[(r-1)*PW + 1];
                }
                #pragma unroll
                for (int k = 0; k < 9; ++k) {
                    int ky = k/3, kx = k - 3*ky;
                    float t0 = v[ky*3+kx];
                    float t1 = v[(ky+1)*3+kx];
                    v2f wk = wp[k];
                    a0 += wk*(v2f){t0,t0};
                    a1 += wk*(v2f){t1,t1};
                }
                p += PSL;
                wp += 9;
            }
        }
        qpartB[(size_t)co0*NP2 + ub]          = a0.x;
        qpartB[(size_t)(co0+1)*NP2 + ub]      = a0.y;
        qpartB[(size_t)co0*NP2 + ub + W2]     = a1.x;
        qpartB[(size_t)(co0+1)*NP2 + ub + W2] = a1.y;
    }
}

// q_fin: q's rh-pass (wq ci 0..31) + qpartA + qpartB + bias -> tanh -> GRU update.
// grid dim3(nblk, 16)
__global__ __launch_bounds__(256, 4)
void q_fin(const float* __restrict__ rhpad, const float* __restrict__ hworkA,
           const float* __restrict__ zbuf, const float* __restrict__ qpartA,
           const float* __restrict__ qpartB,
           const float2* __restrict__ wqpk, const float* __restrict__ bq,
           float* __restrict__ hfinal, float* __restrict__ hworkB, int d, int Wd) {
    __shared__ v2f lw[288];
    int cg  = blockIdx.y;
    int co0 = cg*2;
    {
        const float2* wsrc = wqpk + (size_t)cg*864;   // wq ci 0..31
        for (int i = threadIdx.x; i < 288; i += 256) {
            float2 w = wsrc[i];
            lw[i] = (v2f){w.x, w.y};
        }
    }
    __syncthreads();
    int sp2 = blockIdx.x*256 + threadIdx.x;
    if (sp2 >= 48*Wd) return;
    int rp = sp2 / Wd;
    int lx = sp2 - rp*Wd;
    int y0 = rp*2;
    int gx = d + lx;
    size_t poff = (size_t)(y0+1)*PW + (gx+1);
    int ub = y0*W2 + gx;

    v2f a0 = (v2f){bq[co0], bq[co0+1]};
    v2f a1 = a0;
    {
        const float* p = rhpad + poff;
        const v2f* wp = lw;
        #pragma unroll 2
        for (int ci = 0; ci < 32; ++ci) {
            float v[12];
            #pragma unroll
            for (int r = 0; r < 4; ++r) {
                v[r*3+0] = p[(r-1)*PW - 1];
                v[r*3+1] = p[(r-1)*PW    ];
                v[r*3+2] = p[(r-1)*PW + 1];
            }
            #pragma unroll
            for (int k = 0; k < 9; ++k) {
                int ky = k/3, kx = k - 3*ky;
                float t0 = v[ky*3+kx];
                float t1 = v[(ky+1)*3+kx];
                v2f wk = lw[(wp - lw) + k];
                a0 += wk*(v2f){t0,t0};
                a1 += wk*(v2f){t1,t1};
            }
            p += PSL;
            wp += 9;
        }
    }
    a0.x += qpartA[(size_t)co0*NP2 + ub]          + qpartB[(size_t)co0*NP2 + ub];
    a0.y += qpartA[(size_t)(co0+1)*NP2 + ub]      + qpartB[(size_t)(co0+1)*NP2 + ub];
    a1.x += qpartA[(size_t)co0*NP2 + ub + W2]     + qpartB[(size_t)co0*NP2 + ub + W2];
    a1.y += qpartA[(size_t)(co0+1)*NP2 + ub + W2] + qpartB[(size_t)(co0+1)*NP2 + ub + W2];
    float q00 = tanhf(a0.x), q01 = tanhf(a0.y);
    float q10 = tanhf(a1.x), q11 = tanhf(a1.y);
    #pragma unroll
    for (int j = 0; j < 2; ++j) {
        float qa = (j == 0) ? q00 : q01;
        float qb = (j == 0) ? q10 : q11;
        size_t pidx = (size_t)(co0+j)*PSL + poff;
        size_t uidx = (size_t)(co0+j)*NP2 + ub;
        float z_a = zbuf[uidx];
        float z_b = zbuf[uidx + W2];
        float h_a = hworkA[pidx];
        float h_b = hworkA[pidx + PW];
        float hn_a = (1.f - z_a)*h_a + z_a*qa;
        float hn_b = (1.f - z_b)*h_b + z_b*qb;
        if (lx == 0 || d == ND-1) {
            hfinal[pidx]      = hn_a;
            hfinal[pidx + PW] = hn_b;
        }
        hworkB[pidx]      = (lx == 0) ? 0.f : hn_a;
        hworkB[pidx + PW] = (lx == 0) ? 0.f : hn_b;
    }
}

// ---------------- disparity head ----------------

// 3x3 conv 32->64 + relu on padded hfinal; grid dim3(30, 16); thread: 2 rows x 4 co
__global__ __launch_bounds__(256, 4)
void disp1_v6(const float* __restrict__ hfinal, const float* __restrict__ wt,
              const float* __restrict__ b, float* __restrict__ out) {
    __shared__ float4 lw[288];   // [ci*9+k] -> 4 co weights
    int cg  = blockIdx.y;
    int co0 = cg*4;
    for (int i = threadIdx.x; i < 288; i += 256)
        lw[i] = *(const float4*)&wt[i*64 + co0];
    __syncthreads();
    int sp2 = blockIdx.x*256 + threadIdx.x;   // 0..7679
    int y0 = (sp2 / W2)*2;
    int gx = sp2 % W2;
    size_t poff = (size_t)(y0+1)*PW + (gx+1);
    float4 bb = *(const float4*)&b[co0];
    float acc0[4] = {bb.x, bb.y, bb.z, bb.w};
    float acc1[4] = {bb.x, bb.y, bb.z, bb.w};
    const float* p = hfinal + poff;
    #pragma unroll 2
    for (int ci = 0; ci < 32; ++ci) {
        float v[12];
        #pragma unroll
        for (int r = 0; r < 4; ++r) {
            v[r*3+0] = p[(r-1)*PW - 1];
            v[r*3+1] = p[(r-1)*PW    ];
            v[r*3+2] = p[(r-1)*PW + 1];
        }
        #pragma unroll
        for (int k = 0; k < 9; ++k) {
            int ky = k/3, kx = k - 3*ky;
            float t0 = v[ky*3+kx];
            float t1 = v[(ky+1)*3+kx];
            float4 w = lw[ci*9+k];
            acc0[0] += t0*w.x; acc0[1] += t0*w.y; acc0[2] += t0*w.z; acc0[3] += t0*w.w;
            acc1[0] += t1*w.x; acc1[1] += t1*w.y; acc1[2] += t1*w.z; acc1[3] += t1*w.w;
        }
        p += PSL;
    }
    int ub = y0*W2 + gx;
    #pragma unroll
    for (int j = 0; j < 4; ++j) {
        out[(co0+j)*NP2 + ub]      = fmaxf(acc0[j], 0.f);
        out[(co0+j)*NP2 + ub + W2] = fmaxf(acc1[j], 0.f);
    }
}

__global__ void disp2_part_kernel(const float* __restrict__ in, const float* __restrict__ w,
                                  float* __restrict__ part) {
    __shared__ float lw[8*9];
    int g  = blockIdx.x / NBLK2;
    int sp = (blockIdx.x % NBLK2)*256 + threadIdx.x;
    if (threadIdx.x < 72) lw[threadIdx.x] = w[g*72 + threadIdx.x];
    __syncthreads();
    int y = sp / W2, x = sp % W2;
    float acc = 0.f;
    #pragma unroll
    for (int ci = 0; ci < 8; ++ci) {
        const float* ip = in + (g*8 + ci)*NP2;
        #pragma unroll
        for (int dy = 0; dy < 3; ++dy) {
            int ys = y+dy-1; if ((unsigned)ys >= (unsigned)H2) continue;
            const float* row = ip + ys*W2;
            #pragma unroll
            for (int dx = 0; dx < 3; ++dx) {
                int xs = x+dx-1; if ((unsigned)xs >= (unsigned)W2) continue;
                acc += lw[ci*9+dy*3+dx] * row[xs];
            }
        }
    }
    part[g*NP2 + sp] = acc;
}

__global__ void disp2_comb_kernel(const float* __restrict__ part, const float* __restrict__ b,
                                  float* __restrict__ out) {
    int sp = blockIdx.x*256 + threadIdx.x;
    float acc = b[0];
    #pragma unroll
    for (int g = 0; g < 8; ++g) acc += part[g*NP2 + sp];
    out[sp] = -acc;
}

// ---------------- launch ----------------

extern "C" void kernel_launch(void* const* d_in, const int* in_sizes, int n_in,
                              void* d_out, int out_size, void* d_ws, size_t ws_size,
                              hipStream_t stream) {
    const float* image1   = (const float*)d_in[0];
    const float* image2   = (const float*)d_in[1];
    const float* fnet_w1  = (const float*)d_in[2];
    const float* fnet_b1  = (const float*)d_in[3];
    const float* fnet_w2  = (const float*)d_in[4];
    const float* fnet_b2  = (const float*)d_in[5];
    const float* fnet_w3  = (const float*)d_in[6];
    const float* fnet_b3  = (const float*)d_in[7];
    const float* cnet_w1  = (const float*)d_in[8];
    const float* cnet_b1  = (const float*)d_in[9];
    const float* cnet_w2  = (const float*)d_in[10];
    const float* cnet_b2  = (const float*)d_in[11];
    const float* cnet_w3  = (const float*)d_in[12];
    const float* cnet_b3  = (const float*)d_in[13];
    const float* bform_a  = (const float*)d_in[14];
    const float* bform_b  = (const float*)d_in[15];
    const float* bform_cd_w = (const float*)d_in[16];
    const float* bform_cd_b = (const float*)d_in[17];
    const float* gru_wz   = (const float*)d_in[18];
    const float* gru_bz   = (const float*)d_in[19];
    const float* gru_wr   = (const float*)d_in[20];
    const float* gru_br   = (const float*)d_in[21];
    const float* gru_wq   = (const float*)d_in[22];
    const float* gru_bq   = (const float*)d_in[23];
    const float* disp_w1  = (const float*)d_in[24];
    const float* disp_b1  = (const float*)d_in[25];
    const float* disp_w2  = (const float*)d_in[26];
    const float* disp_b2  = (const float*)d_in[27];

    float* ws = (float*)d_ws;
    size_t o = 0;
    float* e1f    = ws + o; o += (size_t)32*NP1;
    float* e1c    = ws + o; o += (size_t)32*NP1;
    float* e2     = ws + o; o += CHW;
    float* fmap1  = ws + o; o += CHW;
    float* fmap2  = ws + o; o += CHW;
    float* hidden = ws + o; o += CHW;
    float* zbuf   = ws + o; o += CHW;
    float* qpartA = ws + o; o += CHW;
    float* qpartB = ws + o; o += CHW;
    float* hwork0 = ws + o; o += PCHW;
    /* the next 5 padded buffers are contiguous -> one zero_buf */
    float* hwork1 = ws + o; o += PCHW;
    float* rhpad  = ws + o; o += PCHW;
    float* feat0  = ws + o; o += PCHW;
    float* feat1  = ws + o; o += PCHW;
    float* hfinal = ws + o; o += PCHW;
    float* stats  = ws + o; o += 384;
    float* wzrpk  = ws + o; o += 16*64*9*4;
    float* wqpk   = ws + o; o += 16*96*9*2;
    float* we1f   = ws + o; o += 3*49*32;
    float* we1c   = ws + o; o += 3*49*32;
    float* we2f   = ws + o; o += 32*9*32;
    float* we2c   = ws + o; o += 32*9*32;
    float* w3f    = ws + o; o += 32*32;
    float* w3c    = ws + o; o += 32*32;
    float* wat    = ws + o; o += 32*32;
    float* wbt    = ws + o; o += 32*32;
    float* wct    = ws + o; o += 32*32;
    float* wd1t   = ws + o; o += 32*9*64;
    float* disp1buf  = e1f;  // e1f dead after encoders (64*NP2 <= 32*NP1)
    float* disp2part = e1c;  // e1c dead after encoders

    // --- prep (one launch; zeroes stats) ---
    prep_all<<<(74816 + 255)/256, 256, 0, stream>>>(
        fnet_w1, cnet_w1, fnet_w2, cnet_w2, fnet_w3, cnet_w3,
        bform_a, bform_b, bform_cd_w, disp_w1, gru_wz, gru_wr, gru_wq,
        we1f, we1c, we2f, we2c, w3f, w3c, wat, wbt, wct, wd1t,
        (float4*)wzrpk, (float2*)wqpk, stats);

    // --- encoders (B=1: inorm == bnorm; norm+relu fused into consumers; stats fused into producers) ---
    conv7s2_dual<<<dim3(NP1/256, 4), 256, 0, stream>>>(image1, we1f, we1c, fnet_b1, cnet_b1,
                                                       e1f, e1c, stats+0, stats+64);
    conv3s2_fused<<<4*NBLK2, 256, 0, stream>>>(e1f, stats+0, we2f, fnet_b2, e2, stats+128);
    conv1x1_fused<<<4*NBLK2, 256, 0, stream>>>(e2, stats+128, w3f, fnet_b3, fmap1, 0);
    conv3s2_fused<<<4*NBLK2, 256, 0, stream>>>(e1c, stats+64, we2c, cnet_b2, e2, stats+192);
    conv1x1_fused<<<4*NBLK2, 256, 0, stream>>>(e2, stats+192, w3c, cnet_b3, hidden, 1);
    conv7s2_v3<<<dim3(NP1/256, 2), 256, 0, stream>>>(image2, we1f, fnet_b1, e1f, stats+256);
    conv3s2_fused<<<4*NBLK2, 256, 0, stream>>>(e1f, stats+256, we2f, fnet_b2, e2, stats+320);
    conv1x1_fused<<<4*NBLK2, 256, 0, stream>>>(e2, stats+320, w3f, fnet_b3, fmap2, 0);

    // --- padded working buffers ---
    zero_buf_kernel<<<2048, 256, 0, stream>>>(hwork1, 5*PCHW);  // hwork1..hfinal contiguous
    pad_init_kernel<<<(32*PSL+255)/256, 256, 0, stream>>>(hidden, hwork0);
    feat0_pad_kernel<<<4*NBLK2, 256, 0, stream>>>(fmap1, fmap2, wat, wbt, wct,
                                                  bform_cd_b, feat0);

    // --- sequential GRU sweep: 2 launches per iteration, 3-job pass-split ---
    float* hwA = hwork0; float* hwB = hwork1;
    float* ftA = feat0;  float* ftB = feat1;
    for (int d = 0; d < ND; ++d) {
        int Wd = W2 - d;
        int nblk = (48*Wd + 255)/256;
        zrq_a<<<dim3(nblk, 48), 256, 0, stream>>>(hwA, ftA, fmap1, fmap2,
                                                  (const float4*)wzrpk, (const float2*)wqpk,
                                                  wat, wbt, wct, bform_cd_b,
                                                  gru_bz, gru_br, zbuf, rhpad, ftB,
                                                  qpartA, qpartB, d, Wd);
        q_fin<<<dim3(nblk, 16), 256, 0, stream>>>(rhpad, hwA, zbuf, qpartA, qpartB,
                                                  (const float2*)wqpk, gru_bq,
                                                  hfinal, hwB, d, Wd);
        float* t;
        t = hwA; hwA = hwB; hwB = t;
        t = ftA; ftA = ftB; ftB = t;
    }

    // --- disparity head (reads padded hfinal) ---
    disp1_v6<<<dim3(30, 16), 256, 0, stream>>>(hfinal, wd1t, disp_b1, disp1buf);
    disp2_part_kernel<<<8*NBLK2, 256, 0, stream>>>(disp1buf, disp_w2, disp2part);
    disp2_comb_kernel<<<NBLK2, 256, 0, stream>>>(disp2part, disp_b2, (float*)d_out);
}

// Round 17
// 2843.466 us; speedup vs baseline: 1.4128x; 1.4128x over previous
//
#include <hip/hip_runtime.h>
#include <math.h>

#define H0 384
#define W0 640
#define H1 192
#define W1 320
#define H2 96
#define W2 160
#define NP1 (H1*W1)   /* 61440 */
#define NP2 (H2*W2)   /* 15360 */
#define ND  48        /* MAX_DISP/4 */
#define NBLK2 (NP2/256)  /* 60 */
#define CHW ((size_t)32*NP2)
/* padded (halo=1) layout, global coords */
#define PW 162
#define PH 98
#define PSL (PH*PW)            /* 15876 */
#define PCHW ((size_t)32*PSL)  /* 508032 */

typedef float v2f __attribute__((ext_vector_type(2)));

// ---------------- generic prep ----------------

__global__ void zero_buf_kernel(float* __restrict__ p, size_t n) {
    size_t i = (size_t)blockIdx.x*256 + threadIdx.x;
    size_t stride = (size_t)gridDim.x*256;
    for (; i < n; i += stride) p[i] = 0.f;
}

__device__ __forceinline__ void twr_dev(const float* __restrict__ in, float* __restrict__ out,
                                        int idx, int CI, int K, int CO) {
    int co = idx % CO;
    int t  = idx / CO;
    int k  = t % K;
    int ci = t / K;
    out[idx] = in[(co*CI + ci)*K + k];
}

// single launch: all weight transposes + packs + stats zero (74816 items)
__global__ void prep_all(const float* __restrict__ fnet_w1, const float* __restrict__ cnet_w1,
                         const float* __restrict__ fnet_w2, const float* __restrict__ cnet_w2,
                         const float* __restrict__ fnet_w3, const float* __restrict__ cnet_w3,
                         const float* __restrict__ bform_a, const float* __restrict__ bform_b,
                         const float* __restrict__ bform_cd_w, const float* __restrict__ disp_w1,
                         const float* __restrict__ gru_wz, const float* __restrict__ gru_wr,
                         const float* __restrict__ gru_wq,
                         float* __restrict__ we1f, float* __restrict__ we1c,
                         float* __restrict__ we2f, float* __restrict__ we2c,
                         float* __restrict__ w3f, float* __restrict__ w3c,
                         float* __restrict__ wat, float* __restrict__ wbt,
                         float* __restrict__ wct, float* __restrict__ wd1t,
                         float4* __restrict__ wzrpk, float2* __restrict__ wqpk,
                         float* __restrict__ stats) {
    int i = blockIdx.x*256 + threadIdx.x;
    if (i < 4704) { twr_dev(fnet_w1, we1f, i, 3, 49, 32); return; }
    i -= 4704;
    if (i < 4704) { twr_dev(cnet_w1, we1c, i, 3, 49, 32); return; }
    i -= 4704;
    if (i < 9216) { twr_dev(fnet_w2, we2f, i, 32, 9, 32); return; }
    i -= 9216;
    if (i < 9216) { twr_dev(cnet_w2, we2c, i, 32, 9, 32); return; }
    i -= 9216;
    if (i < 1024) { twr_dev(fnet_w3, w3f, i, 32, 1, 32); return; }
    i -= 1024;
    if (i < 1024) { twr_dev(cnet_w3, w3c, i, 32, 1, 32); return; }
    i -= 1024;
    if (i < 1024) { twr_dev(bform_a, wat, i, 32, 1, 32); return; }
    i -= 1024;
    if (i < 1024) { twr_dev(bform_b, wbt, i, 32, 1, 32); return; }
    i -= 1024;
    if (i < 1024) { twr_dev(bform_cd_w, wct, i, 32, 1, 32); return; }
    i -= 1024;
    if (i < 18432) { twr_dev(disp_w1, wd1t, i, 32, 9, 64); return; }
    i -= 18432;
    if (i < 9216) {   // packed z/r: [cg][ci<64][k] = {z0,z1,r0,r1}
        int k  = i % 9;
        int ci = (i/9) % 64;
        int cg = i / (9*64);
        int co0 = cg*2, co1 = co0 + 1;
        float z0, z1, r0, r1;
        if (ci < 32) {
            z0 = gru_wz[(co0*96 + ci)*9 + k] + gru_wz[(co0*96 + ci + 32)*9 + k];
            z1 = gru_wz[(co1*96 + ci)*9 + k] + gru_wz[(co1*96 + ci + 32)*9 + k];
            r0 = gru_wr[(co0*96 + ci)*9 + k] + gru_wr[(co0*96 + ci + 32)*9 + k];
            r1 = gru_wr[(co1*96 + ci)*9 + k] + gru_wr[(co1*96 + ci + 32)*9 + k];
        } else {
            z0 = gru_wz[(co0*96 + ci + 32)*9 + k];
            z1 = gru_wz[(co1*96 + ci + 32)*9 + k];
            r0 = gru_wr[(co0*96 + ci + 32)*9 + k];
            r1 = gru_wr[(co1*96 + ci + 32)*9 + k];
        }
        wzrpk[i] = make_float4(z0, z1, r0, r1);
        return;
    }
    i -= 9216;
    if (i < 13824) {  // packed q: [cg][ci<96][k] = {co0, co1}
        int k  = i % 9;
        int ci = (i/9) % 96;
        int cg = i / (9*96);
        wqpk[i] = make_float2(gru_wq[((cg*2)*96 + ci)*9 + k], gru_wq[((cg*2+1)*96 + ci)*9 + k]);
        return;
    }
    i -= 13824;
    if (i < 384) stats[i] = 0.f;
}

// hwork[c][py][px] = hidden[c][py-1][px-1] interior, 0 halo
__global__ void pad_init_kernel(const float* __restrict__ hidden, float* __restrict__ hwork) {
    int idx = blockIdx.x*256 + threadIdx.x;
    if (idx >= 32*PSL) return;
    int c = idx / PSL;
    int r = idx % PSL;
    int py = r / PW, px = r % PW;
    int y = py - 1, x = px - 1;
    float v = 0.f;
    if ((unsigned)y < (unsigned)H2 && (unsigned)x < (unsigned)W2)
        v = hidden[c*NP2 + y*W2 + x];
    hwork[idx] = v;
}

// ---------------- encoder kernels ----------------

// 7x7 s2, image1: fnet AND cnet in one pass (shared taps); grid dim3(240, 4); 8 co each net
__global__ __launch_bounds__(256, 4)
void conv7s2_dual(const float* __restrict__ img,
                  const float* __restrict__ wtf, const float* __restrict__ wtc,
                  const float* __restrict__ bf, const float* __restrict__ bc,
                  float* __restrict__ outf, float* __restrict__ outc) {
    int co8 = blockIdx.y*8;
    int sp = blockIdx.x*256 + threadIdx.x;
    int oy = sp / W1, ox = sp % W1;
    float af[8], ac[8];
    #pragma unroll
    for (int j = 0; j < 8; ++j) { af[j] = bf[co8+j]; ac[j] = bc[co8+j]; }
    for (int ci = 0; ci < 3; ++ci) {
        for (int ky = 0; ky < 7; ++ky) {
            int iy = 2*oy - 3 + ky;
            if ((unsigned)iy >= (unsigned)H0) continue;
            const float* row  = img + ci*(H0*W0) + iy*W0;
            int wbase = (ci*49 + ky*7)*32 + co8;
            #pragma unroll
            for (int kx = 0; kx < 7; ++kx) {
                int ix = 2*ox - 3 + kx;
                if ((unsigned)ix >= (unsigned)W0) continue;
                float v = row[ix]*(2.0f/255.0f) - 1.0f;
                const float4* wpf = (const float4*)(wtf + wbase + kx*32);
                const float4* wpc = (const float4*)(wtc + wbase + kx*32);
                float4 f0 = wpf[0], f1 = wpf[1];
                float4 c0 = wpc[0], c1 = wpc[1];
                af[0] += v*f0.x; af[1] += v*f0.y; af[2] += v*f0.z; af[3] += v*f0.w;
                af[4] += v*f1.x; af[5] += v*f1.y; af[6] += v*f1.z; af[7] += v*f1.w;
                ac[0] += v*c0.x; ac[1] += v*c0.y; ac[2] += v*c0.z; ac[3] += v*c0.w;
                ac[4] += v*c1.x; ac[5] += v*c1.y; ac[6] += v*c1.z; ac[7] += v*c1.w;
            }
        }
    }
    #pragma unroll
    for (int j = 0; j < 8; ++j) {
        outf[(co8+j)*NP1 + sp] = af[j];
        outc[(co8+j)*NP1 + sp] = ac[j];
    }
}

// 7x7 s2, single net (image2): grid dim3(240, 2); thread: 1 px, 16 co
__global__ void conv7s2_v3(const float* __restrict__ img, const float* __restrict__ wt,
                           const float* __restrict__ b, float* __restrict__ out) {
    int cg = blockIdx.y;
    int co16 = cg*16;
    int sp = blockIdx.x*256 + threadIdx.x;
    int oy = sp / W1, ox = sp % W1;
    float acc[16];
    #pragma unroll
    for (int j = 0; j < 16; ++j) acc[j] = b[co16+j];
    for (int ci = 0; ci < 3; ++ci) {
        for (int ky = 0; ky < 7; ++ky) {
            int iy = 2*oy - 3 + ky;
            if ((unsigned)iy >= (unsigned)H0) continue;
            const float* row  = img + ci*(H0*W0) + iy*W0;
            const float* wrow = wt + (ci*49 + ky*7)*32 + co16;
            #pragma unroll
            for (int kx = 0; kx < 7; ++kx) {
                int ix = 2*ox - 3 + kx;
                if ((unsigned)ix >= (unsigned)W0) continue;
                float v = row[ix]*(2.0f/255.0f) - 1.0f;
                const float4* wp = (const float4*)(wrow + kx*32);
                #pragma unroll
                for (int j4 = 0; j4 < 4; ++j4) {
                    float4 w4 = wp[j4];
                    acc[4*j4+0] += v*w4.x; acc[4*j4+1] += v*w4.y;
                    acc[4*j4+2] += v*w4.z; acc[4*j4+3] += v*w4.w;
                }
            }
        }
    }
    #pragma unroll
    for (int j = 0; j < 16; ++j) out[(co16+j)*NP1 + sp] = acc[j];
}

__global__ void stats_partial_kernel(const float* __restrict__ x, int N, float* __restrict__ st) {
    int c = blockIdx.x >> 3, sl = blockIdx.x & 7;
    int chunk = N >> 3;
    const float4* p = (const float4*)(x + (size_t)c*N + (size_t)sl*chunk);
    int n4 = chunk >> 2;
    float s = 0.f, s2 = 0.f;
    for (int i = threadIdx.x; i < n4; i += 256) {
        float4 v = p[i];
        s  += v.x + v.y + v.z + v.w;
        s2 += v.x*v.x + v.y*v.y + v.z*v.z + v.w*v.w;
    }
    __shared__ float sh1[256], sh2[256];
    sh1[threadIdx.x] = s; sh2[threadIdx.x] = s2;
    __syncthreads();
    for (int o = 128; o > 0; o >>= 1) {
        if (threadIdx.x < o) { sh1[threadIdx.x] += sh1[threadIdx.x+o]; sh2[threadIdx.x] += sh2[threadIdx.x+o]; }
        __syncthreads();
    }
    if (threadIdx.x == 0) { atomicAdd(&st[2*c], sh1[0]); atomicAdd(&st[2*c+1], sh2[0]); }
}

// 3x3 s2 with fused input instance-norm+relu; grid 4*NBLK2; thread: 1 px, 8 co
__global__ void conv3s2_fused(const float* __restrict__ in, const float* __restrict__ st,
                              const float* __restrict__ wt, const float* __restrict__ b,
                              float* __restrict__ out) {
    int cg = blockIdx.x / NBLK2;
    int sp = (blockIdx.x % NBLK2)*256 + threadIdx.x;
    int co8 = cg*8;
    int oy = sp / W2, ox = sp % W2;
    float acc[8];
    #pragma unroll
    for (int j = 0; j < 8; ++j) acc[j] = b[co8+j];
    for (int ci = 0; ci < 32; ++ci) {
        float m    = st[2*ci] * (1.0f/NP1);
        float var  = st[2*ci+1] * (1.0f/NP1) - m*m;
        float rstd = rsqrtf(var + 1e-5f);
        const float* ip  = in + ci*NP1;
        const float* wci = wt + ci*9*32 + co8;
        #pragma unroll
        for (int ky = 0; ky < 3; ++ky) {
            int iy = 2*oy - 1 + ky;
            if ((unsigned)iy >= (unsigned)H1) continue;
            const float* row = ip + iy*W1;
            #pragma unroll
            for (int kx = 0; kx < 3; ++kx) {
                int ix = 2*ox - 1 + kx;
                if ((unsigned)ix >= (unsigned)W1) continue;
                float t = fmaxf((row[ix] - m)*rstd, 0.f);
                const float4* wp = (const float4*)(wci + (ky*3+kx)*32);
                float4 w0 = wp[0], w1 = wp[1];
                acc[0] += t*w0.x; acc[1] += t*w0.y; acc[2] += t*w0.z; acc[3] += t*w0.w;
                acc[4] += t*w1.x; acc[5] += t*w1.y; acc[6] += t*w1.z; acc[7] += t*w1.w;
            }
        }
    }
    #pragma unroll
    for (int j = 0; j < 8; ++j) out[(co8+j)*NP2 + sp] = acc[j];
}

// 1x1 with fused input instance-norm+relu; grid 4*NBLK2; thread: 1 px, 8 co; optional tanh
__global__ void conv1x1_fused(const float* __restrict__ in, const float* __restrict__ st,
                              const float* __restrict__ wt, const float* __restrict__ b,
                              float* __restrict__ out, int mode) {
    int cg = blockIdx.x / NBLK2;
    int sp = (blockIdx.x % NBLK2)*256 + threadIdx.x;
    int co8 = cg*8;
    float acc[8];
    #pragma unroll
    for (int j = 0; j < 8; ++j) acc[j] = b[co8+j];
    for (int ci = 0; ci < 32; ++ci) {
        float m    = st[2*ci] * (1.0f/NP2);
        float var  = st[2*ci+1] * (1.0f/NP2) - m*m;
        float rstd = rsqrtf(var + 1e-5f);
        float t = fmaxf((in[ci*NP2 + sp] - m)*rstd, 0.f);
        const float4* wp = (const float4*)(wt + ci*32 + co8);
        float4 w0 = wp[0], w1 = wp[1];
        acc[0] += t*w0.x; acc[1] += t*w0.y; acc[2] += t*w0.z; acc[3] += t*w0.w;
        acc[4] += t*w1.x; acc[5] += t*w1.y; acc[6] += t*w1.z; acc[7] += t*w1.w;
    }
    #pragma unroll
    for (int j = 0; j < 8; ++j) {
        float a = acc[j];
        if (mode) a = tanhf(a);
        out[(co8+j)*NP2 + sp] = a;
    }
}

// ---------------- feat(0) prologue (padded) ----------------

__global__ void feat0_pad_kernel(const float* __restrict__ fmap1, const float* __restrict__ fmap2,
                                 const float* __restrict__ wat, const float* __restrict__ wbt,
                                 const float* __restrict__ wct, const float* __restrict__ bc,
                                 float* __restrict__ featA) {
    int cg  = blockIdx.x / NBLK2;
    int sp  = (blockIdx.x % NBLK2)*256 + threadIdx.x;
    int y = sp / W2;
    int gx = sp % W2;
    int co8 = cg*8;
    float acc[8];
    #pragma unroll
    for (int j = 0; j < 8; ++j) acc[j] = bc[co8+j];
    for (int ci = 0; ci < 32; ++ci) {
        float f1 = fmap1[ci*NP2 + sp];
        float f2 = fmap2[ci*NP2 + sp];
        float f12 = f1*f2;
        const float4* ap = (const float4*)(wat + ci*32 + co8);
        const float4* bp = (const float4*)(wbt + ci*32 + co8);
        const float4* cp = (const float4*)(wct + ci*32 + co8);
        float4 a0 = ap[0], a1 = ap[1];
        float4 b0 = bp[0], b1 = bp[1];
        float4 c0 = cp[0], c1 = cp[1];
        acc[0] += f1*a0.x + f2*b0.x + f12*c0.x;
        acc[1] += f1*a0.y + f2*b0.y + f12*c0.y;
        acc[2] += f1*a0.z + f2*b0.z + f12*c0.z;
        acc[3] += f1*a0.w + f2*b0.w + f12*c0.w;
        acc[4] += f1*a1.x + f2*b1.x + f12*c1.x;
        acc[5] += f1*a1.y + f2*b1.y + f12*c1.y;
        acc[6] += f1*a1.z + f2*b1.z + f12*c1.z;
        acc[7] += f1*a1.w + f2*b1.w + f12*c1.w;
    }
    float* dst = featA + (size_t)(y+1)*PW + (gx+1);
    #pragma unroll
    for (int j = 0; j < 8; ++j) dst[(size_t)(co8+j)*PSL] = acc[j];
}

// ---------------- GRU loop kernels (compact-column domain, 3-job split) ----------------
// grid dim3(nblk, 48): blockIdx.y = cg*3 + job.
//   job0: full z/r conv (zbuf, rhpad, rhpad zero col)
//   job1: feat(d+1) -> featB; q-partial over hworkA (wq ci 32..63) -> qpartA
//   job2: q-partial over featA (wq ci 64..95) -> qpartB

__global__ __launch_bounds__(256, 4)
void zrq_a(const float* __restrict__ hworkA, const float* __restrict__ featA,
           const float* __restrict__ fmap1, const float* __restrict__ fmap2,
           const float4* __restrict__ wzrpk, const float2* __restrict__ wqpk,
           const float* __restrict__ wat, const float* __restrict__ wbt,
           const float* __restrict__ wct, const float* __restrict__ bfc,
           const float* __restrict__ bz, const float* __restrict__ br,
           float* __restrict__ zbuf, float* __restrict__ rhpad,
           float* __restrict__ featB, float* __restrict__ qpartA,
           float* __restrict__ qpartB, int d, int Wd) {
    __shared__ v2f lws[1152];
    __shared__ v2f lfa[32], lfb[32], lfc[32];
    int cg  = blockIdx.y / 3;
    int job = blockIdx.y - cg*3;
    int co0 = cg*2;
    if (job == 0) {
        const float4* wsrc = wzrpk + (size_t)cg*576;
        for (int i = threadIdx.x; i < 576; i += 256) {
            float4 w = wsrc[i];
            lws[i]       = (v2f){w.x, w.y};   // z
            lws[576 + i] = (v2f){w.z, w.w};   // r
        }
    } else if (job == 1) {
        const float2* wsrc = wqpk + (size_t)cg*864 + 288;   // wq ci 32..63
        for (int i = threadIdx.x; i < 288; i += 256) {
            float2 w = wsrc[i];
            lws[i] = (v2f){w.x, w.y};
        }
        if (threadIdx.x < 32) {
            int ci = threadIdx.x;
            lfa[ci] = (v2f){wat[ci*32+co0], wat[ci*32+co0+1]};
            lfb[ci] = (v2f){wbt[ci*32+co0], wbt[ci*32+co0+1]};
            lfc[ci] = (v2f){wct[ci*32+co0], wct[ci*32+co0+1]};
        }
    } else {
        const float2* wsrc = wqpk + (size_t)cg*864 + 576;   // wq ci 64..95
        for (int i = threadIdx.x; i < 288; i += 256) {
            float2 w = wsrc[i];
            lws[i] = (v2f){w.x, w.y};
        }
    }
    __syncthreads();
    int sp2 = blockIdx.x*256 + threadIdx.x;
    if (sp2 >= 48*Wd) return;
    int rp = sp2 / Wd;
    int lx = sp2 - rp*Wd;
    int y0 = rp*2;
    int gx = d + lx;
    size_t poff = (size_t)(y0+1)*PW + (gx+1);
    int ub = y0*W2 + gx;

    if (job == 0) {
        // marching zero col for rhpad (left pad of this iteration's q conv)
        if (lx == 0) {
            #pragma unroll
            for (int j = 0; j < 2; ++j) {
                rhpad[(size_t)(co0+j)*PSL + poff - 1]      = 0.f;
                rhpad[(size_t)(co0+j)*PSL + poff + PW - 1] = 0.f;
            }
        }
        // z/r conv: pass 0 = hworkA (ci 0..31), pass 1 = featA (ci 32..63)
        v2f az0 = (v2f){bz[co0], bz[co0+1]}, az1 = az0;
        v2f ar0 = (v2f){br[co0], br[co0+1]}, ar1 = ar0;
        #pragma unroll
        for (int pass = 0; pass < 2; ++pass) {
            const float* p = (pass == 0 ? hworkA : featA) + poff;
            const v2f* wz = lws + pass*288;
            const v2f* wr = lws + 576 + pass*288;
            #pragma unroll 2
            for (int ci = 0; ci < 32; ++ci) {
                float v[12];
                #pragma unroll
                for (int r = 0; r < 4; ++r) {
                    v[r*3+0] = p[(r-1)*PW - 1];
                    v[r*3+1] = p[(r-1)*PW    ];
                    v[r*3+2] = p[(r-1)*PW + 1];
                }
                #pragma unroll
                for (int k = 0; k < 9; ++k) {
                    int ky = k/3, kx = k - 3*ky;
                    float t0 = v[ky*3+kx];
                    float t1 = v[(ky+1)*3+kx];
                    v2f wzk = wz[k], wrk = wr[k];
                    az0 += wzk*(v2f){t0,t0}; az1 += wzk*(v2f){t1,t1};
                    ar0 += wrk*(v2f){t0,t0}; ar1 += wrk*(v2f){t1,t1};
                }
                p += PSL;
                wz += 9; wr += 9;
            }
        }
        v2f z0, z1, r0, r1;
        z0.x = 1.f/(1.f + __expf(-az0.x)); z0.y = 1.f/(1.f + __expf(-az0.y));
        z1.x = 1.f/(1.f + __expf(-az1.x)); z1.y = 1.f/(1.f + __expf(-az1.y));
        r0.x = 1.f/(1.f + __expf(-ar0.x)); r0.y = 1.f/(1.f + __expf(-ar0.y));
        r1.x = 1.f/(1.f + __expf(-ar1.x)); r1.y = 1.f/(1.f + __expf(-ar1.y));
        float h00 = hworkA[(size_t)co0*PSL + poff];
        float h01 = hworkA[(size_t)(co0+1)*PSL + poff];
        float h10 = hworkA[(size_t)co0*PSL + poff + PW];
        float h11 = hworkA[(size_t)(co0+1)*PSL + poff + PW];
        zbuf[(size_t)co0*NP2 + ub]          = z0.x;
        zbuf[(size_t)(co0+1)*NP2 + ub]      = z0.y;
        zbuf[(size_t)co0*NP2 + ub + W2]     = z1.x;
        zbuf[(size_t)(co0+1)*NP2 + ub + W2] = z1.y;
        rhpad[(size_t)co0*PSL + poff]          = r0.x*h00;
        rhpad[(size_t)(co0+1)*PSL + poff]      = r0.y*h01;
        rhpad[(size_t)co0*PSL + poff + PW]     = r1.x*h10;
        rhpad[(size_t)(co0+1)*PSL + poff + PW] = r1.y*h11;
    } else if (job == 1) {
        // feat(d+1) -> featB; col d (lx==0) is its left-halo zero col
        int dn = d + 1;
        if (dn < ND) {
            if (lx == 0) {
                #pragma unroll
                for (int j = 0; j < 2; ++j) {
                    featB[(size_t)(co0+j)*PSL + poff]      = 0.f;
                    featB[(size_t)(co0+j)*PSL + poff + PW] = 0.f;
                }
            } else {
                v2f f0 = (v2f){bfc[co0], bfc[co0+1]};
                v2f f1 = f0;
                int base1 = y0*W2 + gx;
                #pragma unroll 2
                for (int ci = 0; ci < 32; ++ci) {
                    float a1 = fmap1[ci*NP2 + base1];
                    float a2 = fmap1[ci*NP2 + base1 + W2];
                    float b1 = fmap2[ci*NP2 + base1 - dn];
                    float b2 = fmap2[ci*NP2 + base1 + W2 - dn];
                    v2f wa = lfa[ci], wb = lfb[ci], wc = lfc[ci];
                    f0 += wa*(v2f){a1,a1} + wb*(v2f){b1,b1} + wc*(v2f){a1*b1,a1*b1};
                    f1 += wa*(v2f){a2,a2} + wb*(v2f){b2,b2} + wc*(v2f){a2*b2,a2*b2};
                }
                featB[(size_t)co0*PSL + poff]          = f0.x;
                featB[(size_t)(co0+1)*PSL + poff]      = f0.y;
                featB[(size_t)co0*PSL + poff + PW]     = f1.x;
                featB[(size_t)(co0+1)*PSL + poff + PW] = f1.y;
            }
        }
        // q partial A: hworkA with wq ci 32..63
        v2f a0 = (v2f){0.f, 0.f};
        v2f a1 = a0;
        {
            const float* p = hworkA + poff;
            const v2f* wp = lws;
            #pragma unroll 2
            for (int ci = 0; ci < 32; ++ci) {
                float v[12];
                #pragma unroll
                for (int r = 0; r < 4; ++r) {
                    v[r*3+0] = p[(r-1)*PW - 1];
                    v[r*3+1] = p[(r-1)*PW    ];
                    v[r*3+2] = p[(r-1)*PW + 1];
                }
                #pragma unroll
                for (int k = 0; k < 9; ++k) {
                    int ky = k/3, kx = k - 3*ky;
                    float t0 = v[ky*3+kx];
                    float t1 = v[(ky+1)*3+kx];
                    v2f wk = wp[k];
                    a0 += wk*(v2f){t0,t0};
                    a1 += wk*(v2f){t1,t1};
                }
                p += PSL;
                wp += 9;
            }
        }
        qpartA[(size_t)co0*NP2 + ub]          = a0.x;
        qpartA[(size_t)(co0+1)*NP2 + ub]      = a0.y;
        qpartA[(size_t)co0*NP2 + ub + W2]     = a1.x;
        qpartA[(size_t)(co0+1)*NP2 + ub + W2] = a1.y;
    } else {
        // q partial B: featA with wq ci 64..95
        v2f a0 = (v2f){0.f, 0.f};
        v2f a1 = a0;
        {
            const float* p = featA + poff;
            const v2f* wp = lws;
            #pragma unroll 2
            for (int ci = 0; ci < 32; ++ci) {
                float v[12];
                #pragma unroll
                for (int r = 0; r < 4; ++r) {
                    v[r*3+0] = p[(r-1)*PW - 1];
                    v[r*3+1] = p[(r-1)*PW    ];
                    v[r*3+2] = p[(r-1)*PW + 1];
                }
                #pragma unroll
                for (int k = 0; k < 9; ++k) {
                    int ky = k/3, kx = k - 3*ky;
                    float t0 = v[ky*3+kx];
                    float t1 = v[(ky+1)*3+kx];
                    v2f wk = wp[k];
                    a0 += wk*(v2f){t0,t0};
                    a1 += wk*(v2f){t1,t1};
                }
                p += PSL;
                wp += 9;
            }
        }
        qpartB[(size_t)co0*NP2 + ub]          = a0.x;
        qpartB[(size_t)(co0+1)*NP2 + ub]      = a0.y;
        qpartB[(size_t)co0*NP2 + ub + W2]     = a1.x;
        qpartB[(size_t)(co0+1)*NP2 + ub + W2] = a1.y;
    }
}

// q_fin: q's rh-pass (wq ci 0..31) + qpartA + qpartB + bias -> tanh -> GRU update.
// grid dim3(nblk, 16)
__global__ __launch_bounds__(256, 4)
void q_fin(const float* __restrict__ rhpad, const float* __restrict__ hworkA,
           const float* __restrict__ zbuf, const float* __restrict__ qpartA,
           const float* __restrict__ qpartB,
           const float2* __restrict__ wqpk, const float* __restrict__ bq,
           float* __restrict__ hfinal, float* __restrict__ hworkB, int d, int Wd) {
    __shared__ v2f lw[288];
    int cg  = blockIdx.y;
    int co0 = cg*2;
    {
        const float2* wsrc = wqpk + (size_t)cg*864;   // wq ci 0..31
        for (int i = threadIdx.x; i < 288; i += 256) {
            float2 w = wsrc[i];
            lw[i] = (v2f){w.x, w.y};
        }
    }
    __syncthreads();
    int sp2 = blockIdx.x*256 + threadIdx.x;
    if (sp2 >= 48*Wd) return;
    int rp = sp2 / Wd;
    int lx = sp2 - rp*Wd;
    int y0 = rp*2;
    int gx = d + lx;
    size_t poff = (size_t)(y0+1)*PW + (gx+1);
    int ub = y0*W2 + gx;

    v2f a0 = (v2f){bq[co0], bq[co0+1]};
    v2f a1 = a0;
    {
        const float* p = rhpad + poff;
        const v2f* wp = lw;
        #pragma unroll 2
        for (int ci = 0; ci < 32; ++ci) {
            float v[12];
            #pragma unroll
            for (int r = 0; r < 4; ++r) {
                v[r*3+0] = p[(r-1)*PW - 1];
                v[r*3+1] = p[(r-1)*PW    ];
                v[r*3+2] = p[(r-1)*PW + 1];
            }
            #pragma unroll
            for (int k = 0; k < 9; ++k) {
                int ky = k/3, kx = k - 3*ky;
                float t0 = v[ky*3+kx];
                float t1 = v[(ky+1)*3+kx];
                v2f wk = wp[k];
                a0 += wk*(v2f){t0,t0};
                a1 += wk*(v2f){t1,t1};
            }
            p += PSL;
            wp += 9;
        }
    }
    a0.x += qpartA[(size_t)co0*NP2 + ub]          + qpartB[(size_t)co0*NP2 + ub];
    a0.y += qpartA[(size_t)(co0+1)*NP2 + ub]      + qpartB[(size_t)(co0+1)*NP2 + ub];
    a1.x += qpartA[(size_t)co0*NP2 + ub + W2]     + qpartB[(size_t)co0*NP2 + ub + W2];
    a1.y += qpartA[(size_t)(co0+1)*NP2 + ub + W2] + qpartB[(size_t)(co0+1)*NP2 + ub + W2];
    float q00 = tanhf(a0.x), q01 = tanhf(a0.y);
    float q10 = tanhf(a1.x), q11 = tanhf(a1.y);
    #pragma unroll
    for (int j = 0; j < 2; ++j) {
        float qa = (j == 0) ? q00 : q01;
        float qb = (j == 0) ? q10 : q11;
        size_t pidx = (size_t)(co0+j)*PSL + poff;
        size_t uidx = (size_t)(co0+j)*NP2 + ub;
        float z_a = zbuf[uidx];
        float z_b = zbuf[uidx + W2];
        float h_a = hworkA[pidx];
        float h_b = hworkA[pidx + PW];
        float hn_a = (1.f - z_a)*h_a + z_a*qa;
        float hn_b = (1.f - z_b)*h_b + z_b*qb;
        if (lx == 0 || d == ND-1) {
            hfinal[pidx]      = hn_a;
            hfinal[pidx + PW] = hn_b;
        }
        hworkB[pidx]      = (lx == 0) ? 0.f : hn_a;
        hworkB[pidx + PW] = (lx == 0) ? 0.f : hn_b;
    }
}

// ---------------- disparity head ----------------

// 3x3 conv 32->64 + relu on padded hfinal; grid dim3(30, 16); thread: 2 rows x 4 co
__global__ __launch_bounds__(256, 4)
void disp1_v6(const float* __restrict__ hfinal, const float* __restrict__ wt,
              const float* __restrict__ b, float* __restrict__ out) {
    __shared__ float4 lw[288];   // [ci*9+k] -> 4 co weights
    int cg  = blockIdx.y;
    int co0 = cg*4;
    for (int i = threadIdx.x; i < 288; i += 256)
        lw[i] = *(const float4*)&wt[i*64 + co0];
    __syncthreads();
    int sp2 = blockIdx.x*256 + threadIdx.x;   // 0..7679
    int y0 = (sp2 / W2)*2;
    int gx = sp2 % W2;
    size_t poff = (size_t)(y0+1)*PW + (gx+1);
    float4 bb = *(const float4*)&b[co0];
    float acc0[4] = {bb.x, bb.y, bb.z, bb.w};
    float acc1[4] = {bb.x, bb.y, bb.z, bb.w};
    const float* p = hfinal + poff;
    #pragma unroll 2
    for (int ci = 0; ci < 32; ++ci) {
        float v[12];
        #pragma unroll
        for (int r = 0; r < 4; ++r) {
            v[r*3+0] = p[(r-1)*PW - 1];
            v[r*3+1] = p[(r-1)*PW    ];
            v[r*3+2] = p[(r-1)*PW + 1];
        }
        #pragma unroll
        for (int k = 0; k < 9; ++k) {
            int ky = k/3, kx = k - 3*ky;
            float t0 = v[ky*3+kx];
            float t1 = v[(ky+1)*3+kx];
            float4 w = lw[ci*9+k];
            acc0[0] += t0*w.x; acc0[1] += t0*w.y; acc0[2] += t0*w.z; acc0[3] += t0*w.w;
            acc1[0] += t1*w.x; acc1[1] += t1*w.y; acc1[2] += t1*w.z; acc1[3] += t1*w.w;
        }
        p += PSL;
    }
    int ub = y0*W2 + gx;
    #pragma unroll
    for (int j = 0; j < 4; ++j) {
        out[(co0+j)*NP2 + ub]      = fmaxf(acc0[j], 0.f);
        out[(co0+j)*NP2 + ub + W2] = fmaxf(acc1[j], 0.f);
    }
}

__global__ void disp2_part_kernel(const float* __restrict__ in, const float* __restrict__ w,
                                  float* __restrict__ part) {
    __shared__ float lw[8*9];
    int g  = blockIdx.x / NBLK2;
    int sp = (blockIdx.x % NBLK2)*256 + threadIdx.x;
    if (threadIdx.x < 72) lw[threadIdx.x] = w[g*72 + threadIdx.x];
    __syncthreads();
    int y = sp / W2, x = sp % W2;
    float acc = 0.f;
    #pragma unroll
    for (int ci = 0; ci < 8; ++ci) {
        const float* ip = in + (g*8 + ci)*NP2;
        #pragma unroll
        for (int dy = 0; dy < 3; ++dy) {
            int ys = y+dy-1; if ((unsigned)ys >= (unsigned)H2) continue;
            const float* row = ip + ys*W2;
            #pragma unroll
            for (int dx = 0; dx < 3; ++dx) {
                int xs = x+dx-1; if ((unsigned)xs >= (unsigned)W2) continue;
                acc += lw[ci*9+dy*3+dx] * row[xs];
            }
        }
    }
    part[g*NP2 + sp] = acc;
}

__global__ void disp2_comb_kernel(const float* __restrict__ part, const float* __restrict__ b,
                                  float* __restrict__ out) {
    int sp = blockIdx.x*256 + threadIdx.x;
    float acc = b[0];
    #pragma unroll
    for (int g = 0; g < 8; ++g) acc += part[g*NP2 + sp];
    out[sp] = -acc;
}

// ---------------- launch ----------------

extern "C" void kernel_launch(void* const* d_in, const int* in_sizes, int n_in,
                              void* d_out, int out_size, void* d_ws, size_t ws_size,
                              hipStream_t stream) {
    const float* image1   = (const float*)d_in[0];
    const float* image2   = (const float*)d_in[1];
    const float* fnet_w1  = (const float*)d_in[2];
    const float* fnet_b1  = (const float*)d_in[3];
    const float* fnet_w2  = (const float*)d_in[4];
    const float* fnet_b2  = (const float*)d_in[5];
    const float* fnet_w3  = (const float*)d_in[6];
    const float* fnet_b3  = (const float*)d_in[7];
    const float* cnet_w1  = (const float*)d_in[8];
    const float* cnet_b1  = (const float*)d_in[9];
    const float* cnet_w2  = (const float*)d_in[10];
    const float* cnet_b2  = (const float*)d_in[11];
    const float* cnet_w3  = (const float*)d_in[12];
    const float* cnet_b3  = (const float*)d_in[13];
    const float* bform_a  = (const float*)d_in[14];
    const float* bform_b  = (const float*)d_in[15];
    const float* bform_cd_w = (const float*)d_in[16];
    const float* bform_cd_b = (const float*)d_in[17];
    const float* gru_wz   = (const float*)d_in[18];
    const float* gru_bz   = (const float*)d_in[19];
    const float* gru_wr   = (const float*)d_in[20];
    const float* gru_br   = (const float*)d_in[21];
    const float* gru_wq   = (const float*)d_in[22];
    const float* gru_bq   = (const float*)d_in[23];
    const float* disp_w1  = (const float*)d_in[24];
    const float* disp_b1  = (const float*)d_in[25];
    const float* disp_w2  = (const float*)d_in[26];
    const float* disp_b2  = (const float*)d_in[27];

    float* ws = (float*)d_ws;
    size_t o = 0;
    float* e1f    = ws + o; o += (size_t)32*NP1;
    float* e1c    = ws + o; o += (size_t)32*NP1;
    float* e2     = ws + o; o += CHW;
    float* fmap1  = ws + o; o += CHW;
    float* fmap2  = ws + o; o += CHW;
    float* hidden = ws + o; o += CHW;
    float* zbuf   = ws + o; o += CHW;
    float* qpartA = ws + o; o += CHW;
    float* qpartB = ws + o; o += CHW;
    float* hwork0 = ws + o; o += PCHW;
    /* the next 5 padded buffers are contiguous -> one zero_buf */
    float* hwork1 = ws + o; o += PCHW;
    float* rhpad  = ws + o; o += PCHW;
    float* feat0  = ws + o; o += PCHW;
    float* feat1  = ws + o; o += PCHW;
    float* hfinal = ws + o; o += PCHW;
    float* stats  = ws + o; o += 384;
    float* wzrpk  = ws + o; o += 16*64*9*4;
    float* wqpk   = ws + o; o += 16*96*9*2;
    float* we1f   = ws + o; o += 3*49*32;
    float* we1c   = ws + o; o += 3*49*32;
    float* we2f   = ws + o; o += 32*9*32;
    float* we2c   = ws + o; o += 32*9*32;
    float* w3f    = ws + o; o += 32*32;
    float* w3c    = ws + o; o += 32*32;
    float* wat    = ws + o; o += 32*32;
    float* wbt    = ws + o; o += 32*32;
    float* wct    = ws + o; o += 32*32;
    float* wd1t   = ws + o; o += 32*9*64;
    float* disp1buf  = e1f;  // e1f dead after encoders (64*NP2 <= 32*NP1)
    float* disp2part = e1c;  // e1c dead after encoders

    // --- prep (one launch; zeroes stats) ---
    prep_all<<<(74816 + 255)/256, 256, 0, stream>>>(
        fnet_w1, cnet_w1, fnet_w2, cnet_w2, fnet_w3, cnet_w3,
        bform_a, bform_b, bform_cd_w, disp_w1, gru_wz, gru_wr, gru_wq,
        we1f, we1c, we2f, we2c, w3f, w3c, wat, wbt, wct, wd1t,
        (float4*)wzrpk, (float2*)wqpk, stats);

    // --- encoders (B=1: inorm == bnorm; norm+relu fused into consumers) ---
    conv7s2_dual<<<dim3(NP1/256, 4), 256, 0, stream>>>(image1, we1f, we1c, fnet_b1, cnet_b1,
                                                       e1f, e1c);
    stats_partial_kernel<<<256, 256, 0, stream>>>(e1f, NP1, stats+0);
    stats_partial_kernel<<<256, 256, 0, stream>>>(e1c, NP1, stats+64);
    conv3s2_fused<<<4*NBLK2, 256, 0, stream>>>(e1f, stats+0, we2f, fnet_b2, e2);
    stats_partial_kernel<<<256, 256, 0, stream>>>(e2, NP2, stats+128);
    conv1x1_fused<<<4*NBLK2, 256, 0, stream>>>(e2, stats+128, w3f, fnet_b3, fmap1, 0);
    conv3s2_fused<<<4*NBLK2, 256, 0, stream>>>(e1c, stats+64, we2c, cnet_b2, e2);
    stats_partial_kernel<<<256, 256, 0, stream>>>(e2, NP2, stats+192);
    conv1x1_fused<<<4*NBLK2, 256, 0, stream>>>(e2, stats+192, w3c, cnet_b3, hidden, 1);
    conv7s2_v3<<<dim3(NP1/256, 2), 256, 0, stream>>>(image2, we1f, fnet_b1, e1f);
    stats_partial_kernel<<<256, 256, 0, stream>>>(e1f, NP1, stats+256);
    conv3s2_fused<<<4*NBLK2, 256, 0, stream>>>(e1f, stats+256, we2f, fnet_b2, e2);
    stats_partial_kernel<<<256, 256, 0, stream>>>(e2, NP2, stats+320);
    conv1x1_fused<<<4*NBLK2, 256, 0, stream>>>(e2, stats+320, w3f, fnet_b3, fmap2, 0);

    // --- padded working buffers ---
    zero_buf_kernel<<<2048, 256, 0, stream>>>(hwork1, 5*PCHW);  // hwork1..hfinal contiguous
    pad_init_kernel<<<(32*PSL+255)/256, 256, 0, stream>>>(hidden, hwork0);
    feat0_pad_kernel<<<4*NBLK2, 256, 0, stream>>>(fmap1, fmap2, wat, wbt, wct,
                                                  bform_cd_b, feat0);

    // --- sequential GRU sweep: 2 launches per iteration, 3-job pass-split ---
    float* hwA = hwork0; float* hwB = hwork1;
    float* ftA = feat0;  float* ftB = feat1;
    for (int d = 0; d < ND; ++d) {
        int Wd = W2 - d;
        int nblk = (48*Wd + 255)/256;
        zrq_a<<<dim3(nblk, 48), 256, 0, stream>>>(hwA, ftA, fmap1, fmap2,
                                                  (const float4*)wzrpk, (const float2*)wqpk,
                                                  wat, wbt, wct, bform_cd_b,
                                                  gru_bz, gru_br, zbuf, rhpad, ftB,
                                                  qpartA, qpartB, d, Wd);
        q_fin<<<dim3(nblk, 16), 256, 0, stream>>>(rhpad, hwA, zbuf, qpartA, qpartB,
                                                  (const float2*)wqpk, gru_bq,
                                                  hfinal, hwB, d, Wd);
        float* t;
        t = hwA; hwA = hwB; hwB = t;
        t = ftA; ftA = ftB; ftB = t;
    }

    // --- disparity head (reads padded hfinal) ---
    disp1_v6<<<dim3(30, 16), 256, 0, stream>>>(hfinal, wd1t, disp_b1, disp1buf);
    disp2_part_kernel<<<8*NBLK2, 256, 0, stream>>>(disp1buf, disp_w2, disp2part);
    disp2_comb_kernel<<<NBLK2, 256, 0, stream>>>(disp2part, disp_b2, (float*)d_out);
}

// Round 18
// 2683.935 us; speedup vs baseline: 1.4968x; 1.0594x over previous
//
#include <hip/hip_runtime.h>
#include <math.h>

#define H0 384
#define W0 640
#define H1 192
#define W1 320
#define H2 96
#define W2 160
#define NP1 (H1*W1)   /* 61440 */
#define NP2 (H2*W2)   /* 15360 */
#define ND  48        /* MAX_DISP/4 */
#define NBLK2 (NP2/256)  /* 60 */
#define CHW ((size_t)32*NP2)
/* padded (halo=1) layout, global coords */
#define PW 162
#define PH 98
#define PSL (PH*PW)            /* 15876 */
#define PCHW ((size_t)32*PSL)  /* 508032 */

typedef float v2f __attribute__((ext_vector_type(2)));

// ---------------- generic prep ----------------

__global__ void zero_buf_kernel(float* __restrict__ p, size_t n) {
    size_t i = (size_t)blockIdx.x*256 + threadIdx.x;
    size_t stride = (size_t)gridDim.x*256;
    for (; i < n; i += stride) p[i] = 0.f;
}

__device__ __forceinline__ void twr_dev(const float* __restrict__ in, float* __restrict__ out,
                                        int idx, int CI, int K, int CO) {
    int co = idx % CO;
    int t  = idx / CO;
    int k  = t % K;
    int ci = t / K;
    out[idx] = in[(co*CI + ci)*K + k];
}

// single launch: all weight transposes + packs + stats zero (74816 items)
__global__ void prep_all(const float* __restrict__ fnet_w1, const float* __restrict__ cnet_w1,
                         const float* __restrict__ fnet_w2, const float* __restrict__ cnet_w2,
                         const float* __restrict__ fnet_w3, const float* __restrict__ cnet_w3,
                         const float* __restrict__ bform_a, const float* __restrict__ bform_b,
                         const float* __restrict__ bform_cd_w, const float* __restrict__ disp_w1,
                         const float* __restrict__ gru_wz, const float* __restrict__ gru_wr,
                         const float* __restrict__ gru_wq,
                         float* __restrict__ we1f, float* __restrict__ we1c,
                         float* __restrict__ we2f, float* __restrict__ we2c,
                         float* __restrict__ w3f, float* __restrict__ w3c,
                         float* __restrict__ wat, float* __restrict__ wbt,
                         float* __restrict__ wct, float* __restrict__ wd1t,
                         float4* __restrict__ wzrpk, float2* __restrict__ wqpk,
                         float* __restrict__ stats) {
    int i = blockIdx.x*256 + threadIdx.x;
    if (i < 4704) { twr_dev(fnet_w1, we1f, i, 3, 49, 32); return; }
    i -= 4704;
    if (i < 4704) { twr_dev(cnet_w1, we1c, i, 3, 49, 32); return; }
    i -= 4704;
    if (i < 9216) { twr_dev(fnet_w2, we2f, i, 32, 9, 32); return; }
    i -= 9216;
    if (i < 9216) { twr_dev(cnet_w2, we2c, i, 32, 9, 32); return; }
    i -= 9216;
    if (i < 1024) { twr_dev(fnet_w3, w3f, i, 32, 1, 32); return; }
    i -= 1024;
    if (i < 1024) { twr_dev(cnet_w3, w3c, i, 32, 1, 32); return; }
    i -= 1024;
    if (i < 1024) { twr_dev(bform_a, wat, i, 32, 1, 32); return; }
    i -= 1024;
    if (i < 1024) { twr_dev(bform_b, wbt, i, 32, 1, 32); return; }
    i -= 1024;
    if (i < 1024) { twr_dev(bform_cd_w, wct, i, 32, 1, 32); return; }
    i -= 1024;
    if (i < 18432) { twr_dev(disp_w1, wd1t, i, 32, 9, 64); return; }
    i -= 18432;
    if (i < 9216) {   // packed z/r: [cg][ci<64][k] = {z0,z1,r0,r1}
        int k  = i % 9;
        int ci = (i/9) % 64;
        int cg = i / (9*64);
        int co0 = cg*2, co1 = co0 + 1;
        float z0, z1, r0, r1;
        if (ci < 32) {
            z0 = gru_wz[(co0*96 + ci)*9 + k] + gru_wz[(co0*96 + ci + 32)*9 + k];
            z1 = gru_wz[(co1*96 + ci)*9 + k] + gru_wz[(co1*96 + ci + 32)*9 + k];
            r0 = gru_wr[(co0*96 + ci)*9 + k] + gru_wr[(co0*96 + ci + 32)*9 + k];
            r1 = gru_wr[(co1*96 + ci)*9 + k] + gru_wr[(co1*96 + ci + 32)*9 + k];
        } else {
            z0 = gru_wz[(co0*96 + ci + 32)*9 + k];
            z1 = gru_wz[(co1*96 + ci + 32)*9 + k];
            r0 = gru_wr[(co0*96 + ci + 32)*9 + k];
            r1 = gru_wr[(co1*96 + ci + 32)*9 + k];
        }
        wzrpk[i] = make_float4(z0, z1, r0, r1);
        return;
    }
    i -= 9216;
    if (i < 13824) {  // packed q: [cg][ci<96][k] = {co0, co1}
        int k  = i % 9;
        int ci = (i/9) % 96;
        int cg = i / (9*96);
        wqpk[i] = make_float2(gru_wq[((cg*2)*96 + ci)*9 + k], gru_wq[((cg*2+1)*96 + ci)*9 + k]);
        return;
    }
    i -= 13824;
    if (i < 384) stats[i] = 0.f;
}

// hwork[c][py][px] = hidden[c][py-1][px-1] interior, 0 halo
__global__ void pad_init_kernel(const float* __restrict__ hidden, float* __restrict__ hwork) {
    int idx = blockIdx.x*256 + threadIdx.x;
    if (idx >= 32*PSL) return;
    int c = idx / PSL;
    int r = idx % PSL;
    int py = r / PW, px = r % PW;
    int y = py - 1, x = px - 1;
    float v = 0.f;
    if ((unsigned)y < (unsigned)H2 && (unsigned)x < (unsigned)W2)
        v = hidden[c*NP2 + y*W2 + x];
    hwork[idx] = v;
}

// ---------------- encoder kernels ----------------

// 7x7 s2, image1: fnet AND cnet in one pass (shared taps); grid dim3(240, 4); 8 co each net
__global__ __launch_bounds__(256, 4)
void conv7s2_dual(const float* __restrict__ img,
                  const float* __restrict__ wtf, const float* __restrict__ wtc,
                  const float* __restrict__ bf, const float* __restrict__ bc,
                  float* __restrict__ outf, float* __restrict__ outc) {
    int co8 = blockIdx.y*8;
    int sp = blockIdx.x*256 + threadIdx.x;
    int oy = sp / W1, ox = sp % W1;
    float af[8], ac[8];
    #pragma unroll
    for (int j = 0; j < 8; ++j) { af[j] = bf[co8+j]; ac[j] = bc[co8+j]; }
    for (int ci = 0; ci < 3; ++ci) {
        for (int ky = 0; ky < 7; ++ky) {
            int iy = 2*oy - 3 + ky;
            if ((unsigned)iy >= (unsigned)H0) continue;
            const float* row  = img + ci*(H0*W0) + iy*W0;
            int wbase = (ci*49 + ky*7)*32 + co8;
            #pragma unroll
            for (int kx = 0; kx < 7; ++kx) {
                int ix = 2*ox - 3 + kx;
                if ((unsigned)ix >= (unsigned)W0) continue;
                float v = row[ix]*(2.0f/255.0f) - 1.0f;
                const float4* wpf = (const float4*)(wtf + wbase + kx*32);
                const float4* wpc = (const float4*)(wtc + wbase + kx*32);
                float4 f0 = wpf[0], f1 = wpf[1];
                float4 c0 = wpc[0], c1 = wpc[1];
                af[0] += v*f0.x; af[1] += v*f0.y; af[2] += v*f0.z; af[3] += v*f0.w;
                af[4] += v*f1.x; af[5] += v*f1.y; af[6] += v*f1.z; af[7] += v*f1.w;
                ac[0] += v*c0.x; ac[1] += v*c0.y; ac[2] += v*c0.z; ac[3] += v*c0.w;
                ac[4] += v*c1.x; ac[5] += v*c1.y; ac[6] += v*c1.z; ac[7] += v*c1.w;
            }
        }
    }
    #pragma unroll
    for (int j = 0; j < 8; ++j) {
        outf[(co8+j)*NP1 + sp] = af[j];
        outc[(co8+j)*NP1 + sp] = ac[j];
    }
}

// 7x7 s2, single net (image2): grid dim3(240, 2); thread: 1 px, 16 co
__global__ void conv7s2_v3(const float* __restrict__ img, const float* __restrict__ wt,
                           const float* __restrict__ b, float* __restrict__ out) {
    int cg = blockIdx.y;
    int co16 = cg*16;
    int sp = blockIdx.x*256 + threadIdx.x;
    int oy = sp / W1, ox = sp % W1;
    float acc[16];
    #pragma unroll
    for (int j = 0; j < 16; ++j) acc[j] = b[co16+j];
    for (int ci = 0; ci < 3; ++ci) {
        for (int ky = 0; ky < 7; ++ky) {
            int iy = 2*oy - 3 + ky;
            if ((unsigned)iy >= (unsigned)H0) continue;
            const float* row  = img + ci*(H0*W0) + iy*W0;
            const float* wrow = wt + (ci*49 + ky*7)*32 + co16;
            #pragma unroll
            for (int kx = 0; kx < 7; ++kx) {
                int ix = 2*ox - 3 + kx;
                if ((unsigned)ix >= (unsigned)W0) continue;
                float v = row[ix]*(2.0f/255.0f) - 1.0f;
                const float4* wp = (const float4*)(wrow + kx*32);
                #pragma unroll
                for (int j4 = 0; j4 < 4; ++j4) {
                    float4 w4 = wp[j4];
                    acc[4*j4+0] += v*w4.x; acc[4*j4+1] += v*w4.y;
                    acc[4*j4+2] += v*w4.z; acc[4*j4+3] += v*w4.w;
                }
            }
        }
    }
    #pragma unroll
    for (int j = 0; j < 16; ++j) out[(co16+j)*NP1 + sp] = acc[j];
}

__global__ void stats_partial_kernel(const float* __restrict__ x, int N, float* __restrict__ st) {
    int c = blockIdx.x >> 3, sl = blockIdx.x & 7;
    int chunk = N >> 3;
    const float4* p = (const float4*)(x + (size_t)c*N + (size_t)sl*chunk);
    int n4 = chunk >> 2;
    float s = 0.f, s2 = 0.f;
    for (int i = threadIdx.x; i < n4; i += 256) {
        float4 v = p[i];
        s  += v.x + v.y + v.z + v.w;
        s2 += v.x*v.x + v.y*v.y + v.z*v.z + v.w*v.w;
    }
    __shared__ float sh1[256], sh2[256];
    sh1[threadIdx.x] = s; sh2[threadIdx.x] = s2;
    __syncthreads();
    for (int o = 128; o > 0; o >>= 1) {
        if (threadIdx.x < o) { sh1[threadIdx.x] += sh1[threadIdx.x+o]; sh2[threadIdx.x] += sh2[threadIdx.x+o]; }
        __syncthreads();
    }
    if (threadIdx.x == 0) { atomicAdd(&st[2*c], sh1[0]); atomicAdd(&st[2*c+1], sh2[0]); }
}

// 3x3 s2 with fused input instance-norm+relu; grid 4*NBLK2; thread: 1 px, 8 co
__global__ void conv3s2_fused(const float* __restrict__ in, const float* __restrict__ st,
                              const float* __restrict__ wt, const float* __restrict__ b,
                              float* __restrict__ out) {
    int cg = blockIdx.x / NBLK2;
    int sp = (blockIdx.x % NBLK2)*256 + threadIdx.x;
    int co8 = cg*8;
    int oy = sp / W2, ox = sp % W2;
    float acc[8];
    #pragma unroll
    for (int j = 0; j < 8; ++j) acc[j] = b[co8+j];
    for (int ci = 0; ci < 32; ++ci) {
        float m    = st[2*ci] * (1.0f/NP1);
        float var  = st[2*ci+1] * (1.0f/NP1) - m*m;
        float rstd = rsqrtf(var + 1e-5f);
        const float* ip  = in + ci*NP1;
        const float* wci = wt + ci*9*32 + co8;
        #pragma unroll
        for (int ky = 0; ky < 3; ++ky) {
            int iy = 2*oy - 1 + ky;
            if ((unsigned)iy >= (unsigned)H1) continue;
            const float* row = ip + iy*W1;
            #pragma unroll
            for (int kx = 0; kx < 3; ++kx) {
                int ix = 2*ox - 1 + kx;
                if ((unsigned)ix >= (unsigned)W1) continue;
                float t = fmaxf((row[ix] - m)*rstd, 0.f);
                const float4* wp = (const float4*)(wci + (ky*3+kx)*32);
                float4 w0 = wp[0], w1 = wp[1];
                acc[0] += t*w0.x; acc[1] += t*w0.y; acc[2] += t*w0.z; acc[3] += t*w0.w;
                acc[4] += t*w1.x; acc[5] += t*w1.y; acc[6] += t*w1.z; acc[7] += t*w1.w;
            }
        }
    }
    #pragma unroll
    for (int j = 0; j < 8; ++j) out[(co8+j)*NP2 + sp] = acc[j];
}

// 1x1 with fused input instance-norm+relu; grid 4*NBLK2; thread: 1 px, 8 co; optional tanh
__global__ void conv1x1_fused(const float* __restrict__ in, const float* __restrict__ st,
                              const float* __restrict__ wt, const float* __restrict__ b,
                              float* __restrict__ out, int mode) {
    int cg = blockIdx.x / NBLK2;
    int sp = (blockIdx.x % NBLK2)*256 + threadIdx.x;
    int co8 = cg*8;
    float acc[8];
    #pragma unroll
    for (int j = 0; j < 8; ++j) acc[j] = b[co8+j];
    for (int ci = 0; ci < 32; ++ci) {
        float m    = st[2*ci] * (1.0f/NP2);
        float var  = st[2*ci+1] * (1.0f/NP2) - m*m;
        float rstd = rsqrtf(var + 1e-5f);
        float t = fmaxf((in[ci*NP2 + sp] - m)*rstd, 0.f);
        const float4* wp = (const float4*)(wt + ci*32 + co8);
        float4 w0 = wp[0], w1 = wp[1];
        acc[0] += t*w0.x; acc[1] += t*w0.y; acc[2] += t*w0.z; acc[3] += t*w0.w;
        acc[4] += t*w1.x; acc[5] += t*w1.y; acc[6] += t*w1.z; acc[7] += t*w1.w;
    }
    #pragma unroll
    for (int j = 0; j < 8; ++j) {
        float a = acc[j];
        if (mode) a = tanhf(a);
        out[(co8+j)*NP2 + sp] = a;
    }
}

// ---------------- feat(0) prologue (padded) ----------------

__global__ void feat0_pad_kernel(const float* __restrict__ fmap1, const float* __restrict__ fmap2,
                                 const float* __restrict__ wat, const float* __restrict__ wbt,
                                 const float* __restrict__ wct, const float* __restrict__ bc,
                                 float* __restrict__ featA) {
    int cg  = blockIdx.x / NBLK2;
    int sp  = (blockIdx.x % NBLK2)*256 + threadIdx.x;
    int y = sp / W2;
    int gx = sp % W2;
    int co8 = cg*8;
    float acc[8];
    #pragma unroll
    for (int j = 0; j < 8; ++j) acc[j] = bc[co8+j];
    for (int ci = 0; ci < 32; ++ci) {
        float f1 = fmap1[ci*NP2 + sp];
        float f2 = fmap2[ci*NP2 + sp];
        float f12 = f1*f2;
        const float4* ap = (const float4*)(wat + ci*32 + co8);
        const float4* bp = (const float4*)(wbt + ci*32 + co8);
        const float4* cp = (const float4*)(wct + ci*32 + co8);
        float4 a0 = ap[0], a1 = ap[1];
        float4 b0 = bp[0], b1 = bp[1];
        float4 c0 = cp[0], c1 = cp[1];
        acc[0] += f1*a0.x + f2*b0.x + f12*c0.x;
        acc[1] += f1*a0.y + f2*b0.y + f12*c0.y;
        acc[2] += f1*a0.z + f2*b0.z + f12*c0.z;
        acc[3] += f1*a0.w + f2*b0.w + f12*c0.w;
        acc[4] += f1*a1.x + f2*b1.x + f12*c1.x;
        acc[5] += f1*a1.y + f2*b1.y + f12*c1.y;
        acc[6] += f1*a1.z + f2*b1.z + f12*c1.z;
        acc[7] += f1*a1.w + f2*b1.w + f12*c1.w;
    }
    float* dst = featA + (size_t)(y+1)*PW + (gx+1);
    #pragma unroll
    for (int j = 0; j < 8; ++j) dst[(size_t)(co8+j)*PSL] = acc[j];
}

// ---------------- GRU loop kernels (compact-column domain, pass-split) ----------------
// grid dim3(nblk, 32): blockIdx.y = cg*2 + job.
//   job0: full z/r conv (zbuf, rhpad, rhpad zero col)
//   job1: q-partial over {hworkA (wq ci32..63), featA (wq ci64..95)} -> qpart; feat(d+1) -> featB

__global__ __launch_bounds__(256, 4)
void zrq_a(const float* __restrict__ hworkA, const float* __restrict__ featA,
           const float* __restrict__ fmap1, const float* __restrict__ fmap2,
           const float4* __restrict__ wzrpk, const float2* __restrict__ wqpk,
           const float* __restrict__ wat, const float* __restrict__ wbt,
           const float* __restrict__ wct, const float* __restrict__ bfc,
           const float* __restrict__ bz, const float* __restrict__ br,
           float* __restrict__ zbuf, float* __restrict__ rhpad,
           float* __restrict__ featB, float* __restrict__ qpart,
           int d, int Wd) {
    __shared__ v2f lws[1152];
    __shared__ v2f lfa[32], lfb[32], lfc[32];
    int cg  = blockIdx.y >> 1;
    int job = blockIdx.y & 1;
    int co0 = cg*2;
    if (job == 0) {
        const float4* wsrc = wzrpk + (size_t)cg*576;
        for (int i = threadIdx.x; i < 576; i += 256) {
            float4 w = wsrc[i];
            lws[i]       = (v2f){w.x, w.y};   // z
            lws[576 + i] = (v2f){w.z, w.w};   // r
        }
    } else {
        const float2* wsrc = wqpk + (size_t)cg*864 + 288;   // wq ci 32..95
        for (int i = threadIdx.x; i < 576; i += 256) {
            float2 w = wsrc[i];
            lws[i] = (v2f){w.x, w.y};
        }
        if (threadIdx.x < 32) {
            int ci = threadIdx.x;
            lfa[ci] = (v2f){wat[ci*32+co0], wat[ci*32+co0+1]};
            lfb[ci] = (v2f){wbt[ci*32+co0], wbt[ci*32+co0+1]};
            lfc[ci] = (v2f){wct[ci*32+co0], wct[ci*32+co0+1]};
        }
    }
    __syncthreads();
    int sp2 = blockIdx.x*256 + threadIdx.x;
    if (sp2 >= 48*Wd) return;
    int rp = sp2 / Wd;
    int lx = sp2 - rp*Wd;
    int y0 = rp*2;
    int gx = d + lx;
    size_t poff = (size_t)(y0+1)*PW + (gx+1);
    int ub = y0*W2 + gx;

    if (job == 0) {
        // marching zero col for rhpad (left pad of this iteration's q conv)
        if (lx == 0) {
            #pragma unroll
            for (int j = 0; j < 2; ++j) {
                rhpad[(size_t)(co0+j)*PSL + poff - 1]      = 0.f;
                rhpad[(size_t)(co0+j)*PSL + poff + PW - 1] = 0.f;
            }
        }
        // z/r conv: pass 0 = hworkA (ci 0..31), pass 1 = featA (ci 32..63)
        v2f az0 = (v2f){bz[co0], bz[co0+1]}, az1 = az0;
        v2f ar0 = (v2f){br[co0], br[co0+1]}, ar1 = ar0;
        #pragma unroll
        for (int pass = 0; pass < 2; ++pass) {
            const float* p = (pass == 0 ? hworkA : featA) + poff;
            const v2f* wz = lws + pass*288;
            const v2f* wr = lws + 576 + pass*288;
            #pragma unroll 2
            for (int ci = 0; ci < 32; ++ci) {
                float v[12];
                #pragma unroll
                for (int r = 0; r < 4; ++r) {
                    v[r*3+0] = p[(r-1)*PW - 1];
                    v[r*3+1] = p[(r-1)*PW    ];
                    v[r*3+2] = p[(r-1)*PW + 1];
                }
                #pragma unroll
                for (int k = 0; k < 9; ++k) {
                    int ky = k/3, kx = k - 3*ky;
                    float t0 = v[ky*3+kx];
                    float t1 = v[(ky+1)*3+kx];
                    v2f wzk = wz[k], wrk = wr[k];
                    az0 += wzk*(v2f){t0,t0}; az1 += wzk*(v2f){t1,t1};
                    ar0 += wrk*(v2f){t0,t0}; ar1 += wrk*(v2f){t1,t1};
                }
                p += PSL;
                wz += 9; wr += 9;
            }
        }
        v2f z0, z1, r0, r1;
        z0.x = 1.f/(1.f + __expf(-az0.x)); z0.y = 1.f/(1.f + __expf(-az0.y));
        z1.x = 1.f/(1.f + __expf(-az1.x)); z1.y = 1.f/(1.f + __expf(-az1.y));
        r0.x = 1.f/(1.f + __expf(-ar0.x)); r0.y = 1.f/(1.f + __expf(-ar0.y));
        r1.x = 1.f/(1.f + __expf(-ar1.x)); r1.y = 1.f/(1.f + __expf(-ar1.y));
        float h00 = hworkA[(size_t)co0*PSL + poff];
        float h01 = hworkA[(size_t)(co0+1)*PSL + poff];
        float h10 = hworkA[(size_t)co0*PSL + poff + PW];
        float h11 = hworkA[(size_t)(co0+1)*PSL + poff + PW];
        zbuf[(size_t)co0*NP2 + ub]          = z0.x;
        zbuf[(size_t)(co0+1)*NP2 + ub]      = z0.y;
        zbuf[(size_t)co0*NP2 + ub + W2]     = z1.x;
        zbuf[(size_t)(co0+1)*NP2 + ub + W2] = z1.y;
        rhpad[(size_t)co0*PSL + poff]          = r0.x*h00;
        rhpad[(size_t)(co0+1)*PSL + poff]      = r0.y*h01;
        rhpad[(size_t)co0*PSL + poff + PW]     = r1.x*h10;
        rhpad[(size_t)(co0+1)*PSL + poff + PW] = r1.y*h11;
    } else {
        // feat(d+1) -> featB; col d (lx==0) is its left-halo zero col
        int dn = d + 1;
        if (dn < ND) {
            if (lx == 0) {
                #pragma unroll
                for (int j = 0; j < 2; ++j) {
                    featB[(size_t)(co0+j)*PSL + poff]      = 0.f;
                    featB[(size_t)(co0+j)*PSL + poff + PW] = 0.f;
                }
            } else {
                v2f f0 = (v2f){bfc[co0], bfc[co0+1]};
                v2f f1 = f0;
                int base1 = y0*W2 + gx;
                #pragma unroll 2
                for (int ci = 0; ci < 32; ++ci) {
                    float a1 = fmap1[ci*NP2 + base1];
                    float a2 = fmap1[ci*NP2 + base1 + W2];
                    float b1 = fmap2[ci*NP2 + base1 - dn];
                    float b2 = fmap2[ci*NP2 + base1 + W2 - dn];
                    v2f wa = lfa[ci], wb = lfb[ci], wc = lfc[ci];
                    f0 += wa*(v2f){a1,a1} + wb*(v2f){b1,b1} + wc*(v2f){a1*b1,a1*b1};
                    f1 += wa*(v2f){a2,a2} + wb*(v2f){b2,b2} + wc*(v2f){a2*b2,a2*b2};
                }
                featB[(size_t)co0*PSL + poff]          = f0.x;
                featB[(size_t)(co0+1)*PSL + poff]      = f0.y;
                featB[(size_t)co0*PSL + poff + PW]     = f1.x;
                featB[(size_t)(co0+1)*PSL + poff + PW] = f1.y;
            }
        }
        // q partial: pass 0 = hworkA (wq ci 32..63), pass 1 = featA (wq ci 64..95)
        v2f a0 = (v2f){0.f, 0.f};
        v2f a1 = a0;
        #pragma unroll
        for (int pass = 0; pass < 2; ++pass) {
            const float* p = (pass == 0 ? hworkA : featA) + poff;
            const v2f* wp = lws + pass*288;
            #pragma unroll 2
            for (int ci = 0; ci < 32; ++ci) {
                float v[12];
                #pragma unroll
                for (int r = 0; r < 4; ++r) {
                    v[r*3+0] = p[(r-1)*PW - 1];
                    v[r*3+1] = p[(r-1)*PW    ];
                    v[r*3+2] = p[(r-1)*PW + 1];
                }
                #pragma unroll
                for (int k = 0; k < 9; ++k) {
                    int ky = k/3, kx = k - 3*ky;
                    float t0 = v[ky*3+kx];
                    float t1 = v[(ky+1)*3+kx];
                    v2f wk = wp[k];
                    a0 += wk*(v2f){t0,t0};
                    a1 += wk*(v2f){t1,t1};
                }
                p += PSL;
                wp += 9;
            }
        }
        qpart[(size_t)co0*NP2 + ub]          = a0.x;
        qpart[(size_t)(co0+1)*NP2 + ub]      = a0.y;
        qpart[(size_t)co0*NP2 + ub + W2]     = a1.x;
        qpart[(size_t)(co0+1)*NP2 + ub + W2] = a1.y;
    }
}

// q_fin: q's rh-pass (wq ci 0..31) + qpart + bias -> tanh -> GRU update.
// grid dim3(nblk, 16)
__global__ __launch_bounds__(256, 4)
void q_fin(const float* __restrict__ rhpad, const float* __restrict__ hworkA,
           const float* __restrict__ zbuf, const float* __restrict__ qpart,
           const float2* __restrict__ wqpk, const float* __restrict__ bq,
           float* __restrict__ hfinal, float* __restrict__ hworkB, int d, int Wd) {
    __shared__ v2f lw[288];
    int cg  = blockIdx.y;
    int co0 = cg*2;
    {
        const float2* wsrc = wqpk + (size_t)cg*864;   // wq ci 0..31
        for (int i = threadIdx.x; i < 288; i += 256) {
            float2 w = wsrc[i];
            lw[i] = (v2f){w.x, w.y};
        }
    }
    __syncthreads();
    int sp2 = blockIdx.x*256 + threadIdx.x;
    if (sp2 >= 48*Wd) return;
    int rp = sp2 / Wd;
    int lx = sp2 - rp*Wd;
    int y0 = rp*2;
    int gx = d + lx;
    size_t poff = (size_t)(y0+1)*PW + (gx+1);
    int ub = y0*W2 + gx;

    v2f a0 = (v2f){bq[co0], bq[co0+1]};
    v2f a1 = a0;
    {
        const float* p = rhpad + poff;
        const v2f* wp = lw;
        #pragma unroll 2
        for (int ci = 0; ci < 32; ++ci) {
            float v[12];
            #pragma unroll
            for (int r = 0; r < 4; ++r) {
                v[r*3+0] = p[(r-1)*PW - 1];
                v[r*3+1] = p[(r-1)*PW    ];
                v[r*3+2] = p[(r-1)*PW + 1];
            }
            #pragma unroll
            for (int k = 0; k < 9; ++k) {
                int ky = k/3, kx = k - 3*ky;
                float t0 = v[ky*3+kx];
                float t1 = v[(ky+1)*3+kx];
                v2f wk = wp[k];
                a0 += wk*(v2f){t0,t0};
                a1 += wk*(v2f){t1,t1};
            }
            p += PSL;
            wp += 9;
        }
    }
    a0.x += qpart[(size_t)co0*NP2 + ub];
    a0.y += qpart[(size_t)(co0+1)*NP2 + ub];
    a1.x += qpart[(size_t)co0*NP2 + ub + W2];
    a1.y += qpart[(size_t)(co0+1)*NP2 + ub + W2];
    float q00 = tanhf(a0.x), q01 = tanhf(a0.y);
    float q10 = tanhf(a1.x), q11 = tanhf(a1.y);
    #pragma unroll
    for (int j = 0; j < 2; ++j) {
        float qa = (j == 0) ? q00 : q01;
        float qb = (j == 0) ? q10 : q11;
        size_t pidx = (size_t)(co0+j)*PSL + poff;
        size_t uidx = (size_t)(co0+j)*NP2 + ub;
        float z_a = zbuf[uidx];
        float z_b = zbuf[uidx + W2];
        float h_a = hworkA[pidx];
        float h_b = hworkA[pidx + PW];
        float hn_a = (1.f - z_a)*h_a + z_a*qa;
        float hn_b = (1.f - z_b)*h_b + z_b*qb;
        if (lx == 0 || d == ND-1) {
            hfinal[pidx]      = hn_a;
            hfinal[pidx + PW] = hn_b;
        }
        hworkB[pidx]      = (lx == 0) ? 0.f : hn_a;
        hworkB[pidx + PW] = (lx == 0) ? 0.f : hn_b;
    }
}

// ---------------- disparity head ----------------

// 3x3 conv 32->64 + relu on padded hfinal; grid dim3(30, 16); thread: 2 rows x 4 co
__global__ __launch_bounds__(256, 4)
void disp1_v6(const float* __restrict__ hfinal, const float* __restrict__ wt,
              const float* __restrict__ b, float* __restrict__ out) {
    __shared__ float4 lw[288];   // [ci*9+k] -> 4 co weights
    int cg  = blockIdx.y;
    int co0 = cg*4;
    for (int i = threadIdx.x; i < 288; i += 256)
        lw[i] = *(const float4*)&wt[i*64 + co0];
    __syncthreads();
    int sp2 = blockIdx.x*256 + threadIdx.x;   // 0..7679
    int y0 = (sp2 / W2)*2;
    int gx = sp2 % W2;
    size_t poff = (size_t)(y0+1)*PW + (gx+1);
    float4 bb = *(const float4*)&b[co0];
    float acc0[4] = {bb.x, bb.y, bb.z, bb.w};
    float acc1[4] = {bb.x, bb.y, bb.z, bb.w};
    const float* p = hfinal + poff;
    #pragma unroll 2
    for (int ci = 0; ci < 32; ++ci) {
        float v[12];
        #pragma unroll
        for (int r = 0; r < 4; ++r) {
            v[r*3+0] = p[(r-1)*PW - 1];
            v[r*3+1] = p[(r-1)*PW    ];
            v[r*3+2] = p[(r-1)*PW + 1];
        }
        #pragma unroll
        for (int k = 0; k < 9; ++k) {
            int ky = k/3, kx = k - 3*ky;
            float t0 = v[ky*3+kx];
            float t1 = v[(ky+1)*3+kx];
            float4 w = lw[ci*9+k];
            acc0[0] += t0*w.x; acc0[1] += t0*w.y; acc0[2] += t0*w.z; acc0[3] += t0*w.w;
            acc1[0] += t1*w.x; acc1[1] += t1*w.y; acc1[2] += t1*w.z; acc1[3] += t1*w.w;
        }
        p += PSL;
    }
    int ub = y0*W2 + gx;
    #pragma unroll
    for (int j = 0; j < 4; ++j) {
        out[(co0+j)*NP2 + ub]      = fmaxf(acc0[j], 0.f);
        out[(co0+j)*NP2 + ub + W2] = fmaxf(acc1[j], 0.f);
    }
}

__global__ void disp2_part_kernel(const float* __restrict__ in, const float* __restrict__ w,
                                  float* __restrict__ part) {
    __shared__ float lw[8*9];
    int g  = blockIdx.x / NBLK2;
    int sp = (blockIdx.x % NBLK2)*256 + threadIdx.x;
    if (threadIdx.x < 72) lw[threadIdx.x] = w[g*72 + threadIdx.x];
    __syncthreads();
    int y = sp / W2, x = sp % W2;
    float acc = 0.f;
    #pragma unroll
    for (int ci = 0; ci < 8; ++ci) {
        const float* ip = in + (g*8 + ci)*NP2;
        #pragma unroll
        for (int dy = 0; dy < 3; ++dy) {
            int ys = y+dy-1; if ((unsigned)ys >= (unsigned)H2) continue;
            const float* row = ip + ys*W2;
            #pragma unroll
            for (int dx = 0; dx < 3; ++dx) {
                int xs = x+dx-1; if ((unsigned)xs >= (unsigned)W2) continue;
                acc += lw[ci*9+dy*3+dx] * row[xs];
            }
        }
    }
    part[g*NP2 + sp] = acc;
}

__global__ void disp2_comb_kernel(const float* __restrict__ part, const float* __restrict__ b,
                                  float* __restrict__ out) {
    int sp = blockIdx.x*256 + threadIdx.x;
    float acc = b[0];
    #pragma unroll
    for (int g = 0; g < 8; ++g) acc += part[g*NP2 + sp];
    out[sp] = -acc;
}

// ---------------- launch ----------------

extern "C" void kernel_launch(void* const* d_in, const int* in_sizes, int n_in,
                              void* d_out, int out_size, void* d_ws, size_t ws_size,
                              hipStream_t stream) {
    const float* image1   = (const float*)d_in[0];
    const float* image2   = (const float*)d_in[1];
    const float* fnet_w1  = (const float*)d_in[2];
    const float* fnet_b1  = (const float*)d_in[3];
    const float* fnet_w2  = (const float*)d_in[4];
    const float* fnet_b2  = (const float*)d_in[5];
    const float* fnet_w3  = (const float*)d_in[6];
    const float* fnet_b3  = (const float*)d_in[7];
    const float* cnet_w1  = (const float*)d_in[8];
    const float* cnet_b1  = (const float*)d_in[9];
    const float* cnet_w2  = (const float*)d_in[10];
    const float* cnet_b2  = (const float*)d_in[11];
    const float* cnet_w3  = (const float*)d_in[12];
    const float* cnet_b3  = (const float*)d_in[13];
    const float* bform_a  = (const float*)d_in[14];
    const float* bform_b  = (const float*)d_in[15];
    const float* bform_cd_w = (const float*)d_in[16];
    const float* bform_cd_b = (const float*)d_in[17];
    const float* gru_wz   = (const float*)d_in[18];
    const float* gru_bz   = (const float*)d_in[19];
    const float* gru_wr   = (const float*)d_in[20];
    const float* gru_br   = (const float*)d_in[21];
    const float* gru_wq   = (const float*)d_in[22];
    const float* gru_bq   = (const float*)d_in[23];
    const float* disp_w1  = (const float*)d_in[24];
    const float* disp_b1  = (const float*)d_in[25];
    const float* disp_w2  = (const float*)d_in[26];
    const float* disp_b2  = (const float*)d_in[27];

    float* ws = (float*)d_ws;
    size_t o = 0;
    float* e1f    = ws + o; o += (size_t)32*NP1;
    float* e1c    = ws + o; o += (size_t)32*NP1;
    float* e2     = ws + o; o += CHW;
    float* fmap1  = ws + o; o += CHW;
    float* fmap2  = ws + o; o += CHW;
    float* hidden = ws + o; o += CHW;
    float* zbuf   = ws + o; o += CHW;
    float* qpart  = ws + o; o += CHW;
    float* hwork0 = ws + o; o += PCHW;
    /* the next 5 padded buffers are contiguous -> one zero_buf */
    float* hwork1 = ws + o; o += PCHW;
    float* rhpad  = ws + o; o += PCHW;
    float* feat0  = ws + o; o += PCHW;
    float* feat1  = ws + o; o += PCHW;
    float* hfinal = ws + o; o += PCHW;
    float* stats  = ws + o; o += 384;
    float* wzrpk  = ws + o; o += 16*64*9*4;
    float* wqpk   = ws + o; o += 16*96*9*2;
    float* we1f   = ws + o; o += 3*49*32;
    float* we1c   = ws + o; o += 3*49*32;
    float* we2f   = ws + o; o += 32*9*32;
    float* we2c   = ws + o; o += 32*9*32;
    float* w3f    = ws + o; o += 32*32;
    float* w3c    = ws + o; o += 32*32;
    float* wat    = ws + o; o += 32*32;
    float* wbt    = ws + o; o += 32*32;
    float* wct    = ws + o; o += 32*32;
    float* wd1t   = ws + o; o += 32*9*64;
    float* disp1buf  = e1f;  // e1f dead after encoders (64*NP2 <= 32*NP1)
    float* disp2part = e1c;  // e1c dead after encoders

    // --- prep (one launch) ---
    prep_all<<<(74816 + 255)/256, 256, 0, stream>>>(
        fnet_w1, cnet_w1, fnet_w2, cnet_w2, fnet_w3, cnet_w3,
        bform_a, bform_b, bform_cd_w, disp_w1, gru_wz, gru_wr, gru_wq,
        we1f, we1c, we2f, we2c, w3f, w3c, wat, wbt, wct, wd1t,
        (float4*)wzrpk, (float2*)wqpk, stats);

    // --- encoders (B=1: inorm == bnorm; norm+relu fused into consumers) ---
    conv7s2_dual<<<dim3(NP1/256, 4), 256, 0, stream>>>(image1, we1f, we1c, fnet_b1, cnet_b1,
                                                       e1f, e1c);
    stats_partial_kernel<<<256, 256, 0, stream>>>(e1f, NP1, stats+0);
    stats_partial_kernel<<<256, 256, 0, stream>>>(e1c, NP1, stats+64);
    conv3s2_fused<<<4*NBLK2, 256, 0, stream>>>(e1f, stats+0, we2f, fnet_b2, e2);
    stats_partial_kernel<<<256, 256, 0, stream>>>(e2, NP2, stats+128);
    conv1x1_fused<<<4*NBLK2, 256, 0, stream>>>(e2, stats+128, w3f, fnet_b3, fmap1, 0);
    conv3s2_fused<<<4*NBLK2, 256, 0, stream>>>(e1c, stats+64, we2c, cnet_b2, e2);
    stats_partial_kernel<<<256, 256, 0, stream>>>(e2, NP2, stats+192);
    conv1x1_fused<<<4*NBLK2, 256, 0, stream>>>(e2, stats+192, w3c, cnet_b3, hidden, 1);
    conv7s2_v3<<<dim3(NP1/256, 2), 256, 0, stream>>>(image2, we1f, fnet_b1, e1f);
    stats_partial_kernel<<<256, 256, 0, stream>>>(e1f, NP1, stats+256);
    conv3s2_fused<<<4*NBLK2, 256, 0, stream>>>(e1f, stats+256, we2f, fnet_b2, e2);
    stats_partial_kernel<<<256, 256, 0, stream>>>(e2, NP2, stats+320);
    conv1x1_fused<<<4*NBLK2, 256, 0, stream>>>(e2, stats+320, w3f, fnet_b3, fmap2, 0);

    // --- padded working buffers ---
    zero_buf_kernel<<<2048, 256, 0, stream>>>(hwork1, 5*PCHW);  // hwork1..hfinal contiguous
    pad_init_kernel<<<(32*PSL+255)/256, 256, 0, stream>>>(hidden, hwork0);
    feat0_pad_kernel<<<4*NBLK2, 256, 0, stream>>>(fmap1, fmap2, wat, wbt, wct,
                                                  bform_cd_b, feat0);

    // --- sequential GRU sweep: 2 launches per iteration, pass-split for occupancy ---
    float* hwA = hwork0; float* hwB = hwork1;
    float* ftA = feat0;  float* ftB = feat1;
    for (int d = 0; d < ND; ++d) {
        int Wd = W2 - d;
        int nblk = (48*Wd + 255)/256;
        zrq_a<<<dim3(nblk, 32), 256, 0, stream>>>(hwA, ftA, fmap1, fmap2,
                                                  (const float4*)wzrpk, (const float2*)wqpk,
                                                  wat, wbt, wct, bform_cd_b,
                                                  gru_bz, gru_br, zbuf, rhpad, ftB, qpart,
                                                  d, Wd);
        q_fin<<<dim3(nblk, 16), 256, 0, stream>>>(rhpad, hwA, zbuf, qpart,
                                                  (const float2*)wqpk, gru_bq,
                                                  hfinal, hwB, d, Wd);
        float* t;
        t = hwA; hwA = hwB; hwB = t;
        t = ftA; ftA = ftB; ftB = t;
    }

    // --- disparity head (reads padded hfinal) ---
    disp1_v6<<<dim3(30, 16), 256, 0, stream>>>(hfinal, wd1t, disp_b1, disp1buf);
    disp2_part_kernel<<<8*NBLK2, 256, 0, stream>>>(disp1buf, disp_w2, disp2part);
    disp2_comb_kernel<<<NBLK2, 256, 0, stream>>>(disp2part, disp_b2, (float*)d_out);
}

// Round 19
// 2553.979 us; speedup vs baseline: 1.5729x; 1.0509x over previous
//
#include <hip/hip_runtime.h>
#include <math.h>

#define H0 384
#define W0 640
#define H1 192
#define W1 320
#define H2 96
#define W2 160
#define NP1 (H1*W1)   /* 61440 */
#define NP2 (H2*W2)   /* 15360 */
#define ND  48        /* MAX_DISP/4 */
#define NBLK2 (NP2/256)  /* 60 */
#define CHW ((size_t)32*NP2)
/* padded (halo=1) layout, global coords */
#define PW 162
#define PH 98
#define PSL (PH*PW)            /* 15876 */
#define PCHW ((size_t)32*PSL)  /* 508032 */

typedef float v2f __attribute__((ext_vector_type(2)));

// ---------------- generic prep ----------------

__global__ void zero_buf_kernel(float* __restrict__ p, size_t n) {
    size_t i = (size_t)blockIdx.x*256 + threadIdx.x;
    size_t stride = (size_t)gridDim.x*256;
    for (; i < n; i += stride) p[i] = 0.f;
}

__device__ __forceinline__ void twr_dev(const float* __restrict__ in, float* __restrict__ out,
                                        int idx, int CI, int K, int CO) {
    int co = idx % CO;
    int t  = idx / CO;
    int k  = t % K;
    int ci = t / K;
    out[idx] = in[(co*CI + ci)*K + k];
}

// single launch: all weight transposes + packs + stats zero (74816 items)
__global__ void prep_all(const float* __restrict__ fnet_w1, const float* __restrict__ cnet_w1,
                         const float* __restrict__ fnet_w2, const float* __restrict__ cnet_w2,
                         const float* __restrict__ fnet_w3, const float* __restrict__ cnet_w3,
                         const float* __restrict__ bform_a, const float* __restrict__ bform_b,
                         const float* __restrict__ bform_cd_w, const float* __restrict__ disp_w1,
                         const float* __restrict__ gru_wz, const float* __restrict__ gru_wr,
                         const float* __restrict__ gru_wq,
                         float* __restrict__ we1f, float* __restrict__ we1c,
                         float* __restrict__ we2f, float* __restrict__ we2c,
                         float* __restrict__ w3f, float* __restrict__ w3c,
                         float* __restrict__ wat, float* __restrict__ wbt,
                         float* __restrict__ wct, float* __restrict__ wd1t,
                         float4* __restrict__ wzrpk, float2* __restrict__ wqpk,
                         float* __restrict__ stats) {
    int i = blockIdx.x*256 + threadIdx.x;
    if (i < 4704) { twr_dev(fnet_w1, we1f, i, 3, 49, 32); return; }
    i -= 4704;
    if (i < 4704) { twr_dev(cnet_w1, we1c, i, 3, 49, 32); return; }
    i -= 4704;
    if (i < 9216) { twr_dev(fnet_w2, we2f, i, 32, 9, 32); return; }
    i -= 9216;
    if (i < 9216) { twr_dev(cnet_w2, we2c, i, 32, 9, 32); return; }
    i -= 9216;
    if (i < 1024) { twr_dev(fnet_w3, w3f, i, 32, 1, 32); return; }
    i -= 1024;
    if (i < 1024) { twr_dev(cnet_w3, w3c, i, 32, 1, 32); return; }
    i -= 1024;
    if (i < 1024) { twr_dev(bform_a, wat, i, 32, 1, 32); return; }
    i -= 1024;
    if (i < 1024) { twr_dev(bform_b, wbt, i, 32, 1, 32); return; }
    i -= 1024;
    if (i < 1024) { twr_dev(bform_cd_w, wct, i, 32, 1, 32); return; }
    i -= 1024;
    if (i < 18432) { twr_dev(disp_w1, wd1t, i, 32, 9, 64); return; }
    i -= 18432;
    if (i < 9216) {   // packed z/r: [cg][ci<64][k] = {z0,z1,r0,r1}
        int k  = i % 9;
        int ci = (i/9) % 64;
        int cg = i / (9*64);
        int co0 = cg*2, co1 = co0 + 1;
        float z0, z1, r0, r1;
        if (ci < 32) {
            z0 = gru_wz[(co0*96 + ci)*9 + k] + gru_wz[(co0*96 + ci + 32)*9 + k];
            z1 = gru_wz[(co1*96 + ci)*9 + k] + gru_wz[(co1*96 + ci + 32)*9 + k];
            r0 = gru_wr[(co0*96 + ci)*9 + k] + gru_wr[(co0*96 + ci + 32)*9 + k];
            r1 = gru_wr[(co1*96 + ci)*9 + k] + gru_wr[(co1*96 + ci + 32)*9 + k];
        } else {
            z0 = gru_wz[(co0*96 + ci + 32)*9 + k];
            z1 = gru_wz[(co1*96 + ci + 32)*9 + k];
            r0 = gru_wr[(co0*96 + ci + 32)*9 + k];
            r1 = gru_wr[(co1*96 + ci + 32)*9 + k];
        }
        wzrpk[i] = make_float4(z0, z1, r0, r1);
        return;
    }
    i -= 9216;
    if (i < 13824) {  // packed q: [cg][ci<96][k] = {co0, co1}
        int k  = i % 9;
        int ci = (i/9) % 96;
        int cg = i / (9*96);
        wqpk[i] = make_float2(gru_wq[((cg*2)*96 + ci)*9 + k], gru_wq[((cg*2+1)*96 + ci)*9 + k]);
        return;
    }
    i -= 13824;
    if (i < 384) stats[i] = 0.f;
}

// hwork[c][py][px] = hidden[c][py-1][px-1] interior, 0 halo
__global__ void pad_init_kernel(const float* __restrict__ hidden, float* __restrict__ hwork) {
    int idx = blockIdx.x*256 + threadIdx.x;
    if (idx >= 32*PSL) return;
    int c = idx / PSL;
    int r = idx % PSL;
    int py = r / PW, px = r % PW;
    int y = py - 1, x = px - 1;
    float v = 0.f;
    if ((unsigned)y < (unsigned)H2 && (unsigned)x < (unsigned)W2)
        v = hidden[c*NP2 + y*W2 + x];
    hwork[idx] = v;
}

// ---------------- merged encoder kernels (3 independent nets per launch) ----------------

// 7x7 s2: grid dim3(240, 12): net = y/4 (0=fnet img1, 1=cnet img1, 2=fnet img2); cg = y%4
__global__ __launch_bounds__(256, 8)
void conv7s2_all(const float* __restrict__ img1, const float* __restrict__ img2,
                 const float* __restrict__ wtf, const float* __restrict__ wtc,
                 const float* __restrict__ bf, const float* __restrict__ bc,
                 float* __restrict__ e1f, float* __restrict__ e1c, float* __restrict__ e1i2) {
    int net = blockIdx.y >> 2;
    int co8 = (blockIdx.y & 3)*8;
    const float* img = (net == 2) ? img2 : img1;
    const float* wt  = (net == 1) ? wtc : wtf;
    const float* bb  = (net == 1) ? bc  : bf;
    float* out = (net == 0) ? e1f : (net == 1 ? e1c : e1i2);
    int sp = blockIdx.x*256 + threadIdx.x;
    int oy = sp / W1, ox = sp % W1;
    float acc[8];
    #pragma unroll
    for (int j = 0; j < 8; ++j) acc[j] = bb[co8+j];
    for (int ci = 0; ci < 3; ++ci) {
        for (int ky = 0; ky < 7; ++ky) {
            int iy = 2*oy - 3 + ky;
            if ((unsigned)iy >= (unsigned)H0) continue;
            const float* row  = img + ci*(H0*W0) + iy*W0;
            const float* wrow = wt + (ci*49 + ky*7)*32 + co8;
            #pragma unroll
            for (int kx = 0; kx < 7; ++kx) {
                int ix = 2*ox - 3 + kx;
                if ((unsigned)ix >= (unsigned)W0) continue;
                float v = row[ix]*(2.0f/255.0f) - 1.0f;
                const float4* wp = (const float4*)(wrow + kx*32);
                float4 w0 = wp[0], w1 = wp[1];
                acc[0] += v*w0.x; acc[1] += v*w0.y; acc[2] += v*w0.z; acc[3] += v*w0.w;
                acc[4] += v*w1.x; acc[5] += v*w1.y; acc[6] += v*w1.z; acc[7] += v*w1.w;
            }
        }
    }
    #pragma unroll
    for (int j = 0; j < 8; ++j) out[(co8+j)*NP1 + sp] = acc[j];
}

// stats for 3 buffers in one launch; grid dim3(256, 3)
__global__ void stats3_kernel(const float* __restrict__ b0, const float* __restrict__ b1,
                              const float* __restrict__ b2, int N,
                              float* __restrict__ st0, float* __restrict__ st1,
                              float* __restrict__ st2) {
    int job = blockIdx.y;
    const float* x = (job == 0) ? b0 : (job == 1 ? b1 : b2);
    float* st      = (job == 0) ? st0 : (job == 1 ? st1 : st2);
    int c = blockIdx.x >> 3, sl = blockIdx.x & 7;
    int chunk = N >> 3;
    const float4* p = (const float4*)(x + (size_t)c*N + (size_t)sl*chunk);
    int n4 = chunk >> 2;
    float s = 0.f, s2 = 0.f;
    for (int i = threadIdx.x; i < n4; i += 256) {
        float4 v = p[i];
        s  += v.x + v.y + v.z + v.w;
        s2 += v.x*v.x + v.y*v.y + v.z*v.z + v.w*v.w;
    }
    __shared__ float sh1[256], sh2[256];
    sh1[threadIdx.x] = s; sh2[threadIdx.x] = s2;
    __syncthreads();
    for (int o = 128; o > 0; o >>= 1) {
        if (threadIdx.x < o) { sh1[threadIdx.x] += sh1[threadIdx.x+o]; sh2[threadIdx.x] += sh2[threadIdx.x+o]; }
        __syncthreads();
    }
    if (threadIdx.x == 0) { atomicAdd(&st[2*c], sh1[0]); atomicAdd(&st[2*c+1], sh2[0]); }
}

// 3x3 s2 with fused input inorm+relu, 3 nets; grid dim3(60, 12)
__global__ void conv3s2_all(const float* __restrict__ e1f, const float* __restrict__ e1c,
                            const float* __restrict__ e1i2, const float* __restrict__ stats,
                            const float* __restrict__ we2f, const float* __restrict__ we2c,
                            const float* __restrict__ fb2, const float* __restrict__ cb2,
                            float* __restrict__ e2f, float* __restrict__ e2c,
                            float* __restrict__ e2i2) {
    int net = blockIdx.y >> 2;
    int co8 = (blockIdx.y & 3)*8;
    const float* in = (net == 0) ? e1f : (net == 1 ? e1c : e1i2);
    const float* st = (net == 0) ? stats+0 : (net == 1 ? stats+64 : stats+256);
    const float* wt = (net == 1) ? we2c : we2f;
    const float* b  = (net == 1) ? cb2 : fb2;
    float* out = (net == 0) ? e2f : (net == 1 ? e2c : e2i2);
    int sp = blockIdx.x*256 + threadIdx.x;
    int oy = sp / W2, ox = sp % W2;
    float acc[8];
    #pragma unroll
    for (int j = 0; j < 8; ++j) acc[j] = b[co8+j];
    for (int ci = 0; ci < 32; ++ci) {
        float m    = st[2*ci] * (1.0f/NP1);
        float var  = st[2*ci+1] * (1.0f/NP1) - m*m;
        float rstd = rsqrtf(var + 1e-5f);
        const float* ip  = in + ci*NP1;
        const float* wci = wt + ci*9*32 + co8;
        #pragma unroll
        for (int ky = 0; ky < 3; ++ky) {
            int iy = 2*oy - 1 + ky;
            if ((unsigned)iy >= (unsigned)H1) continue;
            const float* row = ip + iy*W1;
            #pragma unroll
            for (int kx = 0; kx < 3; ++kx) {
                int ix = 2*ox - 1 + kx;
                if ((unsigned)ix >= (unsigned)W1) continue;
                float t = fmaxf((row[ix] - m)*rstd, 0.f);
                const float4* wp = (const float4*)(wci + (ky*3+kx)*32);
                float4 w0 = wp[0], w1 = wp[1];
                acc[0] += t*w0.x; acc[1] += t*w0.y; acc[2] += t*w0.z; acc[3] += t*w0.w;
                acc[4] += t*w1.x; acc[5] += t*w1.y; acc[6] += t*w1.z; acc[7] += t*w1.w;
            }
        }
    }
    #pragma unroll
    for (int j = 0; j < 8; ++j) out[(co8+j)*NP2 + sp] = acc[j];
}

// 1x1 with fused input inorm+relu, 3 nets; grid dim3(60, 12); tanh on net 1
__global__ void conv1x1_all(const float* __restrict__ e2f, const float* __restrict__ e2c,
                            const float* __restrict__ e2i2, const float* __restrict__ stats,
                            const float* __restrict__ w3f, const float* __restrict__ w3c,
                            const float* __restrict__ fb3, const float* __restrict__ cb3,
                            float* __restrict__ fmap1, float* __restrict__ hiddenb,
                            float* __restrict__ fmap2) {
    int net = blockIdx.y >> 2;
    int co8 = (blockIdx.y & 3)*8;
    const float* in = (net == 0) ? e2f : (net == 1 ? e2c : e2i2);
    const float* st = (net == 0) ? stats+128 : (net == 1 ? stats+192 : stats+320);
    const float* wt = (net == 1) ? w3c : w3f;
    const float* b  = (net == 1) ? cb3 : fb3;
    float* out = (net == 0) ? fmap1 : (net == 1 ? hiddenb : fmap2);
    int sp = blockIdx.x*256 + threadIdx.x;
    float acc[8];
    #pragma unroll
    for (int j = 0; j < 8; ++j) acc[j] = b[co8+j];
    for (int ci = 0; ci < 32; ++ci) {
        float m    = st[2*ci] * (1.0f/NP2);
        float var  = st[2*ci+1] * (1.0f/NP2) - m*m;
        float rstd = rsqrtf(var + 1e-5f);
        float t = fmaxf((in[ci*NP2 + sp] - m)*rstd, 0.f);
        const float4* wp = (const float4*)(wt + ci*32 + co8);
        float4 w0 = wp[0], w1 = wp[1];
        acc[0] += t*w0.x; acc[1] += t*w0.y; acc[2] += t*w0.z; acc[3] += t*w0.w;
        acc[4] += t*w1.x; acc[5] += t*w1.y; acc[6] += t*w1.z; acc[7] += t*w1.w;
    }
    #pragma unroll
    for (int j = 0; j < 8; ++j) {
        float a = acc[j];
        if (net == 1) a = tanhf(a);
        out[(co8+j)*NP2 + sp] = a;
    }
}

// ---------------- feat(0) prologue (padded) ----------------

__global__ void feat0_pad_kernel(const float* __restrict__ fmap1, const float* __restrict__ fmap2,
                                 const float* __restrict__ wat, const float* __restrict__ wbt,
                                 const float* __restrict__ wct, const float* __restrict__ bc,
                                 float* __restrict__ featA) {
    int cg  = blockIdx.x / NBLK2;
    int sp  = (blockIdx.x % NBLK2)*256 + threadIdx.x;
    int y = sp / W2;
    int gx = sp % W2;
    int co8 = cg*8;
    float acc[8];
    #pragma unroll
    for (int j = 0; j < 8; ++j) acc[j] = bc[co8+j];
    for (int ci = 0; ci < 32; ++ci) {
        float f1 = fmap1[ci*NP2 + sp];
        float f2 = fmap2[ci*NP2 + sp];
        float f12 = f1*f2;
        const float4* ap = (const float4*)(wat + ci*32 + co8);
        const float4* bp = (const float4*)(wbt + ci*32 + co8);
        const float4* cp = (const float4*)(wct + ci*32 + co8);
        float4 a0 = ap[0], a1 = ap[1];
        float4 b0 = bp[0], b1 = bp[1];
        float4 c0 = cp[0], c1 = cp[1];
        acc[0] += f1*a0.x + f2*b0.x + f12*c0.x;
        acc[1] += f1*a0.y + f2*b0.y + f12*c0.y;
        acc[2] += f1*a0.z + f2*b0.z + f12*c0.z;
        acc[3] += f1*a0.w + f2*b0.w + f12*c0.w;
        acc[4] += f1*a1.x + f2*b1.x + f12*c1.x;
        acc[5] += f1*a1.y + f2*b1.y + f12*c1.y;
        acc[6] += f1*a1.z + f2*b1.z + f12*c1.z;
        acc[7] += f1*a1.w + f2*b1.w + f12*c1.w;
    }
    float* dst = featA + (size_t)(y+1)*PW + (gx+1);
    #pragma unroll
    for (int j = 0; j < 8; ++j) dst[(size_t)(co8+j)*PSL] = acc[j];
}

// ---------------- GRU loop kernels (compact-column domain, pass-split) ----------------
// grid dim3(nblk, 32): blockIdx.y = cg*2 + job.
//   job0: full z/r conv (zbuf, rhpad, rhpad zero col)
//   job1: q-partial over {hworkA (wq ci32..63), featA (wq ci64..95)} -> qpart; feat(d+1) -> featB

__global__ __launch_bounds__(256, 4)
void zrq_a(const float* __restrict__ hworkA, const float* __restrict__ featA,
           const float* __restrict__ fmap1, const float* __restrict__ fmap2,
           const float4* __restrict__ wzrpk, const float2* __restrict__ wqpk,
           const float* __restrict__ wat, const float* __restrict__ wbt,
           const float* __restrict__ wct, const float* __restrict__ bfc,
           const float* __restrict__ bz, const float* __restrict__ br,
           float* __restrict__ zbuf, float* __restrict__ rhpad,
           float* __restrict__ featB, float* __restrict__ qpart,
           int d, int Wd) {
    __shared__ v2f lws[1152];
    __shared__ v2f lfa[32], lfb[32], lfc[32];
    int cg  = blockIdx.y >> 1;
    int job = blockIdx.y & 1;
    int co0 = cg*2;
    if (job == 0) {
        const float4* wsrc = wzrpk + (size_t)cg*576;
        for (int i = threadIdx.x; i < 576; i += 256) {
            float4 w = wsrc[i];
            lws[i]       = (v2f){w.x, w.y};   // z
            lws[576 + i] = (v2f){w.z, w.w};   // r
        }
    } else {
        const float2* wsrc = wqpk + (size_t)cg*864 + 288;   // wq ci 32..95
        for (int i = threadIdx.x; i < 576; i += 256) {
            float2 w = wsrc[i];
            lws[i] = (v2f){w.x, w.y};
        }
        if (threadIdx.x < 32) {
            int ci = threadIdx.x;
            lfa[ci] = (v2f){wat[ci*32+co0], wat[ci*32+co0+1]};
            lfb[ci] = (v2f){wbt[ci*32+co0], wbt[ci*32+co0+1]};
            lfc[ci] = (v2f){wct[ci*32+co0], wct[ci*32+co0+1]};
        }
    }
    __syncthreads();
    int sp2 = blockIdx.x*256 + threadIdx.x;
    if (sp2 >= 48*Wd) return;
    int rp = sp2 / Wd;
    int lx = sp2 - rp*Wd;
    int y0 = rp*2;
    int gx = d + lx;
    size_t poff = (size_t)(y0+1)*PW + (gx+1);
    int ub = y0*W2 + gx;

    if (job == 0) {
        // marching zero col for rhpad (left pad of this iteration's q conv)
        if (lx == 0) {
            #pragma unroll
            for (int j = 0; j < 2; ++j) {
                rhpad[(size_t)(co0+j)*PSL + poff - 1]      = 0.f;
                rhpad[(size_t)(co0+j)*PSL + poff + PW - 1] = 0.f;
            }
        }
        // z/r conv: pass 0 = hworkA (ci 0..31), pass 1 = featA (ci 32..63)
        v2f az0 = (v2f){bz[co0], bz[co0+1]}, az1 = az0;
        v2f ar0 = (v2f){br[co0], br[co0+1]}, ar1 = ar0;
        #pragma unroll
        for (int pass = 0; pass < 2; ++pass) {
            const float* p = (pass == 0 ? hworkA : featA) + poff;
            const v2f* wz = lws + pass*288;
            const v2f* wr = lws + 576 + pass*288;
            #pragma unroll 2
            for (int ci = 0; ci < 32; ++ci) {
                float v[12];
                #pragma unroll
                for (int r = 0; r < 4; ++r) {
                    v[r*3+0] = p[(r-1)*PW - 1];
                    v[r*3+1] = p[(r-1)*PW    ];
                    v[r*3+2] = p[(r-1)*PW + 1];
                }
                #pragma unroll
                for (int k = 0; k < 9; ++k) {
                    int ky = k/3, kx = k - 3*ky;
                    float t0 = v[ky*3+kx];
                    float t1 = v[(ky+1)*3+kx];
                    v2f wzk = wz[k], wrk = wr[k];
                    az0 += wzk*(v2f){t0,t0}; az1 += wzk*(v2f){t1,t1};
                    ar0 += wrk*(v2f){t0,t0}; ar1 += wrk*(v2f){t1,t1};
                }
                p += PSL;
                wz += 9; wr += 9;
            }
        }
        v2f z0, z1, r0, r1;
        z0.x = 1.f/(1.f + __expf(-az0.x)); z0.y = 1.f/(1.f + __expf(-az0.y));
        z1.x = 1.f/(1.f + __expf(-az1.x)); z1.y = 1.f/(1.f + __expf(-az1.y));
        r0.x = 1.f/(1.f + __expf(-ar0.x)); r0.y = 1.f/(1.f + __expf(-ar0.y));
        r1.x = 1.f/(1.f + __expf(-ar1.x)); r1.y = 1.f/(1.f + __expf(-ar1.y));
        float h00 = hworkA[(size_t)co0*PSL + poff];
        float h01 = hworkA[(size_t)(co0+1)*PSL + poff];
        float h10 = hworkA[(size_t)co0*PSL + poff + PW];
        float h11 = hworkA[(size_t)(co0+1)*PSL + poff + PW];
        zbuf[(size_t)co0*NP2 + ub]          = z0.x;
        zbuf[(size_t)(co0+1)*NP2 + ub]      = z0.y;
        zbuf[(size_t)co0*NP2 + ub + W2]     = z1.x;
        zbuf[(size_t)(co0+1)*NP2 + ub + W2] = z1.y;
        rhpad[(size_t)co0*PSL + poff]          = r0.x*h00;
        rhpad[(size_t)(co0+1)*PSL + poff]      = r0.y*h01;
        rhpad[(size_t)co0*PSL + poff + PW]     = r1.x*h10;
        rhpad[(size_t)(co0+1)*PSL + poff + PW] = r1.y*h11;
    } else {
        // feat(d+1) -> featB; col d (lx==0) is its left-halo zero col
        int dn = d + 1;
        if (dn < ND) {
            if (lx == 0) {
                #pragma unroll
                for (int j = 0; j < 2; ++j) {
                    featB[(size_t)(co0+j)*PSL + poff]      = 0.f;
                    featB[(size_t)(co0+j)*PSL + poff + PW] = 0.f;
                }
            } else {
                v2f f0 = (v2f){bfc[co0], bfc[co0+1]};
                v2f f1 = f0;
                int base1 = y0*W2 + gx;
                #pragma unroll 2
                for (int ci = 0; ci < 32; ++ci) {
                    float a1 = fmap1[ci*NP2 + base1];
                    float a2 = fmap1[ci*NP2 + base1 + W2];
                    float b1 = fmap2[ci*NP2 + base1 - dn];
                    float b2 = fmap2[ci*NP2 + base1 + W2 - dn];
                    v2f wa = lfa[ci], wb = lfb[ci], wc = lfc[ci];
                    f0 += wa*(v2f){a1,a1} + wb*(v2f){b1,b1} + wc*(v2f){a1*b1,a1*b1};
                    f1 += wa*(v2f){a2,a2} + wb*(v2f){b2,b2} + wc*(v2f){a2*b2,a2*b2};
                }
                featB[(size_t)co0*PSL + poff]          = f0.x;
                featB[(size_t)(co0+1)*PSL + poff]      = f0.y;
                featB[(size_t)co0*PSL + poff + PW]     = f1.x;
                featB[(size_t)(co0+1)*PSL + poff + PW] = f1.y;
            }
        }
        // q partial: pass 0 = hworkA (wq ci 32..63), pass 1 = featA (wq ci 64..95)
        v2f a0 = (v2f){0.f, 0.f};
        v2f a1 = a0;
        #pragma unroll
        for (int pass = 0; pass < 2; ++pass) {
            const float* p = (pass == 0 ? hworkA : featA) + poff;
            const v2f* wp = lws + pass*288;
            #pragma unroll 2
            for (int ci = 0; ci < 32; ++ci) {
                float v[12];
                #pragma unroll
                for (int r = 0; r < 4; ++r) {
                    v[r*3+0] = p[(r-1)*PW - 1];
                    v[r*3+1] = p[(r-1)*PW    ];
                    v[r*3+2] = p[(r-1)*PW + 1];
                }
                #pragma unroll
                for (int k = 0; k < 9; ++k) {
                    int ky = k/3, kx = k - 3*ky;
                    float t0 = v[ky*3+kx];
                    float t1 = v[(ky+1)*3+kx];
                    v2f wk = wp[k];
                    a0 += wk*(v2f){t0,t0};
                    a1 += wk*(v2f){t1,t1};
                }
                p += PSL;
                wp += 9;
            }
        }
        qpart[(size_t)co0*NP2 + ub]          = a0.x;
        qpart[(size_t)(co0+1)*NP2 + ub]      = a0.y;
        qpart[(size_t)co0*NP2 + ub + W2]     = a1.x;
        qpart[(size_t)(co0+1)*NP2 + ub + W2] = a1.y;
    }
}

// q_fin: q's rh-pass (wq ci 0..31) + qpart + bias -> tanh -> GRU update.
// grid dim3(nblk, 16)
__global__ __launch_bounds__(256, 4)
void q_fin(const float* __restrict__ rhpad, const float* __restrict__ hworkA,
           const float* __restrict__ zbuf, const float* __restrict__ qpart,
           const float2* __restrict__ wqpk, const float* __restrict__ bq,
           float* __restrict__ hfinal, float* __restrict__ hworkB, int d, int Wd) {
    __shared__ v2f lw[288];
    int cg  = blockIdx.y;
    int co0 = cg*2;
    {
        const float2* wsrc = wqpk + (size_t)cg*864;   // wq ci 0..31
        for (int i = threadIdx.x; i < 288; i += 256) {
            float2 w = wsrc[i];
            lw[i] = (v2f){w.x, w.y};
        }
    }
    __syncthreads();
    int sp2 = blockIdx.x*256 + threadIdx.x;
    if (sp2 >= 48*Wd) return;
    int rp = sp2 / Wd;
    int lx = sp2 - rp*Wd;
    int y0 = rp*2;
    int gx = d + lx;
    size_t poff = (size_t)(y0+1)*PW + (gx+1);
    int ub = y0*W2 + gx;

    v2f a0 = (v2f){bq[co0], bq[co0+1]};
    v2f a1 = a0;
    {
        const float* p = rhpad + poff;
        const v2f* wp = lw;
        #pragma unroll 2
        for (int ci = 0; ci < 32; ++ci) {
            float v[12];
            #pragma unroll
            for (int r = 0; r < 4; ++r) {
                v[r*3+0] = p[(r-1)*PW - 1];
                v[r*3+1] = p[(r-1)*PW    ];
                v[r*3+2] = p[(r-1)*PW + 1];
            }
            #pragma unroll
            for (int k = 0; k < 9; ++k) {
                int ky = k/3, kx = k - 3*ky;
                float t0 = v[ky*3+kx];
                float t1 = v[(ky+1)*3+kx];
                v2f wk = wp[k];
                a0 += wk*(v2f){t0,t0};
                a1 += wk*(v2f){t1,t1};
            }
            p += PSL;
            wp += 9;
        }
    }
    a0.x += qpart[(size_t)co0*NP2 + ub];
    a0.y += qpart[(size_t)(co0+1)*NP2 + ub];
    a1.x += qpart[(size_t)co0*NP2 + ub + W2];
    a1.y += qpart[(size_t)(co0+1)*NP2 + ub + W2];
    float q00 = tanhf(a0.x), q01 = tanhf(a0.y);
    float q10 = tanhf(a1.x), q11 = tanhf(a1.y);
    #pragma unroll
    for (int j = 0; j < 2; ++j) {
        float qa = (j == 0) ? q00 : q01;
        float qb = (j == 0) ? q10 : q11;
        size_t pidx = (size_t)(co0+j)*PSL + poff;
        size_t uidx = (size_t)(co0+j)*NP2 + ub;
        float z_a = zbuf[uidx];
        float z_b = zbuf[uidx + W2];
        float h_a = hworkA[pidx];
        float h_b = hworkA[pidx + PW];
        float hn_a = (1.f - z_a)*h_a + z_a*qa;
        float hn_b = (1.f - z_b)*h_b + z_b*qb;
        if (lx == 0 || d == ND-1) {
            hfinal[pidx]      = hn_a;
            hfinal[pidx + PW] = hn_b;
        }
        hworkB[pidx]      = (lx == 0) ? 0.f : hn_a;
        hworkB[pidx + PW] = (lx == 0) ? 0.f : hn_b;
    }
}

// ---------------- disparity head ----------------

// 3x3 conv 32->64 + relu on padded hfinal; grid dim3(30, 16); thread: 2 rows x 4 co
__global__ __launch_bounds__(256, 4)
void disp1_v6(const float* __restrict__ hfinal, const float* __restrict__ wt,
              const float* __restrict__ b, float* __restrict__ out) {
    __shared__ float4 lw[288];   // [ci*9+k] -> 4 co weights
    int cg  = blockIdx.y;
    int co0 = cg*4;
    for (int i = threadIdx.x; i < 288; i += 256)
        lw[i] = *(const float4*)&wt[i*64 + co0];
    __syncthreads();
    int sp2 = blockIdx.x*256 + threadIdx.x;   // 0..7679
    int y0 = (sp2 / W2)*2;
    int gx = sp2 % W2;
    size_t poff = (size_t)(y0+1)*PW + (gx+1);
    float4 bb = *(const float4*)&b[co0];
    float acc0[4] = {bb.x, bb.y, bb.z, bb.w};
    float acc1[4] = {bb.x, bb.y, bb.z, bb.w};
    const float* p = hfinal + poff;
    #pragma unroll 2
    for (int ci = 0; ci < 32; ++ci) {
        float v[12];
        #pragma unroll
        for (int r = 0; r < 4; ++r) {
            v[r*3+0] = p[(r-1)*PW - 1];
            v[r*3+1] = p[(r-1)*PW    ];
            v[r*3+2] = p[(r-1)*PW + 1];
        }
        #pragma unroll
        for (int k = 0; k < 9; ++k) {
            int ky = k/3, kx = k - 3*ky;
            float t0 = v[ky*3+kx];
            float t1 = v[(ky+1)*3+kx];
            float4 w = lw[ci*9+k];
            acc0[0] += t0*w.x; acc0[1] += t0*w.y; acc0[2] += t0*w.z; acc0[3] += t0*w.w;
            acc1[0] += t1*w.x; acc1[1] += t1*w.y; acc1[2] += t1*w.z; acc1[3] += t1*w.w;
        }
        p += PSL;
    }
    int ub = y0*W2 + gx;
    #pragma unroll
    for (int j = 0; j < 4; ++j) {
        out[(co0+j)*NP2 + ub]      = fmaxf(acc0[j], 0.f);
        out[(co0+j)*NP2 + ub + W2] = fmaxf(acc1[j], 0.f);
    }
}

__global__ void disp2_part_kernel(const float* __restrict__ in, const float* __restrict__ w,
                                  float* __restrict__ part) {
    __shared__ float lw[8*9];
    int g  = blockIdx.x / NBLK2;
    int sp = (blockIdx.x % NBLK2)*256 + threadIdx.x;
    if (threadIdx.x < 72) lw[threadIdx.x] = w[g*72 + threadIdx.x];
    __syncthreads();
    int y = sp / W2, x = sp % W2;
    float acc = 0.f;
    #pragma unroll
    for (int ci = 0; ci < 8; ++ci) {
        const float* ip = in + (g*8 + ci)*NP2;
        #pragma unroll
        for (int dy = 0; dy < 3; ++dy) {
            int ys = y+dy-1; if ((unsigned)ys >= (unsigned)H2) continue;
            const float* row = ip + ys*W2;
            #pragma unroll
            for (int dx = 0; dx < 3; ++dx) {
                int xs = x+dx-1; if ((unsigned)xs >= (unsigned)W2) continue;
                acc += lw[ci*9+dy*3+dx] * row[xs];
            }
        }
    }
    part[g*NP2 + sp] = acc;
}

__global__ void disp2_comb_kernel(const float* __restrict__ part, const float* __restrict__ b,
                                  float* __restrict__ out) {
    int sp = blockIdx.x*256 + threadIdx.x;
    float acc = b[0];
    #pragma unroll
    for (int g = 0; g < 8; ++g) acc += part[g*NP2 + sp];
    out[sp] = -acc;
}

// ---------------- launch ----------------

extern "C" void kernel_launch(void* const* d_in, const int* in_sizes, int n_in,
                              void* d_out, int out_size, void* d_ws, size_t ws_size,
                              hipStream_t stream) {
    const float* image1   = (const float*)d_in[0];
    const float* image2   = (const float*)d_in[1];
    const float* fnet_w1  = (const float*)d_in[2];
    const float* fnet_b1  = (const float*)d_in[3];
    const float* fnet_w2  = (const float*)d_in[4];
    const float* fnet_b2  = (const float*)d_in[5];
    const float* fnet_w3  = (const float*)d_in[6];
    const float* fnet_b3  = (const float*)d_in[7];
    const float* cnet_w1  = (const float*)d_in[8];
    const float* cnet_b1  = (const float*)d_in[9];
    const float* cnet_w2  = (const float*)d_in[10];
    const float* cnet_b2  = (const float*)d_in[11];
    const float* cnet_w3  = (const float*)d_in[12];
    const float* cnet_b3  = (const float*)d_in[13];
    const float* bform_a  = (const float*)d_in[14];
    const float* bform_b  = (const float*)d_in[15];
    const float* bform_cd_w = (const float*)d_in[16];
    const float* bform_cd_b = (const float*)d_in[17];
    const float* gru_wz   = (const float*)d_in[18];
    const float* gru_bz   = (const float*)d_in[19];
    const float* gru_wr   = (const float*)d_in[20];
    const float* gru_br   = (const float*)d_in[21];
    const float* gru_wq   = (const float*)d_in[22];
    const float* gru_bq   = (const float*)d_in[23];
    const float* disp_w1  = (const float*)d_in[24];
    const float* disp_b1  = (const float*)d_in[25];
    const float* disp_w2  = (const float*)d_in[26];
    const float* disp_b2  = (const float*)d_in[27];

    float* ws = (float*)d_ws;
    size_t o = 0;
    float* e1f    = ws + o; o += (size_t)32*NP1;
    float* e1c    = ws + o; o += (size_t)32*NP1;
    float* e1i2   = ws + o; o += (size_t)32*NP1;
    float* e2f    = ws + o; o += CHW;
    float* e2c    = ws + o; o += CHW;
    float* e2i2   = ws + o; o += CHW;
    float* fmap1  = ws + o; o += CHW;
    float* fmap2  = ws + o; o += CHW;
    float* hidden = ws + o; o += CHW;
    float* zbuf   = ws + o; o += CHW;
    float* qpart  = ws + o; o += CHW;
    float* hwork0 = ws + o; o += PCHW;
    /* the next 5 padded buffers are contiguous -> one zero_buf */
    float* hwork1 = ws + o; o += PCHW;
    float* rhpad  = ws + o; o += PCHW;
    float* feat0  = ws + o; o += PCHW;
    float* feat1  = ws + o; o += PCHW;
    float* hfinal = ws + o; o += PCHW;
    float* stats  = ws + o; o += 384;
    float* wzrpk  = ws + o; o += 16*64*9*4;
    float* wqpk   = ws + o; o += 16*96*9*2;
    float* we1f   = ws + o; o += 3*49*32;
    float* we1c   = ws + o; o += 3*49*32;
    float* we2f   = ws + o; o += 32*9*32;
    float* we2c   = ws + o; o += 32*9*32;
    float* w3f    = ws + o; o += 32*32;
    float* w3c    = ws + o; o += 32*32;
    float* wat    = ws + o; o += 32*32;
    float* wbt    = ws + o; o += 32*32;
    float* wct    = ws + o; o += 32*32;
    float* wd1t   = ws + o; o += 32*9*64;
    float* disp1buf  = e1f;  // e1f dead after encoders (64*NP2 <= 32*NP1)
    float* disp2part = e1c;  // e1c dead after encoders

    // --- prep (one launch; zeroes stats) ---
    prep_all<<<(74816 + 255)/256, 256, 0, stream>>>(
        fnet_w1, cnet_w1, fnet_w2, cnet_w2, fnet_w3, cnet_w3,
        bform_a, bform_b, bform_cd_w, disp_w1, gru_wz, gru_wr, gru_wq,
        we1f, we1c, we2f, we2c, w3f, w3c, wat, wbt, wct, wd1t,
        (float4*)wzrpk, (float2*)wqpk, stats);

    // --- encoders: 3 independent chains merged per stage (5 launches total) ---
    conv7s2_all<<<dim3(NP1/256, 12), 256, 0, stream>>>(image1, image2, we1f, we1c,
                                                       fnet_b1, cnet_b1, e1f, e1c, e1i2);
    stats3_kernel<<<dim3(256, 3), 256, 0, stream>>>(e1f, e1c, e1i2, NP1,
                                                    stats+0, stats+64, stats+256);
    conv3s2_all<<<dim3(NBLK2, 12), 256, 0, stream>>>(e1f, e1c, e1i2, stats,
                                                     we2f, we2c, fnet_b2, cnet_b2,
                                                     e2f, e2c, e2i2);
    stats3_kernel<<<dim3(256, 3), 256, 0, stream>>>(e2f, e2c, e2i2, NP2,
                                                    stats+128, stats+192, stats+320);
    conv1x1_all<<<dim3(NBLK2, 12), 256, 0, stream>>>(e2f, e2c, e2i2, stats,
                                                     w3f, w3c, fnet_b3, cnet_b3,
                                                     fmap1, hidden, fmap2);

    // --- padded working buffers ---
    zero_buf_kernel<<<2048, 256, 0, stream>>>(hwork1, 5*PCHW);  // hwork1..hfinal contiguous
    pad_init_kernel<<<(32*PSL+255)/256, 256, 0, stream>>>(hidden, hwork0);
    feat0_pad_kernel<<<4*NBLK2, 256, 0, stream>>>(fmap1, fmap2, wat, wbt, wct,
                                                  bform_cd_b, feat0);

    // --- sequential GRU sweep: 2 launches per iteration, pass-split for occupancy ---
    float* hwA = hwork0; float* hwB = hwork1;
    float* ftA = feat0;  float* ftB = feat1;
    for (int d = 0; d < ND; ++d) {
        int Wd = W2 - d;
        int nblk = (48*Wd + 255)/256;
        zrq_a<<<dim3(nblk, 32), 256, 0, stream>>>(hwA, ftA, fmap1, fmap2,
                                                  (const float4*)wzrpk, (const float2*)wqpk,
                                                  wat, wbt, wct, bform_cd_b,
                                                  gru_bz, gru_br, zbuf, rhpad, ftB, qpart,
                                                  d, Wd);
        q_fin<<<dim3(nblk, 16), 256, 0, stream>>>(rhpad, hwA, zbuf, qpart,
                                                  (const float2*)wqpk, gru_bq,
                                                  hfinal, hwB, d, Wd);
        float* t;
        t = hwA; hwA = hwB; hwB = t;
        t = ftA; ftA = ftB; ftB = t;
    }

    // --- disparity head (reads padded hfinal) ---
    disp1_v6<<<dim3(30, 16), 256, 0, stream>>>(hfinal, wd1t, disp_b1, disp1buf);
    disp2_part_kernel<<<8*NBLK2, 256, 0, stream>>>(disp1buf, disp_w2, disp2part);
    disp2_comb_kernel<<<NBLK2, 256, 0, stream>>>(disp2part, disp_b2, (float*)d_out);
}

// Round 20
// 2552.994 us; speedup vs baseline: 1.5735x; 1.0004x over previous
//
#include <hip/hip_runtime.h>
#include <math.h>

#define H0 384
#define W0 640
#define H1 192
#define W1 320
#define H2 96
#define W2 160
#define NP1 (H1*W1)   /* 61440 */
#define NP2 (H2*W2)   /* 15360 */
#define ND  48        /* MAX_DISP/4 */
#define NBLK2 (NP2/256)  /* 60 */
#define CHW ((size_t)32*NP2)
/* padded (halo=1) layout, global coords */
#define PW 162
#define PH 98
#define PSL (PH*PW)            /* 15876 */
#define PCHW ((size_t)32*PSL)  /* 508032 */

typedef float v2f __attribute__((ext_vector_type(2)));
typedef float f4u __attribute__((ext_vector_type(4), aligned(4)));   // 4B-aligned float4

// ---------------- generic prep ----------------

__global__ void zero_buf_kernel(float* __restrict__ p, size_t n) {
    size_t i = (size_t)blockIdx.x*256 + threadIdx.x;
    size_t stride = (size_t)gridDim.x*256;
    for (; i < n; i += stride) p[i] = 0.f;
}

__device__ __forceinline__ void twr_dev(const float* __restrict__ in, float* __restrict__ out,
                                        int idx, int CI, int K, int CO) {
    int co = idx % CO;
    int t  = idx / CO;
    int k  = t % K;
    int ci = t / K;
    out[idx] = in[(co*CI + ci)*K + k];
}

// single launch: all weight transposes + packs + stats zero (74816 items)
__global__ void prep_all(const float* __restrict__ fnet_w1, const float* __restrict__ cnet_w1,
                         const float* __restrict__ fnet_w2, const float* __restrict__ cnet_w2,
                         const float* __restrict__ fnet_w3, const float* __restrict__ cnet_w3,
                         const float* __restrict__ bform_a, const float* __restrict__ bform_b,
                         const float* __restrict__ bform_cd_w, const float* __restrict__ disp_w1,
                         const float* __restrict__ gru_wz, const float* __restrict__ gru_wr,
                         const float* __restrict__ gru_wq,
                         float* __restrict__ we1f, float* __restrict__ we1c,
                         float* __restrict__ we2f, float* __restrict__ we2c,
                         float* __restrict__ w3f, float* __restrict__ w3c,
                         float* __restrict__ wat, float* __restrict__ wbt,
                         float* __restrict__ wct, float* __restrict__ wd1t,
                         float4* __restrict__ wzrpk, float2* __restrict__ wqpk,
                         float* __restrict__ stats) {
    int i = blockIdx.x*256 + threadIdx.x;
    if (i < 4704) { twr_dev(fnet_w1, we1f, i, 3, 49, 32); return; }
    i -= 4704;
    if (i < 4704) { twr_dev(cnet_w1, we1c, i, 3, 49, 32); return; }
    i -= 4704;
    if (i < 9216) { twr_dev(fnet_w2, we2f, i, 32, 9, 32); return; }
    i -= 9216;
    if (i < 9216) { twr_dev(cnet_w2, we2c, i, 32, 9, 32); return; }
    i -= 9216;
    if (i < 1024) { twr_dev(fnet_w3, w3f, i, 32, 1, 32); return; }
    i -= 1024;
    if (i < 1024) { twr_dev(cnet_w3, w3c, i, 32, 1, 32); return; }
    i -= 1024;
    if (i < 1024) { twr_dev(bform_a, wat, i, 32, 1, 32); return; }
    i -= 1024;
    if (i < 1024) { twr_dev(bform_b, wbt, i, 32, 1, 32); return; }
    i -= 1024;
    if (i < 1024) { twr_dev(bform_cd_w, wct, i, 32, 1, 32); return; }
    i -= 1024;
    if (i < 18432) { twr_dev(disp_w1, wd1t, i, 32, 9, 64); return; }
    i -= 18432;
    if (i < 9216) {   // packed z/r: [cg][ci<64][k] = {z0,z1,r0,r1}
        int k  = i % 9;
        int ci = (i/9) % 64;
        int cg = i / (9*64);
        int co0 = cg*2, co1 = co0 + 1;
        float z0, z1, r0, r1;
        if (ci < 32) {
            z0 = gru_wz[(co0*96 + ci)*9 + k] + gru_wz[(co0*96 + ci + 32)*9 + k];
            z1 = gru_wz[(co1*96 + ci)*9 + k] + gru_wz[(co1*96 + ci + 32)*9 + k];
            r0 = gru_wr[(co0*96 + ci)*9 + k] + gru_wr[(co0*96 + ci + 32)*9 + k];
            r1 = gru_wr[(co1*96 + ci)*9 + k] + gru_wr[(co1*96 + ci + 32)*9 + k];
        } else {
            z0 = gru_wz[(co0*96 + ci + 32)*9 + k];
            z1 = gru_wz[(co1*96 + ci + 32)*9 + k];
            r0 = gru_wr[(co0*96 + ci + 32)*9 + k];
            r1 = gru_wr[(co1*96 + ci + 32)*9 + k];
        }
        wzrpk[i] = make_float4(z0, z1, r0, r1);
        return;
    }
    i -= 9216;
    if (i < 13824) {  // packed q: [cg][ci<96][k] = {co0, co1}
        int k  = i % 9;
        int ci = (i/9) % 96;
        int cg = i / (9*96);
        wqpk[i] = make_float2(gru_wq[((cg*2)*96 + ci)*9 + k], gru_wq[((cg*2+1)*96 + ci)*9 + k]);
        return;
    }
    i -= 13824;
    if (i < 384) stats[i] = 0.f;
}

// hwork[c][py][px] = hidden[c][py-1][px-1] interior, 0 halo
__global__ void pad_init_kernel(const float* __restrict__ hidden, float* __restrict__ hwork) {
    int idx = blockIdx.x*256 + threadIdx.x;
    if (idx >= 32*PSL) return;
    int c = idx / PSL;
    int r = idx % PSL;
    int py = r / PW, px = r % PW;
    int y = py - 1, x = px - 1;
    float v = 0.f;
    if ((unsigned)y < (unsigned)H2 && (unsigned)x < (unsigned)W2)
        v = hidden[c*NP2 + y*W2 + x];
    hwork[idx] = v;
}

// ---------------- merged encoder kernels (3 independent nets per launch) ----------------

// 7x7 s2: grid dim3(240, 12): net = y/4 (0=fnet img1, 1=cnet img1, 2=fnet img2); cg = y%4
__global__ __launch_bounds__(256, 8)
void conv7s2_all(const float* __restrict__ img1, const float* __restrict__ img2,
                 const float* __restrict__ wtf, const float* __restrict__ wtc,
                 const float* __restrict__ bf, const float* __restrict__ bc,
                 float* __restrict__ e1f, float* __restrict__ e1c, float* __restrict__ e1i2) {
    int net = blockIdx.y >> 2;
    int co8 = (blockIdx.y & 3)*8;
    const float* img = (net == 2) ? img2 : img1;
    const float* wt  = (net == 1) ? wtc : wtf;
    const float* bb  = (net == 1) ? bc  : bf;
    float* out = (net == 0) ? e1f : (net == 1 ? e1c : e1i2);
    int sp = blockIdx.x*256 + threadIdx.x;
    int oy = sp / W1, ox = sp % W1;
    float acc[8];
    #pragma unroll
    for (int j = 0; j < 8; ++j) acc[j] = bb[co8+j];
    for (int ci = 0; ci < 3; ++ci) {
        for (int ky = 0; ky < 7; ++ky) {
            int iy = 2*oy - 3 + ky;
            if ((unsigned)iy >= (unsigned)H0) continue;
            const float* row  = img + ci*(H0*W0) + iy*W0;
            const float* wrow = wt + (ci*49 + ky*7)*32 + co8;
            #pragma unroll
            for (int kx = 0; kx < 7; ++kx) {
                int ix = 2*ox - 3 + kx;
                if ((unsigned)ix >= (unsigned)W0) continue;
                float v = row[ix]*(2.0f/255.0f) - 1.0f;
                const float4* wp = (const float4*)(wrow + kx*32);
                float4 w0 = wp[0], w1 = wp[1];
                acc[0] += v*w0.x; acc[1] += v*w0.y; acc[2] += v*w0.z; acc[3] += v*w0.w;
                acc[4] += v*w1.x; acc[5] += v*w1.y; acc[6] += v*w1.z; acc[7] += v*w1.w;
            }
        }
    }
    #pragma unroll
    for (int j = 0; j < 8; ++j) out[(co8+j)*NP1 + sp] = acc[j];
}

// stats for 3 buffers in one launch; grid dim3(256, 3)
__global__ void stats3_kernel(const float* __restrict__ b0, const float* __restrict__ b1,
                              const float* __restrict__ b2, int N,
                              float* __restrict__ st0, float* __restrict__ st1,
                              float* __restrict__ st2) {
    int job = blockIdx.y;
    const float* x = (job == 0) ? b0 : (job == 1 ? b1 : b2);
    float* st      = (job == 0) ? st0 : (job == 1 ? st1 : st2);
    int c = blockIdx.x >> 3, sl = blockIdx.x & 7;
    int chunk = N >> 3;
    const float4* p = (const float4*)(x + (size_t)c*N + (size_t)sl*chunk);
    int n4 = chunk >> 2;
    float s = 0.f, s2 = 0.f;
    for (int i = threadIdx.x; i < n4; i += 256) {
        float4 v = p[i];
        s  += v.x + v.y + v.z + v.w;
        s2 += v.x*v.x + v.y*v.y + v.z*v.z + v.w*v.w;
    }
    __shared__ float sh1[256], sh2[256];
    sh1[threadIdx.x] = s; sh2[threadIdx.x] = s2;
    __syncthreads();
    for (int o = 128; o > 0; o >>= 1) {
        if (threadIdx.x < o) { sh1[threadIdx.x] += sh1[threadIdx.x+o]; sh2[threadIdx.x] += sh2[threadIdx.x+o]; }
        __syncthreads();
    }
    if (threadIdx.x == 0) { atomicAdd(&st[2*c], sh1[0]); atomicAdd(&st[2*c+1], sh2[0]); }
}

// 3x3 s2 with fused input inorm+relu, 3 nets; grid dim3(60, 12)
__global__ void conv3s2_all(const float* __restrict__ e1f, const float* __restrict__ e1c,
                            const float* __restrict__ e1i2, const float* __restrict__ stats,
                            const float* __restrict__ we2f, const float* __restrict__ we2c,
                            const float* __restrict__ fb2, const float* __restrict__ cb2,
                            float* __restrict__ e2f, float* __restrict__ e2c,
                            float* __restrict__ e2i2) {
    int net = blockIdx.y >> 2;
    int co8 = (blockIdx.y & 3)*8;
    const float* in = (net == 0) ? e1f : (net == 1 ? e1c : e1i2);
    const float* st = (net == 0) ? stats+0 : (net == 1 ? stats+64 : stats+256);
    const float* wt = (net == 1) ? we2c : we2f;
    const float* b  = (net == 1) ? cb2 : fb2;
    float* out = (net == 0) ? e2f : (net == 1 ? e2c : e2i2);
    int sp = blockIdx.x*256 + threadIdx.x;
    int oy = sp / W2, ox = sp % W2;
    float acc[8];
    #pragma unroll
    for (int j = 0; j < 8; ++j) acc[j] = b[co8+j];
    for (int ci = 0; ci < 32; ++ci) {
        float m    = st[2*ci] * (1.0f/NP1);
        float var  = st[2*ci+1] * (1.0f/NP1) - m*m;
        float rstd = rsqrtf(var + 1e-5f);
        const float* ip  = in + ci*NP1;
        const float* wci = wt + ci*9*32 + co8;
        #pragma unroll
        for (int ky = 0; ky < 3; ++ky) {
            int iy = 2*oy - 1 + ky;
            if ((unsigned)iy >= (unsigned)H1) continue;
            const float* row = ip + iy*W1;
            #pragma unroll
            for (int kx = 0; kx < 3; ++kx) {
                int ix = 2*ox - 1 + kx;
                if ((unsigned)ix >= (unsigned)W1) continue;
                float t = fmaxf((row[ix] - m)*rstd, 0.f);
                const float4* wp = (const float4*)(wci + (ky*3+kx)*32);
                float4 w0 = wp[0], w1 = wp[1];
                acc[0] += t*w0.x; acc[1] += t*w0.y; acc[2] += t*w0.z; acc[3] += t*w0.w;
                acc[4] += t*w1.x; acc[5] += t*w1.y; acc[6] += t*w1.z; acc[7] += t*w1.w;
            }
        }
    }
    #pragma unroll
    for (int j = 0; j < 8; ++j) out[(co8+j)*NP2 + sp] = acc[j];
}

// 1x1 with fused input inorm+relu, 3 nets; grid dim3(60, 12); tanh on net 1
__global__ void conv1x1_all(const float* __restrict__ e2f, const float* __restrict__ e2c,
                            const float* __restrict__ e2i2, const float* __restrict__ stats,
                            const float* __restrict__ w3f, const float* __restrict__ w3c,
                            const float* __restrict__ fb3, const float* __restrict__ cb3,
                            float* __restrict__ fmap1, float* __restrict__ hiddenb,
                            float* __restrict__ fmap2) {
    int net = blockIdx.y >> 2;
    int co8 = (blockIdx.y & 3)*8;
    const float* in = (net == 0) ? e2f : (net == 1 ? e2c : e2i2);
    const float* st = (net == 0) ? stats+128 : (net == 1 ? stats+192 : stats+320);
    const float* wt = (net == 1) ? w3c : w3f;
    const float* b  = (net == 1) ? cb3 : fb3;
    float* out = (net == 0) ? fmap1 : (net == 1 ? hiddenb : fmap2);
    int sp = blockIdx.x*256 + threadIdx.x;
    float acc[8];
    #pragma unroll
    for (int j = 0; j < 8; ++j) acc[j] = b[co8+j];
    for (int ci = 0; ci < 32; ++ci) {
        float m    = st[2*ci] * (1.0f/NP2);
        float var  = st[2*ci+1] * (1.0f/NP2) - m*m;
        float rstd = rsqrtf(var + 1e-5f);
        float t = fmaxf((in[ci*NP2 + sp] - m)*rstd, 0.f);
        const float4* wp = (const float4*)(wt + ci*32 + co8);
        float4 w0 = wp[0], w1 = wp[1];
        acc[0] += t*w0.x; acc[1] += t*w0.y; acc[2] += t*w0.z; acc[3] += t*w0.w;
        acc[4] += t*w1.x; acc[5] += t*w1.y; acc[6] += t*w1.z; acc[7] += t*w1.w;
    }
    #pragma unroll
    for (int j = 0; j < 8; ++j) {
        float a = acc[j];
        if (net == 1) a = tanhf(a);
        out[(co8+j)*NP2 + sp] = a;
    }
}

// ---------------- feat(0) prologue (padded) ----------------

__global__ void feat0_pad_kernel(const float* __restrict__ fmap1, const float* __restrict__ fmap2,
                                 const float* __restrict__ wat, const float* __restrict__ wbt,
                                 const float* __restrict__ wct, const float* __restrict__ bc,
                                 float* __restrict__ featA) {
    int cg  = blockIdx.x / NBLK2;
    int sp  = (blockIdx.x % NBLK2)*256 + threadIdx.x;
    int y = sp / W2;
    int gx = sp % W2;
    int co8 = cg*8;
    float acc[8];
    #pragma unroll
    for (int j = 0; j < 8; ++j) acc[j] = bc[co8+j];
    for (int ci = 0; ci < 32; ++ci) {
        float f1 = fmap1[ci*NP2 + sp];
        float f2 = fmap2[ci*NP2 + sp];
        float f12 = f1*f2;
        const float4* ap = (const float4*)(wat + ci*32 + co8);
        const float4* bp = (const float4*)(wbt + ci*32 + co8);
        const float4* cp = (const float4*)(wct + ci*32 + co8);
        float4 a0 = ap[0], a1 = ap[1];
        float4 b0 = bp[0], b1 = bp[1];
        float4 c0 = cp[0], c1 = cp[1];
        acc[0] += f1*a0.x + f2*b0.x + f12*c0.x;
        acc[1] += f1*a0.y + f2*b0.y + f12*c0.y;
        acc[2] += f1*a0.z + f2*b0.z + f12*c0.z;
        acc[3] += f1*a0.w + f2*b0.w + f12*c0.w;
        acc[4] += f1*a1.x + f2*b1.x + f12*c1.x;
        acc[5] += f1*a1.y + f2*b1.y + f12*c1.y;
        acc[6] += f1*a1.z + f2*b1.z + f12*c1.z;
        acc[7] += f1*a1.w + f2*b1.w + f12*c1.w;
    }
    float* dst = featA + (size_t)(y+1)*PW + (gx+1);
    #pragma unroll
    for (int j = 0; j < 8; ++j) dst[(size_t)(co8+j)*PSL] = acc[j];
}

// ---------------- GRU loop kernels (compact-column domain, pass-split) ----------------
// grid dim3(nblk, 32): blockIdx.y = cg*2 + job.
//   job0: full z/r conv (zbuf, rhpad, rhpad zero col)
//   job1: q-partial over {hworkA (wq ci32..63), featA (wq ci64..95)} -> qpart; feat(d+1) -> featB

__global__ __launch_bounds__(256, 4)
void zrq_a(const float* __restrict__ hworkA, const float* __restrict__ featA,
           const float* __restrict__ fmap1, const float* __restrict__ fmap2,
           const float4* __restrict__ wzrpk, const float2* __restrict__ wqpk,
           const float* __restrict__ wat, const float* __restrict__ wbt,
           const float* __restrict__ wct, const float* __restrict__ bfc,
           const float* __restrict__ bz, const float* __restrict__ br,
           float* __restrict__ zbuf, float* __restrict__ rhpad,
           float* __restrict__ featB, float* __restrict__ qpart,
           int d, int Wd) {
    __shared__ v2f lws[1152];
    __shared__ v2f lfa[32], lfb[32], lfc[32];
    int cg  = blockIdx.y >> 1;
    int job = blockIdx.y & 1;
    int co0 = cg*2;
    if (job == 0) {
        const float4* wsrc = wzrpk + (size_t)cg*576;
        for (int i = threadIdx.x; i < 576; i += 256) {
            float4 w = wsrc[i];
            lws[i]       = (v2f){w.x, w.y};   // z
            lws[576 + i] = (v2f){w.z, w.w};   // r
        }
    } else {
        const float2* wsrc = wqpk + (size_t)cg*864 + 288;   // wq ci 32..95
        for (int i = threadIdx.x; i < 576; i += 256) {
            float2 w = wsrc[i];
            lws[i] = (v2f){w.x, w.y};
        }
        if (threadIdx.x < 32) {
            int ci = threadIdx.x;
            lfa[ci] = (v2f){wat[ci*32+co0], wat[ci*32+co0+1]};
            lfb[ci] = (v2f){wbt[ci*32+co0], wbt[ci*32+co0+1]};
            lfc[ci] = (v2f){wct[ci*32+co0], wct[ci*32+co0+1]};
        }
    }
    __syncthreads();
    int sp2 = blockIdx.x*256 + threadIdx.x;
    if (sp2 >= 48*Wd) return;
    int rp = sp2 / Wd;
    int lx = sp2 - rp*Wd;
    int y0 = rp*2;
    int gx = d + lx;
    size_t poff = (size_t)(y0+1)*PW + (gx+1);
    int ub = y0*W2 + gx;

    if (job == 0) {
        // marching zero col for rhpad (left pad of this iteration's q conv)
        if (lx == 0) {
            #pragma unroll
            for (int j = 0; j < 2; ++j) {
                rhpad[(size_t)(co0+j)*PSL + poff - 1]      = 0.f;
                rhpad[(size_t)(co0+j)*PSL + poff + PW - 1] = 0.f;
            }
        }
        // z/r conv: pass 0 = hworkA (ci 0..31), pass 1 = featA (ci 32..63)
        v2f az0 = (v2f){bz[co0], bz[co0+1]}, az1 = az0;
        v2f ar0 = (v2f){br[co0], br[co0+1]}, ar1 = ar0;
        #pragma unroll
        for (int pass = 0; pass < 2; ++pass) {
            const float* p = (pass == 0 ? hworkA : featA) + poff;
            const v2f* wz = lws + pass*288;
            const v2f* wr = lws + 576 + pass*288;
            #pragma unroll 2
            for (int ci = 0; ci < 32; ++ci) {
                float v[12];
                #pragma unroll
                for (int r = 0; r < 4; ++r) {
                    f4u t4 = *(const f4u*)(p + (r-1)*PW - 1);
                    v[r*3+0] = t4.x; v[r*3+1] = t4.y; v[r*3+2] = t4.z;
                }
                #pragma unroll
                for (int k = 0; k < 9; ++k) {
                    int ky = k/3, kx = k - 3*ky;
                    float t0 = v[ky*3+kx];
                    float t1 = v[(ky+1)*3+kx];
                    v2f wzk = wz[k], wrk = wr[k];
                    az0 += wzk*(v2f){t0,t0}; az1 += wzk*(v2f){t1,t1};
                    ar0 += wrk*(v2f){t0,t0}; ar1 += wrk*(v2f){t1,t1};
                }
                p += PSL;
                wz += 9; wr += 9;
            }
        }
        v2f z0, z1, r0, r1;
        z0.x = 1.f/(1.f + __expf(-az0.x)); z0.y = 1.f/(1.f + __expf(-az0.y));
        z1.x = 1.f/(1.f + __expf(-az1.x)); z1.y = 1.f/(1.f + __expf(-az1.y));
        r0.x = 1.f/(1.f + __expf(-ar0.x)); r0.y = 1.f/(1.f + __expf(-ar0.y));
        r1.x = 1.f/(1.f + __expf(-ar1.x)); r1.y = 1.f/(1.f + __expf(-ar1.y));
        float h00 = hworkA[(size_t)co0*PSL + poff];
        float h01 = hworkA[(size_t)(co0+1)*PSL + poff];
        float h10 = hworkA[(size_t)co0*PSL + poff + PW];
        float h11 = hworkA[(size_t)(co0+1)*PSL + poff + PW];
        zbuf[(size_t)co0*NP2 + ub]          = z0.x;
        zbuf[(size_t)(co0+1)*NP2 + ub]      = z0.y;
        zbuf[(size_t)co0*NP2 + ub + W2]     = z1.x;
        zbuf[(size_t)(co0+1)*NP2 + ub + W2] = z1.y;
        rhpad[(size_t)co0*PSL + poff]          = r0.x*h00;
        rhpad[(size_t)(co0+1)*PSL + poff]      = r0.y*h01;
        rhpad[(size_t)co0*PSL + poff + PW]     = r1.x*h10;
        rhpad[(size_t)(co0+1)*PSL + poff + PW] = r1.y*h11;
    } else {
        // feat(d+1) -> featB; col d (lx==0) is its left-halo zero col
        int dn = d + 1;
        if (dn < ND) {
            if (lx == 0) {
                #pragma unroll
                for (int j = 0; j < 2; ++j) {
                    featB[(size_t)(co0+j)*PSL + poff]      = 0.f;
                    featB[(size_t)(co0+j)*PSL + poff + PW] = 0.f;
                }
            } else {
                v2f f0 = (v2f){bfc[co0], bfc[co0+1]};
                v2f f1 = f0;
                int base1 = y0*W2 + gx;
                #pragma unroll 2
                for (int ci = 0; ci < 32; ++ci) {
                    float a1 = fmap1[ci*NP2 + base1];
                    float a2 = fmap1[ci*NP2 + base1 + W2];
                    float b1 = fmap2[ci*NP2 + base1 - dn];
                    float b2 = fmap2[ci*NP2 + base1 + W2 - dn];
                    v2f wa = lfa[ci], wb = lfb[ci], wc = lfc[ci];
                    f0 += wa*(v2f){a1,a1} + wb*(v2f){b1,b1} + wc*(v2f){a1*b1,a1*b1};
                    f1 += wa*(v2f){a2,a2} + wb*(v2f){b2,b2} + wc*(v2f){a2*b2,a2*b2};
                }
                featB[(size_t)co0*PSL + poff]          = f0.x;
                featB[(size_t)(co0+1)*PSL + poff]      = f0.y;
                featB[(size_t)co0*PSL + poff + PW]     = f1.x;
                featB[(size_t)(co0+1)*PSL + poff + PW] = f1.y;
            }
        }
        // q partial: pass 0 = hworkA (wq ci 32..63), pass 1 = featA (wq ci 64..95)
        v2f a0 = (v2f){0.f, 0.f};
        v2f a1 = a0;
        #pragma unroll
        for (int pass = 0; pass < 2; ++pass) {
            const float* p = (pass == 0 ? hworkA : featA) + poff;
            const v2f* wp = lws + pass*288;
            #pragma unroll 2
            for (int ci = 0; ci < 32; ++ci) {
                float v[12];
                #pragma unroll
                for (int r = 0; r < 4; ++r) {
                    f4u t4 = *(const f4u*)(p + (r-1)*PW - 1);
                    v[r*3+0] = t4.x; v[r*3+1] = t4.y; v[r*3+2] = t4.z;
                }
                #pragma unroll
                for (int k = 0; k < 9; ++k) {
                    int ky = k/3, kx = k - 3*ky;
                    float t0 = v[ky*3+kx];
                    float t1 = v[(ky+1)*3+kx];
                    v2f wk = wp[k];
                    a0 += wk*(v2f){t0,t0};
                    a1 += wk*(v2f){t1,t1};
                }
                p += PSL;
                wp += 9;
            }
        }
        qpart[(size_t)co0*NP2 + ub]          = a0.x;
        qpart[(size_t)(co0+1)*NP2 + ub]      = a0.y;
        qpart[(size_t)co0*NP2 + ub + W2]     = a1.x;
        qpart[(size_t)(co0+1)*NP2 + ub + W2] = a1.y;
    }
}

// q_fin: q's rh-pass (wq ci 0..31) + qpart + bias -> tanh -> GRU update.
// grid dim3(nblk, 16)
__global__ __launch_bounds__(256, 4)
void q_fin(const float* __restrict__ rhpad, const float* __restrict__ hworkA,
           const float* __restrict__ zbuf, const float* __restrict__ qpart,
           const float2* __restrict__ wqpk, const float* __restrict__ bq,
           float* __restrict__ hfinal, float* __restrict__ hworkB, int d, int Wd) {
    __shared__ v2f lw[288];
    int cg  = blockIdx.y;
    int co0 = cg*2;
    {
        const float2* wsrc = wqpk + (size_t)cg*864;   // wq ci 0..31
        for (int i = threadIdx.x; i < 288; i += 256) {
            float2 w = wsrc[i];
            lw[i] = (v2f){w.x, w.y};
        }
    }
    __syncthreads();
    int sp2 = blockIdx.x*256 + threadIdx.x;
    if (sp2 >= 48*Wd) return;
    int rp = sp2 / Wd;
    int lx = sp2 - rp*Wd;
    int y0 = rp*2;
    int gx = d + lx;
    size_t poff = (size_t)(y0+1)*PW + (gx+1);
    int ub = y0*W2 + gx;

    v2f a0 = (v2f){bq[co0], bq[co0+1]};
    v2f a1 = a0;
    {
        const float* p = rhpad + poff;
        const v2f* wp = lw;
        #pragma unroll 2
        for (int ci = 0; ci < 32; ++ci) {
            float v[12];
            #pragma unroll
            for (int r = 0; r < 4; ++r) {
                f4u t4 = *(const f4u*)(p + (r-1)*PW - 1);
                v[r*3+0] = t4.x; v[r*3+1] = t4.y; v[r*3+2] = t4.z;
            }
            #pragma unroll
            for (int k = 0; k < 9; ++k) {
                int ky = k/3, kx = k - 3*ky;
                float t0 = v[ky*3+kx];
                float t1 = v[(ky+1)*3+kx];
                v2f wk = wp[k];
                a0 += wk*(v2f){t0,t0};
                a1 += wk*(v2f){t1,t1};
            }
            p += PSL;
            wp += 9;
        }
    }
    a0.x += qpart[(size_t)co0*NP2 + ub];
    a0.y += qpart[(size_t)(co0+1)*NP2 + ub];
    a1.x += qpart[(size_t)co0*NP2 + ub + W2];
    a1.y += qpart[(size_t)(co0+1)*NP2 + ub + W2];
    float q00 = tanhf(a0.x), q01 = tanhf(a0.y);
    float q10 = tanhf(a1.x), q11 = tanhf(a1.y);
    #pragma unroll
    for (int j = 0; j < 2; ++j) {
        float qa = (j == 0) ? q00 : q01;
        float qb = (j == 0) ? q10 : q11;
        size_t pidx = (size_t)(co0+j)*PSL + poff;
        size_t uidx = (size_t)(co0+j)*NP2 + ub;
        float z_a = zbuf[uidx];
        float z_b = zbuf[uidx + W2];
        float h_a = hworkA[pidx];
        float h_b = hworkA[pidx + PW];
        float hn_a = (1.f - z_a)*h_a + z_a*qa;
        float hn_b = (1.f - z_b)*h_b + z_b*qb;
        if (lx == 0 || d == ND-1) {
            hfinal[pidx]      = hn_a;
            hfinal[pidx + PW] = hn_b;
        }
        hworkB[pidx]      = (lx == 0) ? 0.f : hn_a;
        hworkB[pidx + PW] = (lx == 0) ? 0.f : hn_b;
    }
}

// ---------------- disparity head ----------------

// 3x3 conv 32->64 + relu on padded hfinal; grid dim3(30, 16); thread: 2 rows x 4 co
__global__ __launch_bounds__(256, 4)
void disp1_v6(const float* __restrict__ hfinal, const float* __restrict__ wt,
              const float* __restrict__ b, float* __restrict__ out) {
    __shared__ float4 lw[288];   // [ci*9+k] -> 4 co weights
    int cg  = blockIdx.y;
    int co0 = cg*4;
    for (int i = threadIdx.x; i < 288; i += 256)
        lw[i] = *(const float4*)&wt[i*64 + co0];
    __syncthreads();
    int sp2 = blockIdx.x*256 + threadIdx.x;   // 0..7679
    int y0 = (sp2 / W2)*2;
    int gx = sp2 % W2;
    size_t poff = (size_t)(y0+1)*PW + (gx+1);
    float4 bb = *(const float4*)&b[co0];
    float acc0[4] = {bb.x, bb.y, bb.z, bb.w};
    float acc1[4] = {bb.x, bb.y, bb.z, bb.w};
    const float* p = hfinal + poff;
    #pragma unroll 2
    for (int ci = 0; ci < 32; ++ci) {
        float v[12];
        #pragma unroll
        for (int r = 0; r < 4; ++r) {
            f4u t4 = *(const f4u*)(p + (r-1)*PW - 1);
            v[r*3+0] = t4.x; v[r*3+1] = t4.y; v[r*3+2] = t4.z;
        }
        #pragma unroll
        for (int k = 0; k < 9; ++k) {
            int ky = k/3, kx = k - 3*ky;
            float t0 = v[ky*3+kx];
            float t1 = v[(ky+1)*3+kx];
            float4 w = lw[ci*9+k];
            acc0[0] += t0*w.x; acc0[1] += t0*w.y; acc0[2] += t0*w.z; acc0[3] += t0*w.w;
            acc1[0] += t1*w.x; acc1[1] += t1*w.y; acc1[2] += t1*w.z; acc1[3] += t1*w.w;
        }
        p += PSL;
    }
    int ub = y0*W2 + gx;
    #pragma unroll
    for (int j = 0; j < 4; ++j) {
        out[(co0+j)*NP2 + ub]      = fmaxf(acc0[j], 0.f);
        out[(co0+j)*NP2 + ub + W2] = fmaxf(acc1[j], 0.f);
    }
}

__global__ void disp2_part_kernel(const float* __restrict__ in, const float* __restrict__ w,
                                  float* __restrict__ part) {
    __shared__ float lw[8*9];
    int g  = blockIdx.x / NBLK2;
    int sp = (blockIdx.x % NBLK2)*256 + threadIdx.x;
    if (threadIdx.x < 72) lw[threadIdx.x] = w[g*72 + threadIdx.x];
    __syncthreads();
    int y = sp / W2, x = sp % W2;
    float acc = 0.f;
    #pragma unroll
    for (int ci = 0; ci < 8; ++ci) {
        const float* ip = in + (g*8 + ci)*NP2;
        #pragma unroll
        for (int dy = 0; dy < 3; ++dy) {
            int ys = y+dy-1; if ((unsigned)ys >= (unsigned)H2) continue;
            const float* row = ip + ys*W2;
            #pragma unroll
            for (int dx = 0; dx < 3; ++dx) {
                int xs = x+dx-1; if ((unsigned)xs >= (unsigned)W2) continue;
                acc += lw[ci*9+dy*3+dx] * row[xs];
            }
        }
    }
    part[g*NP2 + sp] = acc;
}

__global__ void disp2_comb_kernel(const float* __restrict__ part, const float* __restrict__ b,
                                  float* __restrict__ out) {
    int sp = blockIdx.x*256 + threadIdx.x;
    float acc = b[0];
    #pragma unroll
    for (int g = 0; g < 8; ++g) acc += part[g*NP2 + sp];
    out[sp] = -acc;
}

// ---------------- launch ----------------

extern "C" void kernel_launch(void* const* d_in, const int* in_sizes, int n_in,
                              void* d_out, int out_size, void* d_ws, size_t ws_size,
                              hipStream_t stream) {
    const float* image1   = (const float*)d_in[0];
    const float* image2   = (const float*)d_in[1];
    const float* fnet_w1  = (const float*)d_in[2];
    const float* fnet_b1  = (const float*)d_in[3];
    const float* fnet_w2  = (const float*)d_in[4];
    const float* fnet_b2  = (const float*)d_in[5];
    const float* fnet_w3  = (const float*)d_in[6];
    const float* fnet_b3  = (const float*)d_in[7];
    const float* cnet_w1  = (const float*)d_in[8];
    const float* cnet_b1  = (const float*)d_in[9];
    const float* cnet_w2  = (const float*)d_in[10];
    const float* cnet_b2  = (const float*)d_in[11];
    const float* cnet_w3  = (const float*)d_in[12];
    const float* cnet_b3  = (const float*)d_in[13];
    const float* bform_a  = (const float*)d_in[14];
    const float* bform_b  = (const float*)d_in[15];
    const float* bform_cd_w = (const float*)d_in[16];
    const float* bform_cd_b = (const float*)d_in[17];
    const float* gru_wz   = (const float*)d_in[18];
    const float* gru_bz   = (const float*)d_in[19];
    const float* gru_wr   = (const float*)d_in[20];
    const float* gru_br   = (const float*)d_in[21];
    const float* gru_wq   = (const float*)d_in[22];
    const float* gru_bq   = (const float*)d_in[23];
    const float* disp_w1  = (const float*)d_in[24];
    const float* disp_b1  = (const float*)d_in[25];
    const float* disp_w2  = (const float*)d_in[26];
    const float* disp_b2  = (const float*)d_in[27];

    float* ws = (float*)d_ws;
    size_t o = 0;
    float* e1f    = ws + o; o += (size_t)32*NP1;
    float* e1c    = ws + o; o += (size_t)32*NP1;
    float* e1i2   = ws + o; o += (size_t)32*NP1;
    float* e2f    = ws + o; o += CHW;
    float* e2c    = ws + o; o += CHW;
    float* e2i2   = ws + o; o += CHW;
    float* fmap1  = ws + o; o += CHW;
    float* fmap2  = ws + o; o += CHW;
    float* hidden = ws + o; o += CHW;
    float* zbuf   = ws + o; o += CHW;
    float* qpart  = ws + o; o += CHW;
    float* hwork0 = ws + o; o += PCHW;
    /* the next 5 padded buffers are contiguous -> one zero_buf */
    float* hwork1 = ws + o; o += PCHW;
    float* rhpad  = ws + o; o += PCHW;
    float* feat0  = ws + o; o += PCHW;
    float* feat1  = ws + o; o += PCHW;
    float* hfinal = ws + o; o += PCHW;
    float* stats  = ws + o; o += 384;
    float* wzrpk  = ws + o; o += 16*64*9*4;
    float* wqpk   = ws + o; o += 16*96*9*2;
    float* we1f   = ws + o; o += 3*49*32;
    float* we1c   = ws + o; o += 3*49*32;
    float* we2f   = ws + o; o += 32*9*32;
    float* we2c   = ws + o; o += 32*9*32;
    float* w3f    = ws + o; o += 32*32;
    float* w3c    = ws + o; o += 32*32;
    float* wat    = ws + o; o += 32*32;
    float* wbt    = ws + o; o += 32*32;
    float* wct    = ws + o; o += 32*32;
    float* wd1t   = ws + o; o += 32*9*64;
    float* disp1buf  = e1f;  // e1f dead after encoders (64*NP2 <= 32*NP1)
    float* disp2part = e1c;  // e1c dead after encoders

    // --- prep (one launch; zeroes stats) ---
    prep_all<<<(74816 + 255)/256, 256, 0, stream>>>(
        fnet_w1, cnet_w1, fnet_w2, cnet_w2, fnet_w3, cnet_w3,
        bform_a, bform_b, bform_cd_w, disp_w1, gru_wz, gru_wr, gru_wq,
        we1f, we1c, we2f, we2c, w3f, w3c, wat, wbt, wct, wd1t,
        (float4*)wzrpk, (float2*)wqpk, stats);

    // --- encoders: 3 independent chains merged per stage (5 launches total) ---
    conv7s2_all<<<dim3(NP1/256, 12), 256, 0, stream>>>(image1, image2, we1f, we1c,
                                                       fnet_b1, cnet_b1, e1f, e1c, e1i2);
    stats3_kernel<<<dim3(256, 3), 256, 0, stream>>>(e1f, e1c, e1i2, NP1,
                                                    stats+0, stats+64, stats+256);
    conv3s2_all<<<dim3(NBLK2, 12), 256, 0, stream>>>(e1f, e1c, e1i2, stats,
                                                     we2f, we2c, fnet_b2, cnet_b2,
                                                     e2f, e2c, e2i2);
    stats3_kernel<<<dim3(256, 3), 256, 0, stream>>>(e2f, e2c, e2i2, NP2,
                                                    stats+128, stats+192, stats+320);
    conv1x1_all<<<dim3(NBLK2, 12), 256, 0, stream>>>(e2f, e2c, e2i2, stats,
                                                     w3f, w3c, fnet_b3, cnet_b3,
                                                     fmap1, hidden, fmap2);

    // --- padded working buffers ---
    zero_buf_kernel<<<2048, 256, 0, stream>>>(hwork1, 5*PCHW);  // hwork1..hfinal contiguous
    pad_init_kernel<<<(32*PSL+255)/256, 256, 0, stream>>>(hidden, hwork0);
    feat0_pad_kernel<<<4*NBLK2, 256, 0, stream>>>(fmap1, fmap2, wat, wbt, wct,
                                                  bform_cd_b, feat0);

    // --- sequential GRU sweep: 2 launches per iteration, pass-split for occupancy ---
    float* hwA = hwork0; float* hwB = hwork1;
    float* ftA = feat0;  float* ftB = feat1;
    for (int d = 0; d < ND; ++d) {
        int Wd = W2 - d;
        int nblk = (48*Wd + 255)/256;
        zrq_a<<<dim3(nblk, 32), 256, 0, stream>>>(hwA, ftA, fmap1, fmap2,
                                                  (const float4*)wzrpk, (const float2*)wqpk,
                                                  wat, wbt, wct, bform_cd_b,
                                                  gru_bz, gru_br, zbuf, rhpad, ftB, qpart,
                                                  d, Wd);
        q_fin<<<dim3(nblk, 16), 256, 0, stream>>>(rhpad, hwA, zbuf, qpart,
                                                  (const float2*)wqpk, gru_bq,
                                                  hfinal, hwB, d, Wd);
        float* t;
        t = hwA; hwA = hwB; hwB = t;
        t = ftA; ftA = ftB; ftB = t;
    }

    // --- disparity head (reads padded hfinal) ---
    disp1_v6<<<dim3(30, 16), 256, 0, stream>>>(hfinal, wd1t, disp_b1, disp1buf);
    disp2_part_kernel<<<8*NBLK2, 256, 0, stream>>>(disp1buf, disp_w2, disp2part);
    disp2_comb_kernel<<<NBLK2, 256, 0, stream>>>(disp2part, disp_b2, (float*)d_out);
}